// Round 9
// baseline (569.031 us; speedup 1.0000x reference)
//
#include <hip/hip_runtime.h>

typedef unsigned int u32;
typedef unsigned short u16;

#define NPTS 120000
#define N1PTS 15000
#define NCLSS 17

static inline int cdiv(int a, int b) { return (a + b - 1) / b; }

typedef __attribute__((ext_vector_type(8))) short bf16x8;
typedef __attribute__((ext_vector_type(4))) float f32x4;

// bf16 helpers (storage-only bf16; math fp32)
__device__ __forceinline__ float bflo(u32 u) { return __uint_as_float(u << 16); }
__device__ __forceinline__ float bfhi(u32 u) { return __uint_as_float(u & 0xFFFF0000u); }
__device__ __forceinline__ u32 f2bf(float f) {   // RNE
    u32 u = __float_as_uint(f);
    return (u + 0x7FFFu + ((u >> 16) & 1u)) >> 16;
}
__device__ __forceinline__ u32 pack2(float a, float b) { return f2bf(a) | (f2bf(b) << 16); }

// ---------------- nbr transpose: nbrT[k*M + p] = nbr[p*K + k] ----------------
template<int K>
__global__ __launch_bounds__(256) void transpose_nbr(
    const int* __restrict__ nbr, int* __restrict__ nbrT, int M)
{
    __shared__ int tile[256][K + 1];
    int p0 = blockIdx.x * 256;
    int t = threadIdx.x;
    int np = M - p0; if (np > 256) np = 256;
    int total = np * K;
    for (int i = t; i < total; i += 256) {
        int lp = i / K, k = i - lp * K;
        tile[lp][k] = nbr[(size_t)p0 * K + i];
    }
    __syncthreads();
    if (t < np) {
#pragma unroll
        for (int k = 0; k < K; ++k)
            nbrT[(size_t)k * M + p0 + t] = tile[t][k];
    }
}

// ---------------- weight -> B-fragment conversion (hi/lo bf16 split) ----------------
// uint4 index: s*256 + tile*128 + h*64 + lane  (s = k*CPS + c-chunk, tile = o-half, h=0 hi /1 lo)
struct WbArgs {
    const float* src[8];
    uint4* dst[8];
    int CPS[8];
    int KS2[8];    // K*CPS*2
};

__global__ __launch_bounds__(64) void convert_wb(WbArgs a) {
    int j = blockIdx.y;
    int s2 = blockIdx.x;
    if (s2 >= a.KS2[j]) return;
    int lane = threadIdx.x;
    int s = s2 >> 1, tile = s2 & 1;
    int CPS = a.CPS[j];
    int CIN = CPS * 32;
    int k = s / CPS, c0 = (s % CPS) * 32;
    int c = c0 + (lane >> 4) * 8;
    int o = tile * 16 + (lane & 15);
    const float* w = a.src[j] + ((size_t)k * CIN + c) * 32 + o;
    u32 hw[4], lw[4];
#pragma unroll
    for (int q = 0; q < 4; ++q) {
        float w0 = w[(2 * q) * 32], w1 = w[(2 * q + 1) * 32];
        u32 h0 = f2bf(w0), h1 = f2bf(w1);
        float r0 = w0 - __uint_as_float(h0 << 16);
        float r1 = w1 - __uint_as_float(h1 << 16);
        hw[q] = h0 | (h1 << 16);
        lw[q] = f2bf(r0) | (f2bf(r1) << 16);
    }
    uint4 hv; hv.x = hw[0]; hv.y = hw[1]; hv.z = hw[2]; hv.w = hw[3];
    uint4 lv; lv.x = lw[0]; lv.y = lw[1]; lv.z = lw[2]; lv.w = lw[3];
    a.dst[j][(size_t)(s2 * 2 + 0) * 64 + lane] = hv;
    a.dst[j][(size_t)(s2 * 2 + 1) * 64 + lane] = lv;
}

// ---------------- MFMA sparse conv: async LDS weight ring + counted-vmcnt pipeline ----------------
// Weights DMA'd via global_load_lds into a 3-deep LDS ring (S(c) issued 2 chunks early).
// Pre-barrier wait is a COUNTED vmcnt so gathers (issued 2 chunks ahead) stay in flight.
// ALL loads in the pipeline are unconditional (clamped addr + branchless value masks) so the
// per-wave vmcnt ladder is exact. wb must be padded to NCH+2 chunks (host side).
template<int K, int CIN>
__global__ __launch_bounds__(256, 6) void conv_pipe(
    const u16* __restrict__ src, const int* __restrict__ nbrT,
    const uint4* __restrict__ wb, u16* __restrict__ out,
    float* __restrict__ stats, int M)
{
    constexpr int CPS = CIN / 32;
    constexpr int KS = K * CPS;
    constexpr int NCH = (KS + 1) / 2;
    __shared__ uint4 wlds[3][512];   // 3 x 8 KB ring
    __shared__ float red[4][64];

    int tid = threadIdx.x;
    int lane = tid & 63, wid = tid >> 6;
    int p0 = blockIdx.x * 64 + wid * 16;
    int row = lane & 15, hi4 = lane >> 4;
    int p = p0 + row;
    bool rowok = p < M;
    int psafe = rowok ? p : 0;

    f32x4 acc0 = {0.f, 0.f, 0.f, 0.f};
    f32x4 acc1 = {0.f, 0.f, 0.f, 0.f};

    // always exactly 2 loads (CPS==1) or 1 load (CPS==2); clamped distinct addresses
    auto loadIdxP = [&](int cc, int& ia, int& ib) {
        int s0 = 2 * cc; if (s0 > KS - 1) s0 = KS - 1;
        int s1 = 2 * cc + 1; if (s1 > KS - 1) s1 = KS - 2;
        if constexpr (CPS == 1) {
            ia = nbrT[(size_t)s0 * M + psafe];
            ib = nbrT[(size_t)s1 * M + psafe];
        } else {
            ia = nbrT[(size_t)(s0 >> 1) * M + psafe];
            ib = ia;
        }
    };
    // always exactly 2 loads; branchless masking of invalid rows
    auto gatherG = [&](int ia, int ib, uint4& ga, uint4& gb) {
        int ja = (ia >= 0) ? ia : 0;
        int jb = (ib >= 0) ? ib : 0;
        uint4 a = reinterpret_cast<const uint4*>(src + (size_t)ja * CIN)[hi4];
        uint4 b = reinterpret_cast<const uint4*>(src + (size_t)jb * CIN + (CPS == 2 ? 32 : 0))[hi4];
        u32 ma = (rowok && ia >= 0) ? 0xFFFFFFFFu : 0u;
        u32 mb = (rowok && ib >= 0) ? 0xFFFFFFFFu : 0u;
        ga.x = a.x & ma; ga.y = a.y & ma; ga.z = a.z & ma; ga.w = a.w & ma;
        gb.x = b.x & mb; gb.y = b.y & mb; gb.z = b.z & mb; gb.w = b.w & mb;
    };
    // async DMA: 2 global_load_lds per chunk (counts 2 in vmcnt)
    auto stageC = [&](int cc, int buf) {
        const uint4* gs = wb + (size_t)cc * 512 + tid;
        __builtin_amdgcn_global_load_lds(
            (const __attribute__((address_space(1))) void*)gs,
            (__attribute__((address_space(3))) void*)(&wlds[buf][wid * 64]), 16, 0, 0);
        __builtin_amdgcn_global_load_lds(
            (const __attribute__((address_space(1))) void*)(gs + 256),
            (__attribute__((address_space(3))) void*)(&wlds[buf][256 + wid * 64]), 16, 0, 0);
    };

    // prologue: I(0),I(1),I(2); S(0),S(1); G(0),G(1)   (order pinned)
    int iC2a, iC2b;
    uint4 g0a, g0b, g1a, g1b;
    {
        int i0a, i0b, i1a, i1b;
        loadIdxP(0, i0a, i0b);
        loadIdxP(1, i1a, i1b);
        loadIdxP(2, iC2a, iC2b);
        __builtin_amdgcn_sched_barrier(0);
        stageC(0, 0);
        stageC(1, 1);
        __builtin_amdgcn_sched_barrier(0);
        gatherG(i0a, i0b, g0a, g0b);
        gatherG(i1a, i1b, g1a, g1b);
        __builtin_amdgcn_sched_barrier(0);
    }

    int rbuf = 0;
#pragma unroll 1
    for (int c = 0; c < NCH; ++c) {
        // counted wait: S(c) complete, newer gathers stay in flight
        if (c == 0) {
            asm volatile("s_waitcnt vmcnt(6)" ::: "memory");
        } else {
            if constexpr (CPS == 1) asm volatile("s_waitcnt vmcnt(10)" ::: "memory");
            else                    asm volatile("s_waitcnt vmcnt(8)" ::: "memory");
        }
        __builtin_amdgcn_s_barrier();
        asm volatile("" ::: "memory");
        __builtin_amdgcn_sched_barrier(0);

        int sb = rbuf + 2; if (sb >= 3) sb -= 3;
        stageC(c + 2, sb);                 // S(c+2) -> ring
        __builtin_amdgcn_sched_barrier(0);
        int nIa, nIb;
        loadIdxP(c + 3, nIa, nIb);         // I(c+3)
        __builtin_amdgcn_sched_barrier(0);
        uint4 gf0, gf1;
        gatherG(iC2a, iC2b, gf0, gf1);     // G(c+2)
        __builtin_amdgcn_sched_barrier(0);

        const uint4* bl = &wlds[rbuf][0];
        {
            bf16x8 a = __builtin_bit_cast(bf16x8, g0a);
            bf16x8 b0h = __builtin_bit_cast(bf16x8, bl[lane]);
            bf16x8 b0l = __builtin_bit_cast(bf16x8, bl[64 + lane]);
            bf16x8 b1h = __builtin_bit_cast(bf16x8, bl[128 + lane]);
            bf16x8 b1l = __builtin_bit_cast(bf16x8, bl[192 + lane]);
            acc0 = __builtin_amdgcn_mfma_f32_16x16x32_bf16(a, b0h, acc0, 0, 0, 0);
            acc0 = __builtin_amdgcn_mfma_f32_16x16x32_bf16(a, b0l, acc0, 0, 0, 0);
            acc1 = __builtin_amdgcn_mfma_f32_16x16x32_bf16(a, b1h, acc1, 0, 0, 0);
            acc1 = __builtin_amdgcn_mfma_f32_16x16x32_bf16(a, b1l, acc1, 0, 0, 0);
        }
        if (2 * c + 1 < KS) {
            bf16x8 a = __builtin_bit_cast(bf16x8, g0b);
            bf16x8 b0h = __builtin_bit_cast(bf16x8, bl[256 + lane]);
            bf16x8 b0l = __builtin_bit_cast(bf16x8, bl[320 + lane]);
            bf16x8 b1h = __builtin_bit_cast(bf16x8, bl[384 + lane]);
            bf16x8 b1l = __builtin_bit_cast(bf16x8, bl[448 + lane]);
            acc0 = __builtin_amdgcn_mfma_f32_16x16x32_bf16(a, b0h, acc0, 0, 0, 0);
            acc0 = __builtin_amdgcn_mfma_f32_16x16x32_bf16(a, b0l, acc0, 0, 0, 0);
            acc1 = __builtin_amdgcn_mfma_f32_16x16x32_bf16(a, b1h, acc1, 0, 0, 0);
            acc1 = __builtin_amdgcn_mfma_f32_16x16x32_bf16(a, b1l, acc1, 0, 0, 0);
        }
        g0a = g1a; g0b = g1b; g1a = gf0; g1b = gf1;
        iC2a = nIa; iC2b = nIb;
        rbuf = (rbuf + 1 == 3) ? 0 : rbuf + 1;
    }

    // store: lane holds D[point = hi4*4 + r][o = tile*16 + (lane&15)]
#pragma unroll
    for (int r = 0; r < 4; ++r) {
        int pp = p0 + hi4 * 4 + r;
        if (pp < M) {
            out[(size_t)pp * 32 + (lane & 15)] = (u16)f2bf(acc0[r]);
            out[(size_t)pp * 32 + 16 + (lane & 15)] = (u16)f2bf(acc1[r]);
        }
    }

    // bn stats
    float s0 = 0.f, q0 = 0.f, s1 = 0.f, q1 = 0.f;
#pragma unroll
    for (int r = 0; r < 4; ++r) {
        s0 += acc0[r]; q0 += acc0[r] * acc0[r];
        s1 += acc1[r]; q1 += acc1[r] * acc1[r];
    }
#pragma unroll
    for (int m = 16; m <= 32; m <<= 1) {
        s0 += __shfl_xor(s0, m, 64); q0 += __shfl_xor(q0, m, 64);
        s1 += __shfl_xor(s1, m, 64); q1 += __shfl_xor(q1, m, 64);
    }
    float val = (lane < 16) ? s0 : (lane < 32) ? s1 : (lane < 48) ? q0 : q1;
    red[wid][lane] = val;
    __syncthreads();
    if (wid == 0) {
        float t = red[0][lane] + red[1][lane] + red[2][lane] + red[3][lane];
        atomicAdd(&stats[lane], t);
    }
}

// ---------------- ds 1x1 conv (IDENT): round-8 style, single chunk ----------------
template<int K, int CIN, bool IDENT>
__global__ __launch_bounds__(256, 6) void conv_mfma(
    const u16* __restrict__ src, const int* __restrict__ nbrT,
    const uint4* __restrict__ wb, u16* __restrict__ out,
    float* __restrict__ stats, int M)
{
    constexpr int CPS = CIN / 32;
    constexpr int KS = K * CPS;
    constexpr int NCH = (KS + 1) / 2;
    __shared__ uint4 wlds[2][512];
    __shared__ float red[4][64];

    int tid = threadIdx.x;
    int lane = tid & 63, wid = tid >> 6;
    int p0 = blockIdx.x * 64 + wid * 16;
    int row = lane & 15, hi4 = lane >> 4;
    int p = p0 + row;
    bool rowok = p < M;
    const uint4 z4 = {0u, 0u, 0u, 0u};

    f32x4 acc0 = {0.f, 0.f, 0.f, 0.f};
    f32x4 acc1 = {0.f, 0.f, 0.f, 0.f};

    wlds[0][tid] = wb[tid];
    wlds[0][256 + tid] = wb[256 + tid];
    uint4 av0 = z4, av1 = z4;
    {
        int iA = -1, iB = -1;
        if (rowok) {
            iA = IDENT ? p : nbrT[p];
            if (KS > 1) iB = IDENT ? p : ((CPS == 2) ? iA : nbrT[(size_t)M + p]);
        }
        if (iA >= 0) av0 = reinterpret_cast<const uint4*>(src + (size_t)iA * CIN)[hi4];
        if (KS > 1 && iB >= 0)
            av1 = reinterpret_cast<const uint4*>(src + (size_t)iB * CIN + (CPS == 2 ? 32 : 0))[hi4];
    }

#pragma unroll 1
    for (int c = 0; c < NCH; ++c) {
        asm volatile("s_waitcnt lgkmcnt(0)" ::: "memory");
        __builtin_amdgcn_s_barrier();
        asm volatile("" ::: "memory");
        const uint4* bl = wlds[c & 1];
        {
            bf16x8 a = __builtin_bit_cast(bf16x8, av0);
            bf16x8 b0h = __builtin_bit_cast(bf16x8, bl[lane]);
            bf16x8 b0l = __builtin_bit_cast(bf16x8, bl[64 + lane]);
            bf16x8 b1h = __builtin_bit_cast(bf16x8, bl[128 + lane]);
            bf16x8 b1l = __builtin_bit_cast(bf16x8, bl[192 + lane]);
            acc0 = __builtin_amdgcn_mfma_f32_16x16x32_bf16(a, b0h, acc0, 0, 0, 0);
            acc0 = __builtin_amdgcn_mfma_f32_16x16x32_bf16(a, b0l, acc0, 0, 0, 0);
            acc1 = __builtin_amdgcn_mfma_f32_16x16x32_bf16(a, b1h, acc1, 0, 0, 0);
            acc1 = __builtin_amdgcn_mfma_f32_16x16x32_bf16(a, b1l, acc1, 0, 0, 0);
        }
        if (2 * c + 1 < KS) {
            bf16x8 a = __builtin_bit_cast(bf16x8, av1);
            bf16x8 b0h = __builtin_bit_cast(bf16x8, bl[256 + lane]);
            bf16x8 b0l = __builtin_bit_cast(bf16x8, bl[320 + lane]);
            bf16x8 b1h = __builtin_bit_cast(bf16x8, bl[384 + lane]);
            bf16x8 b1l = __builtin_bit_cast(bf16x8, bl[448 + lane]);
            acc0 = __builtin_amdgcn_mfma_f32_16x16x32_bf16(a, b0h, acc0, 0, 0, 0);
            acc0 = __builtin_amdgcn_mfma_f32_16x16x32_bf16(a, b0l, acc0, 0, 0, 0);
            acc1 = __builtin_amdgcn_mfma_f32_16x16x32_bf16(a, b1h, acc1, 0, 0, 0);
            acc1 = __builtin_amdgcn_mfma_f32_16x16x32_bf16(a, b1l, acc1, 0, 0, 0);
        }
    }

#pragma unroll
    for (int r = 0; r < 4; ++r) {
        int pp = p0 + hi4 * 4 + r;
        if (pp < M) {
            out[(size_t)pp * 32 + (lane & 15)] = (u16)f2bf(acc0[r]);
            out[(size_t)pp * 32 + 16 + (lane & 15)] = (u16)f2bf(acc1[r]);
        }
    }

    float s0 = 0.f, q0 = 0.f, s1 = 0.f, q1 = 0.f;
#pragma unroll
    for (int r = 0; r < 4; ++r) {
        s0 += acc0[r]; q0 += acc0[r] * acc0[r];
        s1 += acc1[r]; q1 += acc1[r] * acc1[r];
    }
#pragma unroll
    for (int m = 16; m <= 32; m <<= 1) {
        s0 += __shfl_xor(s0, m, 64); q0 += __shfl_xor(q0, m, 64);
        s1 += __shfl_xor(s1, m, 64); q1 += __shfl_xor(q1, m, 64);
    }
    float val = (lane < 16) ? s0 : (lane < 32) ? s1 : (lane < 48) ? q0 : q1;
    red[wid][lane] = val;
    __syncthreads();
    if (wid == 0) {
        float t = red[0][lane] + red[1][lane] + red[2][lane] + red[3][lane];
        atomicAdd(&stats[lane], t);
    }
}

// ---------------- stem0 (CIN=3, fp32 x): scalar path, k split across 4 waves ----------------
__device__ __forceinline__ void reduce_store_stats(
    float (&acc)[32], int lane, int wid, bool act, int p,
    u16* __restrict__ out, float* __restrict__ stats)
{
    __shared__ float lds[3][64][17];
#pragma unroll
    for (int r = 0; r < 2; ++r) {
        if (wid > 0) {
#pragma unroll
            for (int j = 0; j < 16; ++j) lds[wid - 1][lane][j] = acc[r * 16 + j];
        }
        __syncthreads();
        if (wid == 0) {
#pragma unroll
            for (int w = 0; w < 3; ++w)
#pragma unroll
                for (int j = 0; j < 16; ++j) acc[r * 16 + j] += lds[w][lane][j];
        }
        __syncthreads();
    }
    if (wid == 0) {
        if (act) {
            u32 wd[16];
#pragma unroll
            for (int q = 0; q < 16; ++q) wd[q] = pack2(acc[2 * q], acc[2 * q + 1]);
            uint4* dst = reinterpret_cast<uint4*>(out + (size_t)p * 32);
            uint4 v;
            v.x = wd[0];  v.y = wd[1];  v.z = wd[2];  v.w = wd[3];  dst[0] = v;
            v.x = wd[4];  v.y = wd[5];  v.z = wd[6];  v.w = wd[7];  dst[1] = v;
            v.x = wd[8];  v.y = wd[9];  v.z = wd[10]; v.w = wd[11]; dst[2] = v;
            v.x = wd[12]; v.y = wd[13]; v.z = wd[14]; v.w = wd[15]; dst[3] = v;
        } else {
#pragma unroll
            for (int o = 0; o < 32; ++o) acc[o] = 0.f;
        }
        float sel1 = 0.f, sel2 = 0.f;
#pragma unroll
        for (int o = 0; o < 32; ++o) {
            float s1 = acc[o], s2 = acc[o] * acc[o];
#pragma unroll
            for (int m = 1; m <= 32; m <<= 1) { s1 += __shfl_xor(s1, m, 64); s2 += __shfl_xor(s2, m, 64); }
            if (lane == o) sel1 = s1;
            if (lane == o + 32) sel2 = s2;
        }
        atomicAdd(&stats[lane], lane < 32 ? sel1 : sel2);
    }
}

__global__ __launch_bounds__(256, 4) void conv_x3(
    const float* __restrict__ src, const int* __restrict__ nbrT,
    const float* __restrict__ W, u16* __restrict__ out,
    float* __restrict__ stats, int M)
{
    constexpr int K = 27;
    int lane = threadIdx.x & 63;
    int wid = __builtin_amdgcn_readfirstlane(threadIdx.x >> 6);
    int p = blockIdx.x * 64 + lane;
    bool act = p < M;
    constexpr int JMAX = 7;

    float acc[32];
#pragma unroll
    for (int o = 0; o < 32; ++o) acc[o] = 0.f;

    int idxs[JMAX];
#pragma unroll
    for (int j = 0; j < JMAX; ++j) {
        int k = wid + 4 * j;
        idxs[j] = (act && k < K) ? nbrT[(size_t)k * M + p] : -1;
    }
#pragma unroll
    for (int j = 0; j < JMAX; ++j) {
        int k = wid + 4 * j;
        if (k >= K) break;
        int idx = idxs[j];
        if (idx >= 0) {
            const float* __restrict__ xr = src + (size_t)idx * 3;
            const float* __restrict__ wk = W + (size_t)k * 3 * 32;
            float x0 = xr[0], x1 = xr[1], x2 = xr[2];
#pragma unroll
            for (int o = 0; o < 32; ++o) {
                float s = fmaf(x0, wk[o], 0.f);
                s = fmaf(x1, wk[32 + o], s);
                acc[o] += fmaf(x2, wk[64 + o], s);
            }
        }
    }
    reduce_store_stats(acc, lane, wid, act, p, out, stats);
}

// ---------------- bn apply in place on bf16 (thread = 8 channels) ----------------
template<bool RELU>
__global__ __launch_bounds__(256) void bn_apply(
    u16* __restrict__ buf, const float* __restrict__ stats,
    const float* __restrict__ gb, float invM, int total)
{
    int i = blockIdx.x * 256 + threadIdx.x;
    if (i >= total) return;
    int c0 = (i & 3) * 8;
    uint4 v = reinterpret_cast<uint4*>(buf)[i];
    u32 w[4] = { v.x, v.y, v.z, v.w };
    u32 r[4];
#pragma unroll
    for (int q = 0; q < 4; ++q) {
        int c = c0 + 2 * q;
        float mu0 = stats[c] * invM;
        float var0 = fmaxf(stats[32 + c] * invM - mu0 * mu0, 0.f);
        float a0 = gb[c] * rsqrtf(var0 + 1e-5f), b0 = gb[32 + c] - mu0 * a0;
        float mu1 = stats[c + 1] * invM;
        float var1 = fmaxf(stats[32 + c + 1] * invM - mu1 * mu1, 0.f);
        float a1 = gb[c + 1] * rsqrtf(var1 + 1e-5f), b1 = gb[32 + c + 1] - mu1 * a1;
        float y0 = fmaf(a0, bflo(w[q]), b0);
        float y1 = fmaf(a1, bfhi(w[q]), b1);
        if (RELU) { y0 = fmaxf(y0, 0.f); y1 = fmaxf(y1, 0.f); }
        r[q] = pack2(y0, y1);
    }
    uint4 o; o.x = r[0]; o.y = r[1]; o.z = r[2]; o.w = r[3];
    reinterpret_cast<uint4*>(buf)[i] = o;
}

// bn+relu(u raw) -> cat[:,0:32]; copy x0 -> cat[:,32:64]
__global__ __launch_bounds__(256) void bnrelu_cat(
    const u16* __restrict__ u, const u16* __restrict__ x0,
    u16* __restrict__ cat, const float* __restrict__ stats,
    const float* __restrict__ gb, float invM, int total)
{
    int i = blockIdx.x * 256 + threadIdx.x;
    if (i >= total) return;
    int p = i >> 2, j = i & 3;
    int c0 = j * 8;
    uint4 v = *reinterpret_cast<const uint4*>(u + (size_t)p * 32 + c0);
    u32 w[4] = { v.x, v.y, v.z, v.w };
    u32 r[4];
#pragma unroll
    for (int q = 0; q < 4; ++q) {
        int c = c0 + 2 * q;
        float mu0 = stats[c] * invM;
        float var0 = fmaxf(stats[32 + c] * invM - mu0 * mu0, 0.f);
        float a0 = gb[c] * rsqrtf(var0 + 1e-5f), b0 = gb[32 + c] - mu0 * a0;
        float mu1 = stats[c + 1] * invM;
        float var1 = fmaxf(stats[32 + c + 1] * invM - mu1 * mu1, 0.f);
        float a1 = gb[c + 1] * rsqrtf(var1 + 1e-5f), b1 = gb[32 + c + 1] - mu1 * a1;
        float y0 = fmaxf(fmaf(a0, bflo(w[q]), b0), 0.f);
        float y1 = fmaxf(fmaf(a1, bfhi(w[q]), b1), 0.f);
        r[q] = pack2(y0, y1);
    }
    uint4 o; o.x = r[0]; o.y = r[1]; o.z = r[2]; o.w = r[3];
    *reinterpret_cast<uint4*>(cat + (size_t)p * 64 + c0) = o;
    uint4 cp = *reinterpret_cast<const uint4*>(x0 + (size_t)p * 32 + c0);
    *reinterpret_cast<uint4*>(cat + (size_t)p * 64 + 32 + c0) = cp;
}

// ---------------- attention ----------------
__device__ __forceinline__ void load_row32(const u16* __restrict__ base, int p, float (&nv)[32])
{
    const uint4* xr = reinterpret_cast<const uint4*>(base + (size_t)p * 32);
#pragma unroll
    for (int q = 0; q < 4; ++q) {
        uint4 v = xr[q];
        nv[q * 8 + 0] = bflo(v.x); nv[q * 8 + 1] = bfhi(v.x);
        nv[q * 8 + 2] = bflo(v.y); nv[q * 8 + 3] = bfhi(v.y);
        nv[q * 8 + 4] = bflo(v.z); nv[q * 8 + 5] = bfhi(v.z);
        nv[q * 8 + 6] = bflo(v.w); nv[q * 8 + 7] = bfhi(v.w);
    }
}

__global__ __launch_bounds__(256) void att_logits(
    const u16* __restrict__ net, const float* __restrict__ wi,
    const float* __restrict__ bi, float* __restrict__ lbuf,
    u32* __restrict__ mx, int M)
{
    int p = blockIdx.x * 256 + threadIdx.x;
    float l = -3.0e38f;
    if (p < M) {
        float nv[32];
        load_row32(net, p, nv);
        float s = bi[0];
#pragma unroll
        for (int c = 0; c < 32; ++c) s = fmaf(nv[c], wi[c], s);
        lbuf[p] = s;
        l = s;
    }
#pragma unroll
    for (int m = 1; m <= 32; m <<= 1) l = fmaxf(l, __shfl_xor(l, m, 64));
    if ((threadIdx.x & 63) == 0) {
        u32 b = __float_as_uint(l);
        u32 e = (b & 0x80000000u) ? ~b : (b | 0x80000000u);
        atomicMax(mx, e);
    }
}

__global__ __launch_bounds__(256) void att_accum(
    const u16* __restrict__ net, const float* __restrict__ lbuf,
    float* __restrict__ att, int M)
{
    int p = blockIdx.x * 256 + threadIdx.x;
    int lane = threadIdx.x & 63, wid = threadIdx.x >> 6;
    u32 um = __float_as_uint(att[0]);
    float mx = (um & 0x80000000u) ? __uint_as_float(um ^ 0x80000000u) : __uint_as_float(~um);
    float w = 0.f;
    float nv[32];
#pragma unroll
    for (int c = 0; c < 32; ++c) nv[c] = 0.f;
    if (p < M) {
        w = expf(lbuf[p] - mx);
        load_row32(net, p, nv);
    }
    float sel = 0.f;
#pragma unroll
    for (int c = 0; c < 32; ++c) {
        float s = w * nv[c];
#pragma unroll
        for (int m = 1; m <= 32; m <<= 1) s += __shfl_xor(s, m, 64);
        if (lane == c) sel = s;
    }
    {
        float s = w;
#pragma unroll
        for (int m = 1; m <= 32; m <<= 1) s += __shfl_xor(s, m, 64);
        if (lane == 32) sel = s;
    }
    __shared__ float red[4][33];
    if (lane < 33) red[wid][lane] = sel;
    __syncthreads();
    if (wid == 0 && lane < 33) {
        float t = red[0][lane] + red[1][lane] + red[2][lane] + red[3][lane];
        atomicAdd(lane < 32 ? &att[2 + lane] : &att[1], t);
    }
}

__global__ void att_ctx_k(const float* __restrict__ wk, const float* __restrict__ bk,
                          float* __restrict__ att)
{
    int o = threadIdx.x;
    if (o >= 32) return;
    float invS = 1.0f / att[1];
    float s = bk[o];
#pragma unroll
    for (int c = 0; c < 32; ++c) s = fmaf(att[2 + c] * invS, wk[c * 32 + o], s);
    att[34 + o] = s;
}

__global__ __launch_bounds__(256) void att_out_res(
    const u16* __restrict__ net, const u16* __restrict__ d,
    const float* __restrict__ wv, const float* __restrict__ bv,
    const float* __restrict__ wo, const float* __restrict__ bo,
    const float* __restrict__ att, u16* __restrict__ r, int M)
{
    int p = blockIdx.x * 256 + threadIdx.x;
    if (p >= M) return;
    float nv[32];
    load_row32(net, p, nv);
    float vv[32];
#pragma unroll
    for (int o = 0; o < 32; ++o) {
        float s = bv[o];
#pragma unroll
        for (int c = 0; c < 32; ++c) s = fmaf(nv[c], wv[c * 32 + o], s);
        vv[o] = s * att[34 + o];
    }
    float dv[32];
    load_row32(d, p, dv);
    u32 wd[16];
#pragma unroll
    for (int q = 0; q < 16; ++q) {
        float y[2];
#pragma unroll
        for (int t = 0; t < 2; ++t) {
            int oo = 2 * q + t;
            float s = bo[oo];
#pragma unroll
            for (int o = 0; o < 32; ++o) s = fmaf(vv[o], wo[o * 32 + oo], s);
            y[t] = fmaxf(s + dv[oo], 0.f);
        }
        wd[q] = pack2(y[0], y[1]);
    }
    uint4* dst = reinterpret_cast<uint4*>(r + (size_t)p * 32);
    uint4 v;
    v.x = wd[0];  v.y = wd[1];  v.z = wd[2];  v.w = wd[3];  dst[0] = v;
    v.x = wd[4];  v.y = wd[5];  v.z = wd[6];  v.w = wd[7];  dst[1] = v;
    v.x = wd[8];  v.y = wd[9];  v.z = wd[10]; v.w = wd[11]; dst[2] = v;
    v.x = wd[12]; v.y = wd[13]; v.z = wd[14]; v.w = wd[15]; dst[3] = v;
}

// ---------------- final: y = relu(bn(net2) + bn(ds)); out = y@Wcls + bcls ----------------
__global__ __launch_bounds__(256) void final_cls(
    const u16* __restrict__ net2, const u16* __restrict__ dsr,
    const float* __restrict__ st7, const float* __restrict__ st8,
    const float* __restrict__ gb7, const float* __restrict__ gb8,
    const float* __restrict__ wcls, const float* __restrict__ bcls,
    float* __restrict__ outp, float invM, int M)
{
    int p = blockIdx.x * 256 + threadIdx.x;
    if (p >= M) return;
    float nv[32], dv[32];
    load_row32(net2, p, nv);
    load_row32(dsr, p, dv);
    float y[32];
#pragma unroll
    for (int c = 0; c < 32; ++c) {
        float mu1 = st7[c] * invM;
        float var1 = fmaxf(st7[32 + c] * invM - mu1 * mu1, 0.f);
        float a1 = gb7[c] * rsqrtf(var1 + 1e-5f);
        float b1 = gb7[32 + c] - mu1 * a1;
        float mu2 = st8[c] * invM;
        float var2 = fmaxf(st8[32 + c] * invM - mu2 * mu2, 0.f);
        float a2 = gb8[c] * rsqrtf(var2 + 1e-5f);
        float b2 = gb8[32 + c] - mu2 * a2;
        float t = fmaf(a1, nv[c], b1) + fmaf(a2, dv[c], b2);
        y[c] = fmaxf(t, 0.f);
    }
#pragma unroll
    for (int j = 0; j < NCLSS; ++j) {
        float s = bcls[j];
#pragma unroll
        for (int c = 0; c < 32; ++c) s = fmaf(y[c], wcls[c * NCLSS + j], s);
        outp[(size_t)p * NCLSS + j] = s;
    }
}

// ---------------- host ----------------
extern "C" void kernel_launch(void* const* d_in, const int* in_sizes, int n_in,
                              void* d_out, int out_size, void* d_ws, size_t ws_size,
                              hipStream_t stream)
{
    char* wsb = (char*)d_ws;

    float* ST  = (float*)wsb;                 // 642 floats: 9*64 stats + 66 att
    float* ATT = ST + 576;
    float* L   = (float*)(wsb + 4096);        // N1 logits fp32
    u16* A = (u16*)(wsb + 65536);             // N*32 bf16 (7,680,000 B each)
    u16* B = (u16*)(wsb + 65536 + 7680000ull);
    u16* C = (u16*)(wsb + 65536 + 2 * 7680000ull);            // N1*32 (960,000 B)
    u16* D = (u16*)(wsb + 65536 + 2 * 7680000ull + 960000ull);
    u16* E = (u16*)(wsb + 65536 + 2 * 7680000ull + 2 * 960000ull);
    u16* F = (u16*)(wsb + 65536 + 2 * 7680000ull + 3 * 960000ull);          // cat N*64
    u16* G = (u16*)(wsb + 65536 + 2 * 7680000ull + 3 * 960000ull + 15360000ull); // net2 N*32

    // B-fragment weight buffers, padded to NCH+2 chunks for the async ring
    size_t wboff = 65536 + 2 * 7680000ull + 3 * 960000ull + 15360000ull + 7680000ull;
    auto wbszP = [](int KS) { int NCH = (KS + 1) / 2; return (size_t)(NCH + 2) * 512 * 16; };
    uint4* wb_stem1 = (uint4*)(wsb + wboff);                 size_t o1 = wboff + wbszP(27);
    uint4* wb_down  = (uint4*)(wsb + o1);                    size_t o2 = o1 + wbszP(8);
    uint4* wb_res1  = (uint4*)(wsb + o2);                    size_t o3 = o2 + wbszP(27);
    uint4* wb_res2  = (uint4*)(wsb + o3);                    size_t o4 = o3 + wbszP(27);
    uint4* wb_up    = (uint4*)(wsb + o4);                    size_t o5 = o4 + wbszP(8);
    uint4* wb_fuse1 = (uint4*)(wsb + o5);                    size_t o6 = o5 + wbszP(54);
    uint4* wb_fuse2 = (uint4*)(wsb + o6);                    size_t o7 = o6 + wbszP(27);
    uint4* wb_ds    = (uint4*)(wsb + o7);                    size_t o8 = o7 + 8192;

    // transposed nbr buffers (k-major)
    int* nbrT0 = (int*)(wsb + o8);                           size_t o9  = o8 + 27ull * NPTS * 4;
    int* nbrTd = (int*)(wsb + o9);                           size_t o10 = o9 + 8ull * N1PTS * 4;
    int* nbrT1 = (int*)(wsb + o10);                          size_t o11 = o10 + 27ull * N1PTS * 4;
    int* nbrTu = (int*)(wsb + o11);

    // inputs (fp32 per reference dtypes)
    const float* X        = (const float*)d_in[0];
    const float* Wstem0   = (const float*)d_in[1];
    const float* gb_stem0 = (const float*)d_in[2];
    const float* Wstem1   = (const float*)d_in[3];
    const float* gb_stem1 = (const float*)d_in[4];
    const float* Wdown    = (const float*)d_in[5];
    const float* gb_down  = (const float*)d_in[6];
    const float* Wres1    = (const float*)d_in[7];
    const float* gb_res1  = (const float*)d_in[8];
    const float* Wres2    = (const float*)d_in[9];
    const float* gb_res2  = (const float*)d_in[10];
    const float* wi = (const float*)d_in[11];
    const float* bi = (const float*)d_in[12];
    const float* wk = (const float*)d_in[13];
    const float* bk = (const float*)d_in[14];
    const float* wv = (const float*)d_in[15];
    const float* bv = (const float*)d_in[16];
    const float* wo = (const float*)d_in[17];
    const float* bo = (const float*)d_in[18];
    const float* Wup      = (const float*)d_in[19];
    const float* gb_up    = (const float*)d_in[20];
    const float* Wfuse1   = (const float*)d_in[21];
    const float* gb_fuse1 = (const float*)d_in[22];
    const float* Wfuse2   = (const float*)d_in[23];
    const float* gb_fuse2 = (const float*)d_in[24];
    const float* Wds      = (const float*)d_in[25];
    const float* gb_ds    = (const float*)d_in[26];
    const float* Wcls     = (const float*)d_in[27];
    const float* bcls     = (const float*)d_in[28];

    const int* nbr0     = (const int*)d_in[29];
    const int* nbr_down = (const int*)d_in[30];
    const int* nbr1     = (const int*)d_in[31];
    const int* nbr_up   = (const int*)d_in[32];

    const float invN  = 1.0f / (float)NPTS;
    const float invN1 = 1.0f / (float)N1PTS;

    hipMemsetAsync((void*)ST, 0, 642 * sizeof(float), stream);

    // transpose nbr arrays to k-major
    hipLaunchKernelGGL((transpose_nbr<27>), dim3(cdiv(NPTS, 256)), dim3(256), 0, stream,
                       nbr0, nbrT0, NPTS);
    hipLaunchKernelGGL((transpose_nbr<8>), dim3(cdiv(N1PTS, 256)), dim3(256), 0, stream,
                       nbr_down, nbrTd, N1PTS);
    hipLaunchKernelGGL((transpose_nbr<27>), dim3(cdiv(N1PTS, 256)), dim3(256), 0, stream,
                       nbr1, nbrT1, N1PTS);
    hipLaunchKernelGGL((transpose_nbr<8>), dim3(cdiv(NPTS, 256)), dim3(256), 0, stream,
                       nbr_up, nbrTu, NPTS);

    // pack all conv weights into MFMA B-fragment layout (hi/lo split)
    {
        WbArgs a;
        a.src[0] = Wstem1; a.dst[0] = wb_stem1; a.CPS[0] = 1; a.KS2[0] = 54;
        a.src[1] = Wdown;  a.dst[1] = wb_down;  a.CPS[1] = 1; a.KS2[1] = 16;
        a.src[2] = Wres1;  a.dst[2] = wb_res1;  a.CPS[2] = 1; a.KS2[2] = 54;
        a.src[3] = Wres2;  a.dst[3] = wb_res2;  a.CPS[3] = 1; a.KS2[3] = 54;
        a.src[4] = Wup;    a.dst[4] = wb_up;    a.CPS[4] = 1; a.KS2[4] = 16;
        a.src[5] = Wfuse1; a.dst[5] = wb_fuse1; a.CPS[5] = 2; a.KS2[5] = 108;
        a.src[6] = Wfuse2; a.dst[6] = wb_fuse2; a.CPS[6] = 1; a.KS2[6] = 54;
        a.src[7] = Wds;    a.dst[7] = wb_ds;    a.CPS[7] = 2; a.KS2[7] = 4;
        hipLaunchKernelGGL(convert_wb, dim3(108, 8), dim3(64), 0, stream, a);
    }

    const int gMN   = cdiv(NPTS, 64);            // 1875 (4 waves x 16 pts)
    const int gMN1  = cdiv(N1PTS, 64);           // 235
    const int gBN   = cdiv(NPTS * 4, 256);
    const int gBN1  = cdiv(N1PTS * 4, 256);
    const int gN1p  = cdiv(N1PTS, 256);
    const int gN    = cdiv(NPTS, 256);

    // stem
    hipLaunchKernelGGL(conv_x3, dim3(gMN), dim3(256), 0, stream,
                       X, nbrT0, Wstem0, A, ST + 0 * 64, NPTS);
    hipLaunchKernelGGL((bn_apply<true>), dim3(gBN), dim3(256), 0, stream,
                       A, ST + 0 * 64, gb_stem0, invN, NPTS * 4);
    hipLaunchKernelGGL((conv_pipe<27, 32>), dim3(gMN), dim3(256), 0, stream,
                       A, nbrT0, wb_stem1, B, ST + 1 * 64, NPTS);
    hipLaunchKernelGGL((bn_apply<true>), dim3(gBN), dim3(256), 0, stream,
                       B, ST + 1 * 64, gb_stem1, invN, NPTS * 4);   // B = x0

    // downsample
    hipLaunchKernelGGL((conv_pipe<8, 32>), dim3(gMN1), dim3(256), 0, stream,
                       B, nbrTd, wb_down, C, ST + 2 * 64, N1PTS);
    hipLaunchKernelGGL((bn_apply<true>), dim3(gBN1), dim3(256), 0, stream,
                       C, ST + 2 * 64, gb_down, invN1, N1PTS * 4);  // C = d

    // residual block convs
    hipLaunchKernelGGL((conv_pipe<27, 32>), dim3(gMN1), dim3(256), 0, stream,
                       C, nbrT1, wb_res1, D, ST + 3 * 64, N1PTS);
    hipLaunchKernelGGL((bn_apply<true>), dim3(gBN1), dim3(256), 0, stream,
                       D, ST + 3 * 64, gb_res1, invN1, N1PTS * 4);
    hipLaunchKernelGGL((conv_pipe<27, 32>), dim3(gMN1), dim3(256), 0, stream,
                       D, nbrT1, wb_res2, E, ST + 4 * 64, N1PTS);
    hipLaunchKernelGGL((bn_apply<false>), dim3(gBN1), dim3(256), 0, stream,
                       E, ST + 4 * 64, gb_res2, invN1, N1PTS * 4);  // E = net

    // attention + residual add (writes r into D)
    hipLaunchKernelGGL(att_logits, dim3(gN1p), dim3(256), 0, stream,
                       E, wi, bi, L, (u32*)ATT, N1PTS);
    hipLaunchKernelGGL(att_accum, dim3(gN1p), dim3(256), 0, stream, E, L, ATT, N1PTS);
    hipLaunchKernelGGL(att_ctx_k, dim3(1), dim3(64), 0, stream, wk, bk, ATT);
    hipLaunchKernelGGL(att_out_res, dim3(gN1p), dim3(256), 0, stream,
                       E, C, wv, bv, wo, bo, ATT, D, N1PTS);        // D = r

    // upsample + cat
    hipLaunchKernelGGL((conv_pipe<8, 32>), dim3(gMN), dim3(256), 0, stream,
                       D, nbrTu, wb_up, A, ST + 5 * 64, NPTS);
    hipLaunchKernelGGL(bnrelu_cat, dim3(gBN), dim3(256), 0, stream,
                       A, B, F, ST + 5 * 64, gb_up, invN, NPTS * 4); // F = cat

    // fuse residual block: ds first, then fuse1/fuse2
    hipLaunchKernelGGL((conv_mfma<1, 64, true>), dim3(gMN), dim3(256), 0, stream,
                       F, (const int*)nullptr, wb_ds, B, ST + 8 * 64, NPTS); // B = ds raw
    hipLaunchKernelGGL((conv_pipe<27, 64>), dim3(gMN), dim3(256), 0, stream,
                       F, nbrT0, wb_fuse1, A, ST + 6 * 64, NPTS);
    hipLaunchKernelGGL((bn_apply<true>), dim3(gBN), dim3(256), 0, stream,
                       A, ST + 6 * 64, gb_fuse1, invN, NPTS * 4);
    hipLaunchKernelGGL((conv_pipe<27, 32>), dim3(gMN), dim3(256), 0, stream,
                       A, nbrT0, wb_fuse2, G, ST + 7 * 64, NPTS);    // G = net2 raw

    // final fuse + classifier
    hipLaunchKernelGGL(final_cls, dim3(gN), dim3(256), 0, stream,
                       G, B, ST + 7 * 64, ST + 8 * 64, gb_fuse2, gb_ds,
                       Wcls, bcls, (float*)d_out, invN, NPTS);
}

// Round 10
// 513.174 us; speedup vs baseline: 1.1088x; 1.1088x over previous
//
#include <hip/hip_runtime.h>

typedef unsigned int u32;
typedef unsigned short u16;

#define NPTS 120000
#define N1PTS 15000
#define NCLSS 17

static inline int cdiv(int a, int b) { return (a + b - 1) / b; }

typedef __attribute__((ext_vector_type(8))) short bf16x8;
typedef __attribute__((ext_vector_type(4))) float f32x4;

// bf16 helpers (storage-only bf16; math fp32)
__device__ __forceinline__ float bflo(u32 u) { return __uint_as_float(u << 16); }
__device__ __forceinline__ float bfhi(u32 u) { return __uint_as_float(u & 0xFFFF0000u); }
__device__ __forceinline__ u32 f2bf(float f) {   // RNE
    u32 u = __float_as_uint(f);
    return (u + 0x7FFFu + ((u >> 16) & 1u)) >> 16;
}
__device__ __forceinline__ u32 pack2(float a, float b) { return f2bf(a) | (f2bf(b) << 16); }

__device__ __forceinline__ f32x4 mfma16(bf16x8 a, uint4 b, f32x4 c) {
    return __builtin_amdgcn_mfma_f32_16x16x32_bf16(a, __builtin_bit_cast(bf16x8, b), c, 0, 0, 0);
}

// ---------------- nbr transpose: nbrT[k*M + p] = nbr[p*K + k] ----------------
template<int K>
__global__ __launch_bounds__(256) void transpose_nbr(
    const int* __restrict__ nbr, int* __restrict__ nbrT, int M)
{
    __shared__ int tile[256][K + 1];
    int p0 = blockIdx.x * 256;
    int t = threadIdx.x;
    int np = M - p0; if (np > 256) np = 256;
    int total = np * K;
    for (int i = t; i < total; i += 256) {
        int lp = i / K, k = i - lp * K;
        tile[lp][k] = nbr[(size_t)p0 * K + i];
    }
    __syncthreads();
    if (t < np) {
#pragma unroll
        for (int k = 0; k < K; ++k)
            nbrT[(size_t)k * M + p0 + t] = tile[t][k];
    }
}

// ---------------- weight -> B-fragment conversion (hi/lo bf16 split) ----------------
// dst uint4 index: k*256 + tile*128 + h*64 + lane. Per-entry CINF (full CIN) + COFF (channel base).
struct WbArgs {
    const float* src[8];
    uint4* dst[8];
    int CINF[8];
    int COFF[8];
    int K2[8];    // 2*K
};

__global__ __launch_bounds__(64) void convert_wb(WbArgs a) {
    int j = blockIdx.y;
    int s2 = blockIdx.x;
    if (s2 >= a.K2[j]) return;
    int lane = threadIdx.x;
    int k = s2 >> 1, tile = s2 & 1;
    int c = a.COFF[j] + (lane >> 4) * 8;
    int o = tile * 16 + (lane & 15);
    const float* w = a.src[j] + ((size_t)k * a.CINF[j] + c) * 32 + o;
    u32 hw[4], lw[4];
#pragma unroll
    for (int q = 0; q < 4; ++q) {
        float w0 = w[(2 * q) * 32], w1 = w[(2 * q + 1) * 32];
        u32 h0 = f2bf(w0), h1 = f2bf(w1);
        float r0 = w0 - __uint_as_float(h0 << 16);
        float r1 = w1 - __uint_as_float(h1 << 16);
        hw[q] = h0 | (h1 << 16);
        lw[q] = f2bf(r0) | (f2bf(r1) << 16);
    }
    uint4 hv; hv.x = hw[0]; hv.y = hw[1]; hv.z = hw[2]; hv.w = hw[3];
    uint4 lv; lv.x = lw[0]; lv.y = lw[1]; lv.z = lw[2]; lv.w = lw[3];
    a.dst[j][(size_t)(s2 * 2 + 0) * 64 + lane] = hv;
    a.dst[j][(size_t)(s2 * 2 + 1) * 64 + lane] = lv;
}

// ---------------- conv_blk: 16-wave block, ALL weights in LDS, barrier-free k-loop ----------------
// CIN = 32. MODE 0: bf16 out + stats; MODE 1: fp32 out (no stats); MODE 2: fp32 in, bf16 out + stats.
// Each wave = 16 points x 32 outputs, independent 3-deep gather pipeline (compiler-scheduled waits).
template<int K, int MODE>
__global__ __launch_bounds__(1024, 4) void conv_blk(
    const u16* __restrict__ src, const int* __restrict__ nbrT,
    const uint4* __restrict__ wb, u16* __restrict__ out,
    float* __restrict__ outf, float* __restrict__ stats, int M)
{
    __shared__ uint4 wl[K * 256];
    __shared__ float red[15][64];
    int tid = threadIdx.x;
    int lane = tid & 63, wid = tid >> 6;
    int p0 = blockIdx.x * 256 + wid * 16;
    int row = lane & 15, hi4 = lane >> 4;
    int p = p0 + row;
    bool rowok = p < M;
    int psafe = rowok ? p : 0;
    const uint4 z4 = {0u, 0u, 0u, 0u};

    // stage entire weight tensor (coalesced, once)
    for (int i = tid; i < K * 256; i += 1024) wl[i] = wb[i];

    f32x4 acc0, acc1;
    if (MODE == 2) {
#pragma unroll
        for (int r = 0; r < 4; ++r) {
            int pp = p0 + hi4 * 4 + r;
            int ps = pp < M ? pp : 0;
            acc0[r] = outf[(size_t)ps * 32 + (lane & 15)];
            acc1[r] = outf[(size_t)ps * 32 + 16 + (lane & 15)];
        }
    } else {
        acc0 = {0.f, 0.f, 0.f, 0.f};
        acc1 = {0.f, 0.f, 0.f, 0.f};
    }

    auto gidx = [&](int k) -> int {
        int kk = k < K ? k : K - 1;
        return nbrT[(size_t)kk * M + psafe];
    };
    auto gat = [&](int idx) -> uint4 {
        int j = idx >= 0 ? idx : 0;
        uint4 v = reinterpret_cast<const uint4*>(src + (size_t)j * 32)[hi4];
        u32 m = (rowok && idx >= 0) ? 0xFFFFFFFFu : 0u;
        uint4 r; r.x = v.x & m; r.y = v.y & m; r.z = v.z & m; r.w = v.w & m;
        return r;
    };

    __syncthreads();   // weights visible; gathers issued after so nothing drains them

    int ia = K > 2 ? gidx(2) : 0;
    uint4 g0 = gat(gidx(0));
    uint4 g1 = K > 1 ? gat(gidx(1)) : z4;

#pragma unroll 1
    for (int k = 0; k < K; ++k) {
        uint4 gn = (k + 2 < K) ? gat(ia) : z4;
        int ian = (k + 3 < K) ? gidx(k + 3) : 0;
        const uint4* bl = &wl[k * 256];
        bf16x8 a = __builtin_bit_cast(bf16x8, g0);
        acc0 = mfma16(a, bl[lane], acc0);
        acc0 = mfma16(a, bl[64 + lane], acc0);
        acc1 = mfma16(a, bl[128 + lane], acc1);
        acc1 = mfma16(a, bl[192 + lane], acc1);
        g0 = g1; g1 = gn; ia = ian;
    }

    if (MODE == 1) {
#pragma unroll
        for (int r = 0; r < 4; ++r) {
            int pp = p0 + hi4 * 4 + r;
            if (pp < M) {
                outf[(size_t)pp * 32 + (lane & 15)] = acc0[r];
                outf[(size_t)pp * 32 + 16 + (lane & 15)] = acc1[r];
            }
        }
        return;
    }

    // bf16 store
#pragma unroll
    for (int r = 0; r < 4; ++r) {
        int pp = p0 + hi4 * 4 + r;
        if (pp < M) {
            out[(size_t)pp * 32 + (lane & 15)] = (u16)f2bf(acc0[r]);
            out[(size_t)pp * 32 + 16 + (lane & 15)] = (u16)f2bf(acc1[r]);
        }
    }

    // bn stats
    float s0 = 0.f, q0 = 0.f, s1 = 0.f, q1 = 0.f;
#pragma unroll
    for (int r = 0; r < 4; ++r) {
        s0 += acc0[r]; q0 += acc0[r] * acc0[r];
        s1 += acc1[r]; q1 += acc1[r] * acc1[r];
    }
#pragma unroll
    for (int m = 16; m <= 32; m <<= 1) {
        s0 += __shfl_xor(s0, m, 64); q0 += __shfl_xor(q0, m, 64);
        s1 += __shfl_xor(s1, m, 64); q1 += __shfl_xor(q1, m, 64);
    }
    float val = (lane < 16) ? s0 : (lane < 32) ? s1 : (lane < 48) ? q0 : q1;
    if (wid > 0) red[wid - 1][lane] = val;
    __syncthreads();
    if (wid == 0) {
        float t = val;
#pragma unroll
        for (int w = 0; w < 15; ++w) t += red[w][lane];
        atomicAdd(&stats[lane], t);
    }
}

// ---------------- conv_mfma: 4-wave version for small N1 grids (round-8 structure) ----------------
template<int K>
__global__ __launch_bounds__(256, 6) void conv_mfma(
    const u16* __restrict__ src, const int* __restrict__ nbrT,
    const uint4* __restrict__ wb, u16* __restrict__ out,
    float* __restrict__ stats, int M)
{
    constexpr int KS = K;
    constexpr int NCH = (KS + 1) / 2;
    __shared__ uint4 wlds[2][512];
    __shared__ float red[4][64];

    int tid = threadIdx.x;
    int lane = tid & 63, wid = tid >> 6;
    int p0 = blockIdx.x * 64 + wid * 16;
    int row = lane & 15, hi4 = lane >> 4;
    int p = p0 + row;
    bool rowok = p < M;
    const uint4 z4 = {0u, 0u, 0u, 0u};

    f32x4 acc0 = {0.f, 0.f, 0.f, 0.f};
    f32x4 acc1 = {0.f, 0.f, 0.f, 0.f};

    {
        uint4 a0 = wb[tid], a1 = wb[256 + tid];
        wlds[0][tid] = a0; wlds[0][256 + tid] = a1;
    }
    uint4 av0 = z4, av1 = z4;
    {
        int iA = -1, iB = -1;
        if (rowok) {
            iA = nbrT[p];
            if (KS > 1) iB = nbrT[(size_t)M + p];
        }
        if (iA >= 0) av0 = reinterpret_cast<const uint4*>(src + (size_t)iA * 32)[hi4];
        if (KS > 1 && iB >= 0) av1 = reinterpret_cast<const uint4*>(src + (size_t)iB * 32)[hi4];
    }

    uint4 wr0 = z4, wr1 = z4;
#pragma unroll 1
    for (int c = 0; c < NCH; ++c) {
        bool last = (c + 1 >= NCH);
        if (!last) {
            wr0 = wb[(size_t)(c + 1) * 512 + tid];
            wr1 = wb[(size_t)(c + 1) * 512 + 256 + tid];
        }
        int nA = -1, nB = -1;
        if (!last && rowok) {
            int s0 = 2 * c + 2;
            nA = nbrT[(size_t)s0 * M + p];
            if (s0 + 1 < KS) nB = nbrT[(size_t)(s0 + 1) * M + p];
        }
        asm volatile("s_waitcnt lgkmcnt(0)" ::: "memory");
        __builtin_amdgcn_s_barrier();
        asm volatile("" ::: "memory");
        uint4 nav0 = z4, nav1 = z4;
        if (nA >= 0) nav0 = reinterpret_cast<const uint4*>(src + (size_t)nA * 32)[hi4];
        if (nB >= 0) nav1 = reinterpret_cast<const uint4*>(src + (size_t)nB * 32)[hi4];

        const uint4* bl = wlds[c & 1];
        {
            bf16x8 a = __builtin_bit_cast(bf16x8, av0);
            acc0 = mfma16(a, bl[lane], acc0);
            acc0 = mfma16(a, bl[64 + lane], acc0);
            acc1 = mfma16(a, bl[128 + lane], acc1);
            acc1 = mfma16(a, bl[192 + lane], acc1);
        }
        if (2 * c + 1 < KS) {
            bf16x8 a = __builtin_bit_cast(bf16x8, av1);
            acc0 = mfma16(a, bl[256 + lane], acc0);
            acc0 = mfma16(a, bl[320 + lane], acc0);
            acc1 = mfma16(a, bl[384 + lane], acc1);
            acc1 = mfma16(a, bl[448 + lane], acc1);
        }
        if (!last) {
            wlds[(c + 1) & 1][tid] = wr0;
            wlds[(c + 1) & 1][256 + tid] = wr1;
        }
        av0 = nav0; av1 = nav1;
    }

#pragma unroll
    for (int r = 0; r < 4; ++r) {
        int pp = p0 + hi4 * 4 + r;
        if (pp < M) {
            out[(size_t)pp * 32 + (lane & 15)] = (u16)f2bf(acc0[r]);
            out[(size_t)pp * 32 + 16 + (lane & 15)] = (u16)f2bf(acc1[r]);
        }
    }

    float s0 = 0.f, q0 = 0.f, s1 = 0.f, q1 = 0.f;
#pragma unroll
    for (int r = 0; r < 4; ++r) {
        s0 += acc0[r]; q0 += acc0[r] * acc0[r];
        s1 += acc1[r]; q1 += acc1[r] * acc1[r];
    }
#pragma unroll
    for (int m = 16; m <= 32; m <<= 1) {
        s0 += __shfl_xor(s0, m, 64); q0 += __shfl_xor(q0, m, 64);
        s1 += __shfl_xor(s1, m, 64); q1 += __shfl_xor(q1, m, 64);
    }
    float val = (lane < 16) ? s0 : (lane < 32) ? s1 : (lane < 48) ? q0 : q1;
    red[wid][lane] = val;
    __syncthreads();
    if (wid == 0) {
        float t = red[0][lane] + red[1][lane] + red[2][lane] + red[3][lane];
        atomicAdd(&stats[lane], t);
    }
}

// ---------------- shared scalar epilogue (conv_x3, conv_ds2) ----------------
__device__ __forceinline__ void reduce_store_stats(
    float (&acc)[32], int lane, int wid, bool act, int p,
    u16* __restrict__ out, float* __restrict__ stats)
{
    __shared__ float lds[3][64][17];
#pragma unroll
    for (int r = 0; r < 2; ++r) {
        if (wid > 0) {
#pragma unroll
            for (int j = 0; j < 16; ++j) lds[wid - 1][lane][j] = acc[r * 16 + j];
        }
        __syncthreads();
        if (wid == 0) {
#pragma unroll
            for (int w = 0; w < 3; ++w)
#pragma unroll
                for (int j = 0; j < 16; ++j) acc[r * 16 + j] += lds[w][lane][j];
        }
        __syncthreads();
    }
    if (wid == 0) {
        if (act) {
            u32 wd[16];
#pragma unroll
            for (int q = 0; q < 16; ++q) wd[q] = pack2(acc[2 * q], acc[2 * q + 1]);
            uint4* dst = reinterpret_cast<uint4*>(out + (size_t)p * 32);
            uint4 v;
            v.x = wd[0];  v.y = wd[1];  v.z = wd[2];  v.w = wd[3];  dst[0] = v;
            v.x = wd[4];  v.y = wd[5];  v.z = wd[6];  v.w = wd[7];  dst[1] = v;
            v.x = wd[8];  v.y = wd[9];  v.z = wd[10]; v.w = wd[11]; dst[2] = v;
            v.x = wd[12]; v.y = wd[13]; v.z = wd[14]; v.w = wd[15]; dst[3] = v;
        } else {
#pragma unroll
            for (int o = 0; o < 32; ++o) acc[o] = 0.f;
        }
        float sel1 = 0.f, sel2 = 0.f;
#pragma unroll
        for (int o = 0; o < 32; ++o) {
            float s1 = acc[o], s2 = acc[o] * acc[o];
#pragma unroll
            for (int m = 1; m <= 32; m <<= 1) { s1 += __shfl_xor(s1, m, 64); s2 += __shfl_xor(s2, m, 64); }
            if (lane == o) sel1 = s1;
            if (lane == o + 32) sel2 = s2;
        }
        atomicAdd(&stats[lane], lane < 32 ? sel1 : sel2);
    }
}

__global__ __launch_bounds__(256, 4) void conv_x3(
    const float* __restrict__ src, const int* __restrict__ nbrT,
    const float* __restrict__ W, u16* __restrict__ out,
    float* __restrict__ stats, int M)
{
    constexpr int K = 27;
    int lane = threadIdx.x & 63;
    int wid = __builtin_amdgcn_readfirstlane(threadIdx.x >> 6);
    int p = blockIdx.x * 64 + lane;
    bool act = p < M;
    constexpr int JMAX = 7;

    float acc[32];
#pragma unroll
    for (int o = 0; o < 32; ++o) acc[o] = 0.f;

    int idxs[JMAX];
#pragma unroll
    for (int j = 0; j < JMAX; ++j) {
        int k = wid + 4 * j;
        idxs[j] = (act && k < K) ? nbrT[(size_t)k * M + p] : -1;
    }
#pragma unroll
    for (int j = 0; j < JMAX; ++j) {
        int k = wid + 4 * j;
        if (k >= K) break;
        int idx = idxs[j];
        if (idx >= 0) {
            const float* __restrict__ xr = src + (size_t)idx * 3;
            const float* __restrict__ wk = W + (size_t)k * 3 * 32;
            float x0 = xr[0], x1 = xr[1], x2 = xr[2];
#pragma unroll
            for (int o = 0; o < 32; ++o) {
                float s = fmaf(x0, wk[o], 0.f);
                s = fmaf(x1, wk[32 + o], s);
                acc[o] += fmaf(x2, wk[64 + o], s);
            }
        }
    }
    reduce_store_stats(acc, lane, wid, act, p, out, stats);
}

// ---------------- ds 1x1 conv from two 32-ch sources (u_bn, x0); fp32 W wave-uniform ----------------
__global__ __launch_bounds__(256, 4) void conv_ds2(
    const u16* __restrict__ u, const u16* __restrict__ x0,
    const float* __restrict__ W, u16* __restrict__ out,
    float* __restrict__ stats, int M)
{
    int lane = threadIdx.x & 63;
    int wid = __builtin_amdgcn_readfirstlane(threadIdx.x >> 6);
    int p = blockIdx.x * 64 + lane;
    bool act = p < M;

    float acc[32];
#pragma unroll
    for (int o = 0; o < 32; ++o) acc[o] = 0.f;

    if (act) {
        const u16* srcp = (wid < 2) ? u : x0;
        const uint4* xr = reinterpret_cast<const uint4*>(srcp + (size_t)p * 32 + (wid & 1) * 16);
        const float* wk = W + (size_t)wid * 16 * 32;   // wave-uniform -> scalar loads
#pragma unroll
        for (int h = 0; h < 2; ++h) {
            uint4 v = xr[h];
            float xv[8] = { bflo(v.x), bfhi(v.x), bflo(v.y), bfhi(v.y),
                            bflo(v.z), bfhi(v.z), bflo(v.w), bfhi(v.w) };
#pragma unroll
            for (int c = 0; c < 8; ++c)
#pragma unroll
                for (int o = 0; o < 32; ++o)
                    acc[o] = fmaf(xv[c], wk[(h * 8 + c) * 32 + o], acc[o]);
        }
    }
    reduce_store_stats(acc, lane, wid, act, p, out, stats);
}

// ---------------- bn apply in place on bf16 (thread = 8 channels) ----------------
template<bool RELU>
__global__ __launch_bounds__(256) void bn_apply(
    u16* __restrict__ buf, const float* __restrict__ stats,
    const float* __restrict__ gb, float invM, int total)
{
    int i = blockIdx.x * 256 + threadIdx.x;
    if (i >= total) return;
    int c0 = (i & 3) * 8;
    uint4 v = reinterpret_cast<uint4*>(buf)[i];
    u32 w[4] = { v.x, v.y, v.z, v.w };
    u32 r[4];
#pragma unroll
    for (int q = 0; q < 4; ++q) {
        int c = c0 + 2 * q;
        float mu0 = stats[c] * invM;
        float var0 = fmaxf(stats[32 + c] * invM - mu0 * mu0, 0.f);
        float a0 = gb[c] * rsqrtf(var0 + 1e-5f), b0 = gb[32 + c] - mu0 * a0;
        float mu1 = stats[c + 1] * invM;
        float var1 = fmaxf(stats[32 + c + 1] * invM - mu1 * mu1, 0.f);
        float a1 = gb[c + 1] * rsqrtf(var1 + 1e-5f), b1 = gb[32 + c + 1] - mu1 * a1;
        float y0 = fmaf(a0, bflo(w[q]), b0);
        float y1 = fmaf(a1, bfhi(w[q]), b1);
        if (RELU) { y0 = fmaxf(y0, 0.f); y1 = fmaxf(y1, 0.f); }
        r[q] = pack2(y0, y1);
    }
    uint4 o; o.x = r[0]; o.y = r[1]; o.z = r[2]; o.w = r[3];
    reinterpret_cast<uint4*>(buf)[i] = o;
}

// ---------------- attention ----------------
__device__ __forceinline__ void load_row32(const u16* __restrict__ base, int p, float (&nv)[32])
{
    const uint4* xr = reinterpret_cast<const uint4*>(base + (size_t)p * 32);
#pragma unroll
    for (int q = 0; q < 4; ++q) {
        uint4 v = xr[q];
        nv[q * 8 + 0] = bflo(v.x); nv[q * 8 + 1] = bfhi(v.x);
        nv[q * 8 + 2] = bflo(v.y); nv[q * 8 + 3] = bfhi(v.y);
        nv[q * 8 + 4] = bflo(v.z); nv[q * 8 + 5] = bfhi(v.z);
        nv[q * 8 + 6] = bflo(v.w); nv[q * 8 + 7] = bfhi(v.w);
    }
}

__global__ __launch_bounds__(256) void att_logits(
    const u16* __restrict__ net, const float* __restrict__ wi,
    const float* __restrict__ bi, float* __restrict__ lbuf,
    u32* __restrict__ mx, int M)
{
    int p = blockIdx.x * 256 + threadIdx.x;
    float l = -3.0e38f;
    if (p < M) {
        float nv[32];
        load_row32(net, p, nv);
        float s = bi[0];
#pragma unroll
        for (int c = 0; c < 32; ++c) s = fmaf(nv[c], wi[c], s);
        lbuf[p] = s;
        l = s;
    }
#pragma unroll
    for (int m = 1; m <= 32; m <<= 1) l = fmaxf(l, __shfl_xor(l, m, 64));
    if ((threadIdx.x & 63) == 0) {
        u32 b = __float_as_uint(l);
        u32 e = (b & 0x80000000u) ? ~b : (b | 0x80000000u);
        atomicMax(mx, e);
    }
}

__global__ __launch_bounds__(256) void att_accum(
    const u16* __restrict__ net, const float* __restrict__ lbuf,
    float* __restrict__ att, int M)
{
    int p = blockIdx.x * 256 + threadIdx.x;
    int lane = threadIdx.x & 63, wid = threadIdx.x >> 6;
    u32 um = __float_as_uint(att[0]);
    float mx = (um & 0x80000000u) ? __uint_as_float(um ^ 0x80000000u) : __uint_as_float(~um);
    float w = 0.f;
    float nv[32];
#pragma unroll
    for (int c = 0; c < 32; ++c) nv[c] = 0.f;
    if (p < M) {
        w = expf(lbuf[p] - mx);
        load_row32(net, p, nv);
    }
    float sel = 0.f;
#pragma unroll
    for (int c = 0; c < 32; ++c) {
        float s = w * nv[c];
#pragma unroll
        for (int m = 1; m <= 32; m <<= 1) s += __shfl_xor(s, m, 64);
        if (lane == c) sel = s;
    }
    {
        float s = w;
#pragma unroll
        for (int m = 1; m <= 32; m <<= 1) s += __shfl_xor(s, m, 64);
        if (lane == 32) sel = s;
    }
    __shared__ float red[4][33];
    if (lane < 33) red[wid][lane] = sel;
    __syncthreads();
    if (wid == 0 && lane < 33) {
        float t = red[0][lane] + red[1][lane] + red[2][lane] + red[3][lane];
        atomicAdd(lane < 32 ? &att[2 + lane] : &att[1], t);
    }
}

__global__ void att_ctx_k(const float* __restrict__ wk, const float* __restrict__ bk,
                          float* __restrict__ att)
{
    int o = threadIdx.x;
    if (o >= 32) return;
    float invS = 1.0f / att[1];
    float s = bk[o];
#pragma unroll
    for (int c = 0; c < 32; ++c) s = fmaf(att[2 + c] * invS, wk[c * 32 + o], s);
    att[34 + o] = s;
}

__global__ __launch_bounds__(256) void att_out_res(
    const u16* __restrict__ net, const u16* __restrict__ d,
    const float* __restrict__ wv, const float* __restrict__ bv,
    const float* __restrict__ wo, const float* __restrict__ bo,
    const float* __restrict__ att, u16* __restrict__ r, int M)
{
    int p = blockIdx.x * 256 + threadIdx.x;
    if (p >= M) return;
    float nv[32];
    load_row32(net, p, nv);
    float vv[32];
#pragma unroll
    for (int o = 0; o < 32; ++o) {
        float s = bv[o];
#pragma unroll
        for (int c = 0; c < 32; ++c) s = fmaf(nv[c], wv[c * 32 + o], s);
        vv[o] = s * att[34 + o];
    }
    float dv[32];
    load_row32(d, p, dv);
    u32 wd[16];
#pragma unroll
    for (int q = 0; q < 16; ++q) {
        float y[2];
#pragma unroll
        for (int t = 0; t < 2; ++t) {
            int oo = 2 * q + t;
            float s = bo[oo];
#pragma unroll
            for (int o = 0; o < 32; ++o) s = fmaf(vv[o], wo[o * 32 + oo], s);
            y[t] = fmaxf(s + dv[oo], 0.f);
        }
        wd[q] = pack2(y[0], y[1]);
    }
    uint4* dst = reinterpret_cast<uint4*>(r + (size_t)p * 32);
    uint4 v;
    v.x = wd[0];  v.y = wd[1];  v.z = wd[2];  v.w = wd[3];  dst[0] = v;
    v.x = wd[4];  v.y = wd[5];  v.z = wd[6];  v.w = wd[7];  dst[1] = v;
    v.x = wd[8];  v.y = wd[9];  v.z = wd[10]; v.w = wd[11]; dst[2] = v;
    v.x = wd[12]; v.y = wd[13]; v.z = wd[14]; v.w = wd[15]; dst[3] = v;
}

// ---------------- final: y = relu(bn(net2) + bn(ds)); out = y@Wcls + bcls ----------------
__global__ __launch_bounds__(256) void final_cls(
    const u16* __restrict__ net2, const u16* __restrict__ dsr,
    const float* __restrict__ st7, const float* __restrict__ st8,
    const float* __restrict__ gb7, const float* __restrict__ gb8,
    const float* __restrict__ wcls, const float* __restrict__ bcls,
    float* __restrict__ outp, float invM, int M)
{
    int p = blockIdx.x * 256 + threadIdx.x;
    if (p >= M) return;
    float nv[32], dv[32];
    load_row32(net2, p, nv);
    load_row32(dsr, p, dv);
    float y[32];
#pragma unroll
    for (int c = 0; c < 32; ++c) {
        float mu1 = st7[c] * invM;
        float var1 = fmaxf(st7[32 + c] * invM - mu1 * mu1, 0.f);
        float a1 = gb7[c] * rsqrtf(var1 + 1e-5f);
        float b1 = gb7[32 + c] - mu1 * a1;
        float mu2 = st8[c] * invM;
        float var2 = fmaxf(st8[32 + c] * invM - mu2 * mu2, 0.f);
        float a2 = gb8[c] * rsqrtf(var2 + 1e-5f);
        float b2 = gb8[32 + c] - mu2 * a2;
        float t = fmaf(a1, nv[c], b1) + fmaf(a2, dv[c], b2);
        y[c] = fmaxf(t, 0.f);
    }
#pragma unroll
    for (int j = 0; j < NCLSS; ++j) {
        float s = bcls[j];
#pragma unroll
        for (int c = 0; c < 32; ++c) s = fmaf(y[c], wcls[c * NCLSS + j], s);
        outp[(size_t)p * NCLSS + j] = s;
    }
}

// ---------------- host ----------------
extern "C" void kernel_launch(void* const* d_in, const int* in_sizes, int n_in,
                              void* d_out, int out_size, void* d_ws, size_t ws_size,
                              hipStream_t stream)
{
    char* wsb = (char*)d_ws;

    float* ST  = (float*)wsb;                          // 642 floats
    float* ATT = ST + 576;
    float* L   = (float*)(wsb + 4096);                 // N1 logits fp32
    u16* A = (u16*)(wsb + 65536);                      // N*32 bf16
    u16* B = (u16*)(wsb + 65536 + 7680000ull);
    u16* C = (u16*)(wsb + 65536 + 2 * 7680000ull);
    u16* D = (u16*)(wsb + 65536 + 2 * 7680000ull + 960000ull);
    u16* E = (u16*)(wsb + 65536 + 2 * 7680000ull + 2 * 960000ull);
    float* T = (float*)(wsb + 65536 + 2 * 7680000ull + 3 * 960000ull);        // N*32 fp32
    u16* G = (u16*)(wsb + 65536 + 2 * 7680000ull + 3 * 960000ull + 15360000ull);

    // packed weight buffers (pad K to even)
    size_t wboff = 65536 + 2 * 7680000ull + 3 * 960000ull + 15360000ull + 7680000ull;
    auto wbsz = [](int K) { return (size_t)((K + 1) & ~1) * 4096; };
    uint4* wb_stem1 = (uint4*)(wsb + wboff);           size_t o1 = wboff + wbsz(27);
    uint4* wb_down  = (uint4*)(wsb + o1);              size_t o2 = o1 + wbsz(8);
    uint4* wb_res1  = (uint4*)(wsb + o2);              size_t o3 = o2 + wbsz(27);
    uint4* wb_res2  = (uint4*)(wsb + o3);              size_t o4 = o3 + wbsz(27);
    uint4* wb_up    = (uint4*)(wsb + o4);              size_t o5 = o4 + wbsz(8);
    uint4* wb_f1A   = (uint4*)(wsb + o5);              size_t o6 = o5 + wbsz(27);
    uint4* wb_f1B   = (uint4*)(wsb + o6);              size_t o7 = o6 + wbsz(27);
    uint4* wb_fuse2 = (uint4*)(wsb + o7);              size_t o8 = o7 + wbsz(27);

    int* nbrT0 = (int*)(wsb + o8);                     size_t o9  = o8 + 27ull * NPTS * 4;
    int* nbrTd = (int*)(wsb + o9);                     size_t o10 = o9 + 8ull * N1PTS * 4;
    int* nbrT1 = (int*)(wsb + o10);                    size_t o11 = o10 + 27ull * N1PTS * 4;
    int* nbrTu = (int*)(wsb + o11);

    const float* X        = (const float*)d_in[0];
    const float* Wstem0   = (const float*)d_in[1];
    const float* gb_stem0 = (const float*)d_in[2];
    const float* Wstem1   = (const float*)d_in[3];
    const float* gb_stem1 = (const float*)d_in[4];
    const float* Wdown    = (const float*)d_in[5];
    const float* gb_down  = (const float*)d_in[6];
    const float* Wres1    = (const float*)d_in[7];
    const float* gb_res1  = (const float*)d_in[8];
    const float* Wres2    = (const float*)d_in[9];
    const float* gb_res2  = (const float*)d_in[10];
    const float* wi = (const float*)d_in[11];
    const float* bi = (const float*)d_in[12];
    const float* wk = (const float*)d_in[13];
    const float* bk = (const float*)d_in[14];
    const float* wv = (const float*)d_in[15];
    const float* bv = (const float*)d_in[16];
    const float* wo = (const float*)d_in[17];
    const float* bo = (const float*)d_in[18];
    const float* Wup      = (const float*)d_in[19];
    const float* gb_up    = (const float*)d_in[20];
    const float* Wfuse1   = (const float*)d_in[21];
    const float* gb_fuse1 = (const float*)d_in[22];
    const float* Wfuse2   = (const float*)d_in[23];
    const float* gb_fuse2 = (const float*)d_in[24];
    const float* Wds      = (const float*)d_in[25];
    const float* gb_ds    = (const float*)d_in[26];
    const float* Wcls     = (const float*)d_in[27];
    const float* bcls     = (const float*)d_in[28];

    const int* nbr0     = (const int*)d_in[29];
    const int* nbr_down = (const int*)d_in[30];
    const int* nbr1     = (const int*)d_in[31];
    const int* nbr_up   = (const int*)d_in[32];

    const float invN  = 1.0f / (float)NPTS;
    const float invN1 = 1.0f / (float)N1PTS;

    hipMemsetAsync((void*)ST, 0, 642 * sizeof(float), stream);

    hipLaunchKernelGGL((transpose_nbr<27>), dim3(cdiv(NPTS, 256)), dim3(256), 0, stream,
                       nbr0, nbrT0, NPTS);
    hipLaunchKernelGGL((transpose_nbr<8>), dim3(cdiv(N1PTS, 256)), dim3(256), 0, stream,
                       nbr_down, nbrTd, N1PTS);
    hipLaunchKernelGGL((transpose_nbr<27>), dim3(cdiv(N1PTS, 256)), dim3(256), 0, stream,
                       nbr1, nbrT1, N1PTS);
    hipLaunchKernelGGL((transpose_nbr<8>), dim3(cdiv(NPTS, 256)), dim3(256), 0, stream,
                       nbr_up, nbrTu, NPTS);

    {
        WbArgs a;
        a.src[0] = Wstem1; a.dst[0] = wb_stem1; a.CINF[0] = 32; a.COFF[0] = 0;  a.K2[0] = 54;
        a.src[1] = Wdown;  a.dst[1] = wb_down;  a.CINF[1] = 32; a.COFF[1] = 0;  a.K2[1] = 16;
        a.src[2] = Wres1;  a.dst[2] = wb_res1;  a.CINF[2] = 32; a.COFF[2] = 0;  a.K2[2] = 54;
        a.src[3] = Wres2;  a.dst[3] = wb_res2;  a.CINF[3] = 32; a.COFF[3] = 0;  a.K2[3] = 54;
        a.src[4] = Wup;    a.dst[4] = wb_up;    a.CINF[4] = 32; a.COFF[4] = 0;  a.K2[4] = 16;
        a.src[5] = Wfuse1; a.dst[5] = wb_f1A;   a.CINF[5] = 64; a.COFF[5] = 0;  a.K2[5] = 54;
        a.src[6] = Wfuse1; a.dst[6] = wb_f1B;   a.CINF[6] = 64; a.COFF[6] = 32; a.K2[6] = 54;
        a.src[7] = Wfuse2; a.dst[7] = wb_fuse2; a.CINF[7] = 32; a.COFF[7] = 0;  a.K2[7] = 54;
        hipLaunchKernelGGL(convert_wb, dim3(54, 8), dim3(64), 0, stream, a);
    }

    const int gS   = cdiv(NPTS, 64);     // 1875 (conv_x3, conv_ds2)
    const int gB   = cdiv(NPTS, 256);    // 469 (conv_blk)
    const int gM1  = cdiv(N1PTS, 64);    // 235 (conv_mfma N1)
    const int gBN  = cdiv(NPTS * 4, 256);
    const int gBN1 = cdiv(N1PTS * 4, 256);
    const int gN1p = cdiv(N1PTS, 256);
    const int gN   = cdiv(NPTS, 256);

    // stem
    hipLaunchKernelGGL(conv_x3, dim3(gS), dim3(256), 0, stream,
                       X, nbrT0, Wstem0, A, ST + 0 * 64, NPTS);
    hipLaunchKernelGGL((bn_apply<true>), dim3(gBN), dim3(256), 0, stream,
                       A, ST + 0 * 64, gb_stem0, invN, NPTS * 4);
    hipLaunchKernelGGL((conv_blk<27, 0>), dim3(gB), dim3(1024), 0, stream,
                       A, nbrT0, wb_stem1, B, (float*)nullptr, ST + 1 * 64, NPTS);
    hipLaunchKernelGGL((bn_apply<true>), dim3(gBN), dim3(256), 0, stream,
                       B, ST + 1 * 64, gb_stem1, invN, NPTS * 4);   // B = x0

    // downsample
    hipLaunchKernelGGL((conv_mfma<8>), dim3(gM1), dim3(256), 0, stream,
                       B, nbrTd, wb_down, C, ST + 2 * 64, N1PTS);
    hipLaunchKernelGGL((bn_apply<true>), dim3(gBN1), dim3(256), 0, stream,
                       C, ST + 2 * 64, gb_down, invN1, N1PTS * 4);  // C = d

    // residual block convs
    hipLaunchKernelGGL((conv_mfma<27>), dim3(gM1), dim3(256), 0, stream,
                       C, nbrT1, wb_res1, D, ST + 3 * 64, N1PTS);
    hipLaunchKernelGGL((bn_apply<true>), dim3(gBN1), dim3(256), 0, stream,
                       D, ST + 3 * 64, gb_res1, invN1, N1PTS * 4);
    hipLaunchKernelGGL((conv_mfma<27>), dim3(gM1), dim3(256), 0, stream,
                       D, nbrT1, wb_res2, E, ST + 4 * 64, N1PTS);
    hipLaunchKernelGGL((bn_apply<false>), dim3(gBN1), dim3(256), 0, stream,
                       E, ST + 4 * 64, gb_res2, invN1, N1PTS * 4);  // E = net

    // attention + residual add (writes r into D)
    hipLaunchKernelGGL(att_logits, dim3(gN1p), dim3(256), 0, stream,
                       E, wi, bi, L, (u32*)ATT, N1PTS);
    hipLaunchKernelGGL(att_accum, dim3(gN1p), dim3(256), 0, stream, E, L, ATT, N1PTS);
    hipLaunchKernelGGL(att_ctx_k, dim3(1), dim3(64), 0, stream, wk, bk, ATT);
    hipLaunchKernelGGL(att_out_res, dim3(gN1p), dim3(256), 0, stream,
                       E, C, wv, bv, wo, bo, ATT, D, N1PTS);        // D = r

    // upsample
    hipLaunchKernelGGL((conv_blk<8, 0>), dim3(gB), dim3(1024), 0, stream,
                       D, nbrTu, wb_up, A, (float*)nullptr, ST + 5 * 64, NPTS);
    hipLaunchKernelGGL((bn_apply<true>), dim3(gBN), dim3(256), 0, stream,
                       A, ST + 5 * 64, gb_up, invN, NPTS * 4);      // A = u_bn

    // fuse residual block, cat never materialized:
    // passA: u_bn half of fuse1 -> T (fp32)
    hipLaunchKernelGGL((conv_blk<27, 1>), dim3(gB), dim3(1024), 0, stream,
                       A, nbrT0, wb_f1A, (u16*)nullptr, T, (float*)nullptr, NPTS);
    // ds shortcut from (u_bn, x0) -> G
    hipLaunchKernelGGL(conv_ds2, dim3(gS), dim3(256), 0, stream,
                       A, B, Wds, G, ST + 8 * 64, NPTS);
    // passB: x0 half, accumulate onto T, emit bf16 fuse1 raw -> A
    hipLaunchKernelGGL((conv_blk<27, 2>), dim3(gB), dim3(1024), 0, stream,
                       B, nbrT0, wb_f1B, A, T, ST + 6 * 64, NPTS);
    hipLaunchKernelGGL((bn_apply<true>), dim3(gBN), dim3(256), 0, stream,
                       A, ST + 6 * 64, gb_fuse1, invN, NPTS * 4);
    // fuse2 -> B (net2 raw)
    hipLaunchKernelGGL((conv_blk<27, 0>), dim3(gB), dim3(1024), 0, stream,
                       A, nbrT0, wb_fuse2, B, (float*)nullptr, ST + 7 * 64, NPTS);

    // final fuse + classifier
    hipLaunchKernelGGL(final_cls, dim3(gN), dim3(256), 0, stream,
                       B, G, ST + 7 * 64, ST + 8 * 64, gb_fuse2, gb_ds,
                       Wcls, bcls, (float*)d_out, invN, NPTS);
}

// Round 11
// 506.658 us; speedup vs baseline: 1.1231x; 1.0129x over previous
//
#include <hip/hip_runtime.h>

typedef unsigned int u32;
typedef unsigned short u16;

#define NPTS 120000
#define N1PTS 15000
#define NCLSS 17
#define NSTRIPE 16

static inline int cdiv(int a, int b) { return (a + b - 1) / b; }

typedef __attribute__((ext_vector_type(8))) short bf16x8;
typedef __attribute__((ext_vector_type(4))) float f32x4;

// bf16 helpers (storage-only bf16; math fp32)
__device__ __forceinline__ float bflo(u32 u) { return __uint_as_float(u << 16); }
__device__ __forceinline__ float bfhi(u32 u) { return __uint_as_float(u & 0xFFFF0000u); }
__device__ __forceinline__ u32 f2bf(float f) {   // RNE
    u32 u = __float_as_uint(f);
    return (u + 0x7FFFu + ((u >> 16) & 1u)) >> 16;
}
__device__ __forceinline__ u32 pack2(float a, float b) { return f2bf(a) | (f2bf(b) << 16); }

__device__ __forceinline__ f32x4 mfma16(bf16x8 a, uint4 b, f32x4 c) {
    return __builtin_amdgcn_mfma_f32_16x16x32_bf16(a, __builtin_bit_cast(bf16x8, b), c, 0, 0, 0);
}

// ---------------- nbr transpose: nbrT[k*M + p] = nbr[p*K + k] ----------------
template<int K>
__global__ __launch_bounds__(256) void transpose_nbr(
    const int* __restrict__ nbr, int* __restrict__ nbrT, int M)
{
    __shared__ int tile[256][K + 1];
    int p0 = blockIdx.x * 256;
    int t = threadIdx.x;
    int np = M - p0; if (np > 256) np = 256;
    int total = np * K;
    for (int i = t; i < total; i += 256) {
        int lp = i / K, k = i - lp * K;
        tile[lp][k] = nbr[(size_t)p0 * K + i];
    }
    __syncthreads();
    if (t < np) {
#pragma unroll
        for (int k = 0; k < K; ++k)
            nbrT[(size_t)k * M + p0 + t] = tile[t][k];
    }
}

// ---------------- weight -> B-fragment conversion (hi/lo bf16 split) ----------------
struct WbArgs {
    const float* src[8];
    uint4* dst[8];
    int CINF[8];
    int COFF[8];
    int K2[8];    // 2*K
};

__global__ __launch_bounds__(64) void convert_wb(WbArgs a) {
    int j = blockIdx.y;
    int s2 = blockIdx.x;
    if (s2 >= a.K2[j]) return;
    int lane = threadIdx.x;
    int k = s2 >> 1, tile = s2 & 1;
    int c = a.COFF[j] + (lane >> 4) * 8;
    int o = tile * 16 + (lane & 15);
    const float* w = a.src[j] + ((size_t)k * a.CINF[j] + c) * 32 + o;
    u32 hw[4], lw[4];
#pragma unroll
    for (int q = 0; q < 4; ++q) {
        float w0 = w[(2 * q) * 32], w1 = w[(2 * q + 1) * 32];
        u32 h0 = f2bf(w0), h1 = f2bf(w1);
        float r0 = w0 - __uint_as_float(h0 << 16);
        float r1 = w1 - __uint_as_float(h1 << 16);
        hw[q] = h0 | (h1 << 16);
        lw[q] = f2bf(r0) | (f2bf(r1) << 16);
    }
    uint4 hv; hv.x = hw[0]; hv.y = hw[1]; hv.z = hw[2]; hv.w = hw[3];
    uint4 lv; lv.x = lw[0]; lv.y = lw[1]; lv.z = lw[2]; lv.w = lw[3];
    a.dst[j][(size_t)(s2 * 2 + 0) * 64 + lane] = hv;
    a.dst[j][(size_t)(s2 * 2 + 1) * 64 + lane] = lv;
}

// ---------------- conv_blk: 16-wave block, weights+idx in LDS, phased L2-resident gathers ----------
// CIN = 32. MODE 0: bf16 out + stats; MODE 1: fp32 out (no stats); MODE 2: fp32 in, bf16 out + stats.
// NPH phases over source row ranges so the gather working set fits per-XCD L2.
template<int K, int MODE, int NPH>
__global__ __launch_bounds__(1024, 4) void conv_blk(
    const u16* __restrict__ src, const int* __restrict__ nbrT,
    const uint4* __restrict__ wb, u16* __restrict__ out,
    float* __restrict__ outf, float* __restrict__ stats, int M, int Msrc)
{
    __shared__ uint4 wl[K * 256];
    __shared__ int il[K * 256];
    __shared__ float red[15][64];
    int tid = threadIdx.x;
    int lane = tid & 63, wid = tid >> 6;
    int p0 = blockIdx.x * 256 + wid * 16;
    int row = lane & 15, hi4 = lane >> 4;
    int lpt = wid * 16 + row;
    const uint4 z4 = {0u, 0u, 0u, 0u};

    // stage weights + nbr tile (coalesced, once)
    for (int i = tid; i < K * 256; i += 1024) wl[i] = wb[i];
    for (int i = tid; i < K * 256; i += 1024) {
        int k = i >> 8, pl = i & 255;
        int pp = blockIdx.x * 256 + pl;
        il[i] = (pp < M) ? nbrT[(size_t)k * M + pp] : -1;
    }

    f32x4 acc0, acc1;
    if (MODE == 2) {
#pragma unroll
        for (int r = 0; r < 4; ++r) {
            int pp = p0 + hi4 * 4 + r;
            int ps = pp < M ? pp : 0;
            acc0[r] = outf[(size_t)ps * 32 + (lane & 15)];
            acc1[r] = outf[(size_t)ps * 32 + 16 + (lane & 15)];
        }
    } else {
        acc0 = {0.f, 0.f, 0.f, 0.f};
        acc1 = {0.f, 0.f, 0.f, 0.f};
    }

    __syncthreads();

    const int HALF = (Msrc + NPH - 1) / NPH;

    auto gld = [&](int k, int lo, int hi) -> uint4 {
        int idx = il[(k << 8) + lpt];
        uint4 r = z4;
        if (idx >= lo && idx < hi)
            r = reinterpret_cast<const uint4*>(src + (size_t)idx * 32)[hi4];
        return r;
    };

#pragma unroll 1
    for (int ph = 0; ph < NPH; ++ph) {
        int lo = ph * HALF, hi = lo + HALF;
        uint4 g0 = gld(0, lo, hi);
        uint4 g1 = (K > 1) ? gld(1, lo, hi) : z4;
#pragma unroll 1
        for (int k = 0; k < K; ++k) {
            uint4 gn = (k + 2 < K) ? gld(k + 2, lo, hi) : z4;
            const uint4* bl = &wl[k * 256];
            bf16x8 a = __builtin_bit_cast(bf16x8, g0);
            acc0 = mfma16(a, bl[lane], acc0);
            acc0 = mfma16(a, bl[64 + lane], acc0);
            acc1 = mfma16(a, bl[128 + lane], acc1);
            acc1 = mfma16(a, bl[192 + lane], acc1);
            g0 = g1; g1 = gn;
        }
    }

    if (MODE == 1) {
#pragma unroll
        for (int r = 0; r < 4; ++r) {
            int pp = p0 + hi4 * 4 + r;
            if (pp < M) {
                outf[(size_t)pp * 32 + (lane & 15)] = acc0[r];
                outf[(size_t)pp * 32 + 16 + (lane & 15)] = acc1[r];
            }
        }
        return;
    }

    // bf16 store
#pragma unroll
    for (int r = 0; r < 4; ++r) {
        int pp = p0 + hi4 * 4 + r;
        if (pp < M) {
            out[(size_t)pp * 32 + (lane & 15)] = (u16)f2bf(acc0[r]);
            out[(size_t)pp * 32 + 16 + (lane & 15)] = (u16)f2bf(acc1[r]);
        }
    }

    // bn stats (striped atomics)
    float s0 = 0.f, q0 = 0.f, s1 = 0.f, q1 = 0.f;
#pragma unroll
    for (int r = 0; r < 4; ++r) {
        s0 += acc0[r]; q0 += acc0[r] * acc0[r];
        s1 += acc1[r]; q1 += acc1[r] * acc1[r];
    }
#pragma unroll
    for (int m = 16; m <= 32; m <<= 1) {
        s0 += __shfl_xor(s0, m, 64); q0 += __shfl_xor(q0, m, 64);
        s1 += __shfl_xor(s1, m, 64); q1 += __shfl_xor(q1, m, 64);
    }
    float val = (lane < 16) ? s0 : (lane < 32) ? s1 : (lane < 48) ? q0 : q1;
    if (wid > 0) red[wid - 1][lane] = val;
    __syncthreads();
    if (wid == 0) {
        float t = val;
#pragma unroll
        for (int w = 0; w < 15; ++w) t += red[w][lane];
        atomicAdd(&stats[((blockIdx.x & (NSTRIPE - 1)) << 6) + lane], t);
    }
}

// ---------------- conv_mfma: 4-wave version for small N1 grids ----------------
template<int K>
__global__ __launch_bounds__(256, 6) void conv_mfma(
    const u16* __restrict__ src, const int* __restrict__ nbrT,
    const uint4* __restrict__ wb, u16* __restrict__ out,
    float* __restrict__ stats, int M)
{
    constexpr int KS = K;
    constexpr int NCH = (KS + 1) / 2;
    __shared__ uint4 wlds[2][512];
    __shared__ float red[4][64];

    int tid = threadIdx.x;
    int lane = tid & 63, wid = tid >> 6;
    int p0 = blockIdx.x * 64 + wid * 16;
    int row = lane & 15, hi4 = lane >> 4;
    int p = p0 + row;
    bool rowok = p < M;
    const uint4 z4 = {0u, 0u, 0u, 0u};

    f32x4 acc0 = {0.f, 0.f, 0.f, 0.f};
    f32x4 acc1 = {0.f, 0.f, 0.f, 0.f};

    {
        uint4 a0 = wb[tid], a1 = wb[256 + tid];
        wlds[0][tid] = a0; wlds[0][256 + tid] = a1;
    }
    uint4 av0 = z4, av1 = z4;
    {
        int iA = -1, iB = -1;
        if (rowok) {
            iA = nbrT[p];
            if (KS > 1) iB = nbrT[(size_t)M + p];
        }
        if (iA >= 0) av0 = reinterpret_cast<const uint4*>(src + (size_t)iA * 32)[hi4];
        if (KS > 1 && iB >= 0) av1 = reinterpret_cast<const uint4*>(src + (size_t)iB * 32)[hi4];
    }

    uint4 wr0 = z4, wr1 = z4;
#pragma unroll 1
    for (int c = 0; c < NCH; ++c) {
        bool last = (c + 1 >= NCH);
        if (!last) {
            wr0 = wb[(size_t)(c + 1) * 512 + tid];
            wr1 = wb[(size_t)(c + 1) * 512 + 256 + tid];
        }
        int nA = -1, nB = -1;
        if (!last && rowok) {
            int s0 = 2 * c + 2;
            nA = nbrT[(size_t)s0 * M + p];
            if (s0 + 1 < KS) nB = nbrT[(size_t)(s0 + 1) * M + p];
        }
        asm volatile("s_waitcnt lgkmcnt(0)" ::: "memory");
        __builtin_amdgcn_s_barrier();
        asm volatile("" ::: "memory");
        uint4 nav0 = z4, nav1 = z4;
        if (nA >= 0) nav0 = reinterpret_cast<const uint4*>(src + (size_t)nA * 32)[hi4];
        if (nB >= 0) nav1 = reinterpret_cast<const uint4*>(src + (size_t)nB * 32)[hi4];

        const uint4* bl = wlds[c & 1];
        {
            bf16x8 a = __builtin_bit_cast(bf16x8, av0);
            acc0 = mfma16(a, bl[lane], acc0);
            acc0 = mfma16(a, bl[64 + lane], acc0);
            acc1 = mfma16(a, bl[128 + lane], acc1);
            acc1 = mfma16(a, bl[192 + lane], acc1);
        }
        if (2 * c + 1 < KS) {
            bf16x8 a = __builtin_bit_cast(bf16x8, av1);
            acc0 = mfma16(a, bl[256 + lane], acc0);
            acc0 = mfma16(a, bl[320 + lane], acc0);
            acc1 = mfma16(a, bl[384 + lane], acc1);
            acc1 = mfma16(a, bl[448 + lane], acc1);
        }
        if (!last) {
            wlds[(c + 1) & 1][tid] = wr0;
            wlds[(c + 1) & 1][256 + tid] = wr1;
        }
        av0 = nav0; av1 = nav1;
    }

#pragma unroll
    for (int r = 0; r < 4; ++r) {
        int pp = p0 + hi4 * 4 + r;
        if (pp < M) {
            out[(size_t)pp * 32 + (lane & 15)] = (u16)f2bf(acc0[r]);
            out[(size_t)pp * 32 + 16 + (lane & 15)] = (u16)f2bf(acc1[r]);
        }
    }

    float s0 = 0.f, q0 = 0.f, s1 = 0.f, q1 = 0.f;
#pragma unroll
    for (int r = 0; r < 4; ++r) {
        s0 += acc0[r]; q0 += acc0[r] * acc0[r];
        s1 += acc1[r]; q1 += acc1[r] * acc1[r];
    }
#pragma unroll
    for (int m = 16; m <= 32; m <<= 1) {
        s0 += __shfl_xor(s0, m, 64); q0 += __shfl_xor(q0, m, 64);
        s1 += __shfl_xor(s1, m, 64); q1 += __shfl_xor(q1, m, 64);
    }
    float val = (lane < 16) ? s0 : (lane < 32) ? s1 : (lane < 48) ? q0 : q1;
    red[wid][lane] = val;
    __syncthreads();
    if (wid == 0) {
        float t = red[0][lane] + red[1][lane] + red[2][lane] + red[3][lane];
        atomicAdd(&stats[((blockIdx.x & (NSTRIPE - 1)) << 6) + lane], t);
    }
}

// ---------------- shared scalar epilogue (conv_x3, conv_ds2) — striped stats ----------------
__device__ __forceinline__ void reduce_store_stats(
    float (&acc)[32], int lane, int wid, bool act, int p,
    u16* __restrict__ out, float* __restrict__ sst)
{
    __shared__ float lds[3][64][17];
#pragma unroll
    for (int r = 0; r < 2; ++r) {
        if (wid > 0) {
#pragma unroll
            for (int j = 0; j < 16; ++j) lds[wid - 1][lane][j] = acc[r * 16 + j];
        }
        __syncthreads();
        if (wid == 0) {
#pragma unroll
            for (int w = 0; w < 3; ++w)
#pragma unroll
                for (int j = 0; j < 16; ++j) acc[r * 16 + j] += lds[w][lane][j];
        }
        __syncthreads();
    }
    if (wid == 0) {
        if (act) {
            u32 wd[16];
#pragma unroll
            for (int q = 0; q < 16; ++q) wd[q] = pack2(acc[2 * q], acc[2 * q + 1]);
            uint4* dst = reinterpret_cast<uint4*>(out + (size_t)p * 32);
            uint4 v;
            v.x = wd[0];  v.y = wd[1];  v.z = wd[2];  v.w = wd[3];  dst[0] = v;
            v.x = wd[4];  v.y = wd[5];  v.z = wd[6];  v.w = wd[7];  dst[1] = v;
            v.x = wd[8];  v.y = wd[9];  v.z = wd[10]; v.w = wd[11]; dst[2] = v;
            v.x = wd[12]; v.y = wd[13]; v.z = wd[14]; v.w = wd[15]; dst[3] = v;
        } else {
#pragma unroll
            for (int o = 0; o < 32; ++o) acc[o] = 0.f;
        }
        float sel1 = 0.f, sel2 = 0.f;
#pragma unroll
        for (int o = 0; o < 32; ++o) {
            float s1 = acc[o], s2 = acc[o] * acc[o];
#pragma unroll
            for (int m = 1; m <= 32; m <<= 1) { s1 += __shfl_xor(s1, m, 64); s2 += __shfl_xor(s2, m, 64); }
            if (lane == o) sel1 = s1;
            if (lane == o + 32) sel2 = s2;
        }
        atomicAdd(&sst[lane], lane < 32 ? sel1 : sel2);
    }
}

__global__ __launch_bounds__(256, 4) void conv_x3(
    const float* __restrict__ src, const int* __restrict__ nbrT,
    const float* __restrict__ W, u16* __restrict__ out,
    float* __restrict__ stats, int M)
{
    constexpr int K = 27;
    int lane = threadIdx.x & 63;
    int wid = __builtin_amdgcn_readfirstlane(threadIdx.x >> 6);
    int p = blockIdx.x * 64 + lane;
    bool act = p < M;
    constexpr int JMAX = 7;

    float acc[32];
#pragma unroll
    for (int o = 0; o < 32; ++o) acc[o] = 0.f;

    int idxs[JMAX];
#pragma unroll
    for (int j = 0; j < JMAX; ++j) {
        int k = wid + 4 * j;
        idxs[j] = (act && k < K) ? nbrT[(size_t)k * M + p] : -1;
    }
#pragma unroll
    for (int j = 0; j < JMAX; ++j) {
        int k = wid + 4 * j;
        if (k >= K) break;
        int idx = idxs[j];
        if (idx >= 0) {
            const float* __restrict__ xr = src + (size_t)idx * 3;
            const float* __restrict__ wk = W + (size_t)k * 3 * 32;
            float x0 = xr[0], x1 = xr[1], x2 = xr[2];
#pragma unroll
            for (int o = 0; o < 32; ++o) {
                float s = fmaf(x0, wk[o], 0.f);
                s = fmaf(x1, wk[32 + o], s);
                acc[o] += fmaf(x2, wk[64 + o], s);
            }
        }
    }
    reduce_store_stats(acc, lane, wid, act, p, out,
                       stats + ((blockIdx.x & (NSTRIPE - 1)) << 6));
}

// ---------------- ds 1x1 conv from two 32-ch sources (u_bn, x0) ----------------
__global__ __launch_bounds__(256, 4) void conv_ds2(
    const u16* __restrict__ u, const u16* __restrict__ x0,
    const float* __restrict__ W, u16* __restrict__ out,
    float* __restrict__ stats, int M)
{
    int lane = threadIdx.x & 63;
    int wid = __builtin_amdgcn_readfirstlane(threadIdx.x >> 6);
    int p = blockIdx.x * 64 + lane;
    bool act = p < M;

    float acc[32];
#pragma unroll
    for (int o = 0; o < 32; ++o) acc[o] = 0.f;

    if (act) {
        const u16* srcp = (wid < 2) ? u : x0;
        const uint4* xr = reinterpret_cast<const uint4*>(srcp + (size_t)p * 32 + (wid & 1) * 16);
        const float* wk = W + (size_t)wid * 16 * 32;
#pragma unroll
        for (int h = 0; h < 2; ++h) {
            uint4 v = xr[h];
            float xv[8] = { bflo(v.x), bfhi(v.x), bflo(v.y), bfhi(v.y),
                            bflo(v.z), bfhi(v.z), bflo(v.w), bfhi(v.w) };
#pragma unroll
            for (int c = 0; c < 8; ++c)
#pragma unroll
                for (int o = 0; o < 32; ++o)
                    acc[o] = fmaf(xv[c], wk[(h * 8 + c) * 32 + o], acc[o]);
        }
    }
    reduce_store_stats(acc, lane, wid, act, p, out,
                       stats + ((blockIdx.x & (NSTRIPE - 1)) << 6));
}

// ---------------- bn apply: sums 16 stripes once per block, then y = a*x + b ----------------
template<bool RELU>
__global__ __launch_bounds__(256) void bn_apply(
    u16* __restrict__ buf, const float* __restrict__ stats,
    const float* __restrict__ gb, float invM, int total)
{
    __shared__ float ab[64];
    if (threadIdx.x < 32) {
        int c = threadIdx.x;
        float s = 0.f, q = 0.f;
#pragma unroll
        for (int st = 0; st < NSTRIPE; ++st) {
            s += stats[st * 64 + c];
            q += stats[st * 64 + 32 + c];
        }
        float mu = s * invM;
        float var = fmaxf(q * invM - mu * mu, 0.f);
        float a = gb[c] * rsqrtf(var + 1e-5f);
        ab[c] = a;
        ab[32 + c] = gb[32 + c] - mu * a;
    }
    __syncthreads();
    int i = blockIdx.x * 256 + threadIdx.x;
    if (i >= total) return;
    int c0 = (i & 3) * 8;
    uint4 v = reinterpret_cast<uint4*>(buf)[i];
    u32 w[4] = { v.x, v.y, v.z, v.w };
    u32 r[4];
#pragma unroll
    for (int q = 0; q < 4; ++q) {
        int c = c0 + 2 * q;
        float y0 = fmaf(ab[c], bflo(w[q]), ab[32 + c]);
        float y1 = fmaf(ab[c + 1], bfhi(w[q]), ab[32 + c + 1]);
        if (RELU) { y0 = fmaxf(y0, 0.f); y1 = fmaxf(y1, 0.f); }
        r[q] = pack2(y0, y1);
    }
    uint4 o; o.x = r[0]; o.y = r[1]; o.z = r[2]; o.w = r[3];
    reinterpret_cast<uint4*>(buf)[i] = o;
}

// ---------------- attention ----------------
__device__ __forceinline__ void load_row32(const u16* __restrict__ base, int p, float (&nv)[32])
{
    const uint4* xr = reinterpret_cast<const uint4*>(base + (size_t)p * 32);
#pragma unroll
    for (int q = 0; q < 4; ++q) {
        uint4 v = xr[q];
        nv[q * 8 + 0] = bflo(v.x); nv[q * 8 + 1] = bfhi(v.x);
        nv[q * 8 + 2] = bflo(v.y); nv[q * 8 + 3] = bfhi(v.y);
        nv[q * 8 + 4] = bflo(v.z); nv[q * 8 + 5] = bfhi(v.z);
        nv[q * 8 + 6] = bflo(v.w); nv[q * 8 + 7] = bfhi(v.w);
    }
}

__global__ __launch_bounds__(256) void att_logits(
    const u16* __restrict__ net, const float* __restrict__ wi,
    const float* __restrict__ bi, float* __restrict__ lbuf,
    u32* __restrict__ mx, int M)
{
    int p = blockIdx.x * 256 + threadIdx.x;
    float l = -3.0e38f;
    if (p < M) {
        float nv[32];
        load_row32(net, p, nv);
        float s = bi[0];
#pragma unroll
        for (int c = 0; c < 32; ++c) s = fmaf(nv[c], wi[c], s);
        lbuf[p] = s;
        l = s;
    }
#pragma unroll
    for (int m = 1; m <= 32; m <<= 1) l = fmaxf(l, __shfl_xor(l, m, 64));
    if ((threadIdx.x & 63) == 0) {
        u32 b = __float_as_uint(l);
        u32 e = (b & 0x80000000u) ? ~b : (b | 0x80000000u);
        atomicMax(mx, e);
    }
}

__global__ __launch_bounds__(256) void att_accum(
    const u16* __restrict__ net, const float* __restrict__ lbuf,
    float* __restrict__ att, int M)
{
    int p = blockIdx.x * 256 + threadIdx.x;
    int lane = threadIdx.x & 63, wid = threadIdx.x >> 6;
    u32 um = __float_as_uint(att[0]);
    float mx = (um & 0x80000000u) ? __uint_as_float(um ^ 0x80000000u) : __uint_as_float(~um);
    float w = 0.f;
    float nv[32];
#pragma unroll
    for (int c = 0; c < 32; ++c) nv[c] = 0.f;
    if (p < M) {
        w = expf(lbuf[p] - mx);
        load_row32(net, p, nv);
    }
    float sel = 0.f;
#pragma unroll
    for (int c = 0; c < 32; ++c) {
        float s = w * nv[c];
#pragma unroll
        for (int m = 1; m <= 32; m <<= 1) s += __shfl_xor(s, m, 64);
        if (lane == c) sel = s;
    }
    {
        float s = w;
#pragma unroll
        for (int m = 1; m <= 32; m <<= 1) s += __shfl_xor(s, m, 64);
        if (lane == 32) sel = s;
    }
    __shared__ float red[4][33];
    if (lane < 33) red[wid][lane] = sel;
    __syncthreads();
    if (wid == 0 && lane < 33) {
        float t = red[0][lane] + red[1][lane] + red[2][lane] + red[3][lane];
        atomicAdd(lane < 32 ? &att[2 + lane] : &att[1], t);
    }
}

__global__ void att_ctx_k(const float* __restrict__ wk, const float* __restrict__ bk,
                          float* __restrict__ att)
{
    int o = threadIdx.x;
    if (o >= 32) return;
    float invS = 1.0f / att[1];
    float s = bk[o];
#pragma unroll
    for (int c = 0; c < 32; ++c) s = fmaf(att[2 + c] * invS, wk[c * 32 + o], s);
    att[34 + o] = s;
}

__global__ __launch_bounds__(256) void att_out_res(
    const u16* __restrict__ net, const u16* __restrict__ d,
    const float* __restrict__ wv, const float* __restrict__ bv,
    const float* __restrict__ wo, const float* __restrict__ bo,
    const float* __restrict__ att, u16* __restrict__ r, int M)
{
    int p = blockIdx.x * 256 + threadIdx.x;
    if (p >= M) return;
    float nv[32];
    load_row32(net, p, nv);
    float vv[32];
#pragma unroll
    for (int o = 0; o < 32; ++o) {
        float s = bv[o];
#pragma unroll
        for (int c = 0; c < 32; ++c) s = fmaf(nv[c], wv[c * 32 + o], s);
        vv[o] = s * att[34 + o];
    }
    float dv[32];
    load_row32(d, p, dv);
    u32 wd[16];
#pragma unroll
    for (int q = 0; q < 16; ++q) {
        float y[2];
#pragma unroll
        for (int t = 0; t < 2; ++t) {
            int oo = 2 * q + t;
            float s = bo[oo];
#pragma unroll
            for (int o = 0; o < 32; ++o) s = fmaf(vv[o], wo[o * 32 + oo], s);
            y[t] = fmaxf(s + dv[oo], 0.f);
        }
        wd[q] = pack2(y[0], y[1]);
    }
    uint4* dst = reinterpret_cast<uint4*>(r + (size_t)p * 32);
    uint4 v;
    v.x = wd[0];  v.y = wd[1];  v.z = wd[2];  v.w = wd[3];  dst[0] = v;
    v.x = wd[4];  v.y = wd[5];  v.z = wd[6];  v.w = wd[7];  dst[1] = v;
    v.x = wd[8];  v.y = wd[9];  v.z = wd[10]; v.w = wd[11]; dst[2] = v;
    v.x = wd[12]; v.y = wd[13]; v.z = wd[14]; v.w = wd[15]; dst[3] = v;
}

// ---------------- final: y = relu(bn(net2) + bn(ds)); out = y@Wcls + bcls ----------------
__global__ __launch_bounds__(256) void final_cls(
    const u16* __restrict__ net2, const u16* __restrict__ dsr,
    const float* __restrict__ st7, const float* __restrict__ st8,
    const float* __restrict__ gb7, const float* __restrict__ gb8,
    const float* __restrict__ wcls, const float* __restrict__ bcls,
    float* __restrict__ outp, float invM, int M)
{
    __shared__ float ab7[64], ab8[64];
    if (threadIdx.x < 64) {
        int c = threadIdx.x & 31;
        const float* st = (threadIdx.x < 32) ? st7 : st8;
        const float* g  = (threadIdx.x < 32) ? gb7 : gb8;
        float* abp      = (threadIdx.x < 32) ? ab7 : ab8;
        float s = 0.f, q = 0.f;
#pragma unroll
        for (int k = 0; k < NSTRIPE; ++k) {
            s += st[k * 64 + c];
            q += st[k * 64 + 32 + c];
        }
        float mu = s * invM;
        float var = fmaxf(q * invM - mu * mu, 0.f);
        float a = g[c] * rsqrtf(var + 1e-5f);
        abp[c] = a;
        abp[32 + c] = g[32 + c] - mu * a;
    }
    __syncthreads();
    int p = blockIdx.x * 256 + threadIdx.x;
    if (p >= M) return;
    float nv[32], dv[32];
    load_row32(net2, p, nv);
    load_row32(dsr, p, dv);
    float y[32];
#pragma unroll
    for (int c = 0; c < 32; ++c) {
        float t = fmaf(ab7[c], nv[c], ab7[32 + c]) + fmaf(ab8[c], dv[c], ab8[32 + c]);
        y[c] = fmaxf(t, 0.f);
    }
#pragma unroll
    for (int j = 0; j < NCLSS; ++j) {
        float s = bcls[j];
#pragma unroll
        for (int c = 0; c < 32; ++c) s = fmaf(y[c], wcls[c * NCLSS + j], s);
        outp[(size_t)p * NCLSS + j] = s;
    }
}

// ---------------- host ----------------
extern "C" void kernel_launch(void* const* d_in, const int* in_sizes, int n_in,
                              void* d_out, int out_size, void* d_ws, size_t ws_size,
                              hipStream_t stream)
{
    char* wsb = (char*)d_ws;

    // stats: 9 slots x 16 stripes x 64 floats; ATT right after
    float* ST  = (float*)wsb;                        // 9216 floats
    float* ATT = ST + 9216;                          // 66 floats
    float* L   = (float*)(wsb + 65536);              // N1 logits fp32
    u16* A = (u16*)(wsb + 131072);                   // N*32 bf16 (7,680,000 B each)
    u16* B = (u16*)(wsb + 131072 + 7680000ull);
    u16* C = (u16*)(wsb + 131072 + 2 * 7680000ull);
    u16* D = (u16*)(wsb + 131072 + 2 * 7680000ull + 960000ull);
    u16* E = (u16*)(wsb + 131072 + 2 * 7680000ull + 2 * 960000ull);
    float* T = (float*)(wsb + 131072 + 2 * 7680000ull + 3 * 960000ull);      // N*32 fp32
    u16* G = (u16*)(wsb + 131072 + 2 * 7680000ull + 3 * 960000ull + 15360000ull);

    size_t wboff = 131072 + 2 * 7680000ull + 3 * 960000ull + 15360000ull + 7680000ull;
    auto wbsz = [](int K) { return (size_t)((K + 1) & ~1) * 4096; };
    uint4* wb_stem1 = (uint4*)(wsb + wboff);         size_t o1 = wboff + wbsz(27);
    uint4* wb_down  = (uint4*)(wsb + o1);            size_t o2 = o1 + wbsz(8);
    uint4* wb_res1  = (uint4*)(wsb + o2);            size_t o3 = o2 + wbsz(27);
    uint4* wb_res2  = (uint4*)(wsb + o3);            size_t o4 = o3 + wbsz(27);
    uint4* wb_up    = (uint4*)(wsb + o4);            size_t o5 = o4 + wbsz(8);
    uint4* wb_f1A   = (uint4*)(wsb + o5);            size_t o6 = o5 + wbsz(27);
    uint4* wb_f1B   = (uint4*)(wsb + o6);            size_t o7 = o6 + wbsz(27);
    uint4* wb_fuse2 = (uint4*)(wsb + o7);            size_t o8 = o7 + wbsz(27);

    int* nbrT0 = (int*)(wsb + o8);                   size_t o9  = o8 + 27ull * NPTS * 4;
    int* nbrTd = (int*)(wsb + o9);                   size_t o10 = o9 + 8ull * N1PTS * 4;
    int* nbrT1 = (int*)(wsb + o10);                  size_t o11 = o10 + 27ull * N1PTS * 4;
    int* nbrTu = (int*)(wsb + o11);

    const float* X        = (const float*)d_in[0];
    const float* Wstem0   = (const float*)d_in[1];
    const float* gb_stem0 = (const float*)d_in[2];
    const float* Wstem1   = (const float*)d_in[3];
    const float* gb_stem1 = (const float*)d_in[4];
    const float* Wdown    = (const float*)d_in[5];
    const float* gb_down  = (const float*)d_in[6];
    const float* Wres1    = (const float*)d_in[7];
    const float* gb_res1  = (const float*)d_in[8];
    const float* Wres2    = (const float*)d_in[9];
    const float* gb_res2  = (const float*)d_in[10];
    const float* wi = (const float*)d_in[11];
    const float* bi = (const float*)d_in[12];
    const float* wk = (const float*)d_in[13];
    const float* bk = (const float*)d_in[14];
    const float* wv = (const float*)d_in[15];
    const float* bv = (const float*)d_in[16];
    const float* wo = (const float*)d_in[17];
    const float* bo = (const float*)d_in[18];
    const float* Wup      = (const float*)d_in[19];
    const float* gb_up    = (const float*)d_in[20];
    const float* Wfuse1   = (const float*)d_in[21];
    const float* gb_fuse1 = (const float*)d_in[22];
    const float* Wfuse2   = (const float*)d_in[23];
    const float* gb_fuse2 = (const float*)d_in[24];
    const float* Wds      = (const float*)d_in[25];
    const float* gb_ds    = (const float*)d_in[26];
    const float* Wcls     = (const float*)d_in[27];
    const float* bcls     = (const float*)d_in[28];

    const int* nbr0     = (const int*)d_in[29];
    const int* nbr_down = (const int*)d_in[30];
    const int* nbr1     = (const int*)d_in[31];
    const int* nbr_up   = (const int*)d_in[32];

    const float invN  = 1.0f / (float)NPTS;
    const float invN1 = 1.0f / (float)N1PTS;

    hipMemsetAsync((void*)ST, 0, (9216 + 66) * sizeof(float), stream);

    hipLaunchKernelGGL((transpose_nbr<27>), dim3(cdiv(NPTS, 256)), dim3(256), 0, stream,
                       nbr0, nbrT0, NPTS);
    hipLaunchKernelGGL((transpose_nbr<8>), dim3(cdiv(N1PTS, 256)), dim3(256), 0, stream,
                       nbr_down, nbrTd, N1PTS);
    hipLaunchKernelGGL((transpose_nbr<27>), dim3(cdiv(N1PTS, 256)), dim3(256), 0, stream,
                       nbr1, nbrT1, N1PTS);
    hipLaunchKernelGGL((transpose_nbr<8>), dim3(cdiv(NPTS, 256)), dim3(256), 0, stream,
                       nbr_up, nbrTu, NPTS);

    {
        WbArgs a;
        a.src[0] = Wstem1; a.dst[0] = wb_stem1; a.CINF[0] = 32; a.COFF[0] = 0;  a.K2[0] = 54;
        a.src[1] = Wdown;  a.dst[1] = wb_down;  a.CINF[1] = 32; a.COFF[1] = 0;  a.K2[1] = 16;
        a.src[2] = Wres1;  a.dst[2] = wb_res1;  a.CINF[2] = 32; a.COFF[2] = 0;  a.K2[2] = 54;
        a.src[3] = Wres2;  a.dst[3] = wb_res2;  a.CINF[3] = 32; a.COFF[3] = 0;  a.K2[3] = 54;
        a.src[4] = Wup;    a.dst[4] = wb_up;    a.CINF[4] = 32; a.COFF[4] = 0;  a.K2[4] = 16;
        a.src[5] = Wfuse1; a.dst[5] = wb_f1A;   a.CINF[5] = 64; a.COFF[5] = 0;  a.K2[5] = 54;
        a.src[6] = Wfuse1; a.dst[6] = wb_f1B;   a.CINF[6] = 64; a.COFF[6] = 32; a.K2[6] = 54;
        a.src[7] = Wfuse2; a.dst[7] = wb_fuse2; a.CINF[7] = 32; a.COFF[7] = 0;  a.K2[7] = 54;
        hipLaunchKernelGGL(convert_wb, dim3(54, 8), dim3(64), 0, stream, a);
    }

    const int gS   = cdiv(NPTS, 64);     // conv_x3, conv_ds2
    const int gB   = cdiv(NPTS, 256);    // conv_blk
    const int gM1  = cdiv(N1PTS, 64);    // conv_mfma N1
    const int gBN  = cdiv(NPTS * 4, 256);
    const int gBN1 = cdiv(N1PTS * 4, 256);
    const int gN1p = cdiv(N1PTS, 256);
    const int gN   = cdiv(NPTS, 256);

    // stem
    hipLaunchKernelGGL(conv_x3, dim3(gS), dim3(256), 0, stream,
                       X, nbrT0, Wstem0, A, ST + 0 * 1024, NPTS);
    hipLaunchKernelGGL((bn_apply<true>), dim3(gBN), dim3(256), 0, stream,
                       A, ST + 0 * 1024, gb_stem0, invN, NPTS * 4);
    hipLaunchKernelGGL((conv_blk<27, 0, 3>), dim3(gB), dim3(1024), 0, stream,
                       A, nbrT0, wb_stem1, B, (float*)nullptr, ST + 1 * 1024, NPTS, NPTS);
    hipLaunchKernelGGL((bn_apply<true>), dim3(gBN), dim3(256), 0, stream,
                       B, ST + 1 * 1024, gb_stem1, invN, NPTS * 4);   // B = x0

    // downsample
    hipLaunchKernelGGL((conv_mfma<8>), dim3(gM1), dim3(256), 0, stream,
                       B, nbrTd, wb_down, C, ST + 2 * 1024, N1PTS);
    hipLaunchKernelGGL((bn_apply<true>), dim3(gBN1), dim3(256), 0, stream,
                       C, ST + 2 * 1024, gb_down, invN1, N1PTS * 4);  // C = d

    // residual block convs
    hipLaunchKernelGGL((conv_mfma<27>), dim3(gM1), dim3(256), 0, stream,
                       C, nbrT1, wb_res1, D, ST + 3 * 1024, N1PTS);
    hipLaunchKernelGGL((bn_apply<true>), dim3(gBN1), dim3(256), 0, stream,
                       D, ST + 3 * 1024, gb_res1, invN1, N1PTS * 4);
    hipLaunchKernelGGL((conv_mfma<27>), dim3(gM1), dim3(256), 0, stream,
                       D, nbrT1, wb_res2, E, ST + 4 * 1024, N1PTS);
    hipLaunchKernelGGL((bn_apply<false>), dim3(gBN1), dim3(256), 0, stream,
                       E, ST + 4 * 1024, gb_res2, invN1, N1PTS * 4);  // E = net

    // attention + residual add (writes r into D)
    hipLaunchKernelGGL(att_logits, dim3(gN1p), dim3(256), 0, stream,
                       E, wi, bi, L, (u32*)ATT, N1PTS);
    hipLaunchKernelGGL(att_accum, dim3(gN1p), dim3(256), 0, stream, E, L, ATT, N1PTS);
    hipLaunchKernelGGL(att_ctx_k, dim3(1), dim3(64), 0, stream, wk, bk, ATT);
    hipLaunchKernelGGL(att_out_res, dim3(gN1p), dim3(256), 0, stream,
                       E, C, wv, bv, wo, bo, ATT, D, N1PTS);          // D = r

    // upsample (src = D, 0.96 MB L2-resident -> single phase)
    hipLaunchKernelGGL((conv_blk<8, 0, 1>), dim3(gB), dim3(1024), 0, stream,
                       D, nbrTu, wb_up, A, (float*)nullptr, ST + 5 * 1024, NPTS, N1PTS);
    hipLaunchKernelGGL((bn_apply<true>), dim3(gBN), dim3(256), 0, stream,
                       A, ST + 5 * 1024, gb_up, invN, NPTS * 4);      // A = u_bn

    // fuse residual block (cat never materialized)
    hipLaunchKernelGGL((conv_blk<27, 1, 3>), dim3(gB), dim3(1024), 0, stream,
                       A, nbrT0, wb_f1A, (u16*)nullptr, T, (float*)nullptr, NPTS, NPTS);
    hipLaunchKernelGGL(conv_ds2, dim3(gS), dim3(256), 0, stream,
                       A, B, Wds, G, ST + 8 * 1024, NPTS);
    hipLaunchKernelGGL((conv_blk<27, 2, 3>), dim3(gB), dim3(1024), 0, stream,
                       B, nbrT0, wb_f1B, A, T, ST + 6 * 1024, NPTS, NPTS);
    hipLaunchKernelGGL((bn_apply<true>), dim3(gBN), dim3(256), 0, stream,
                       A, ST + 6 * 1024, gb_fuse1, invN, NPTS * 4);
    hipLaunchKernelGGL((conv_blk<27, 0, 3>), dim3(gB), dim3(1024), 0, stream,
                       A, nbrT0, wb_fuse2, B, (float*)nullptr, ST + 7 * 1024, NPTS, NPTS);

    // final fuse + classifier
    hipLaunchKernelGGL(final_cls, dim3(gN), dim3(256), 0, stream,
                       B, G, ST + 7 * 1024, ST + 8 * 1024, gb_fuse2, gb_ds,
                       Wcls, bcls, (float*)d_out, invN, NPTS);
}

// Round 12
// 494.267 us; speedup vs baseline: 1.1513x; 1.0251x over previous
//
#include <hip/hip_runtime.h>

typedef unsigned int u32;
typedef unsigned short u16;

#define NPTS 120000
#define N1PTS 15000
#define NCLSS 17
#define NSTRIPE 16

static inline int cdiv(int a, int b) { return (a + b - 1) / b; }

typedef __attribute__((ext_vector_type(8))) short bf16x8;
typedef __attribute__((ext_vector_type(4))) float f32x4;

// bf16 helpers (storage-only bf16; math fp32)
__device__ __forceinline__ float bflo(u32 u) { return __uint_as_float(u << 16); }
__device__ __forceinline__ float bfhi(u32 u) { return __uint_as_float(u & 0xFFFF0000u); }
__device__ __forceinline__ u32 f2bf(float f) {   // RNE
    u32 u = __float_as_uint(f);
    return (u + 0x7FFFu + ((u >> 16) & 1u)) >> 16;
}
__device__ __forceinline__ u32 pack2(float a, float b) { return f2bf(a) | (f2bf(b) << 16); }
// fp16 (RNE) for partial-sum buffers
__device__ __forceinline__ u16 f2h(float f) { _Float16 h = (_Float16)f; return __builtin_bit_cast(u16, h); }
__device__ __forceinline__ float h2f(u16 b) { return (float)__builtin_bit_cast(_Float16, b); }

__device__ __forceinline__ f32x4 mfma16(bf16x8 a, uint4 b, f32x4 c) {
    return __builtin_amdgcn_mfma_f32_16x16x32_bf16(a, __builtin_bit_cast(bf16x8, b), c, 0, 0, 0);
}

// ---------------- nbr transpose: nbrT[k*M + p] = nbr[p*K + k] ----------------
template<int K>
__global__ __launch_bounds__(256) void transpose_nbr(
    const int* __restrict__ nbr, int* __restrict__ nbrT, int M)
{
    __shared__ int tile[256][K + 1];
    int p0 = blockIdx.x * 256;
    int t = threadIdx.x;
    int np = M - p0; if (np > 256) np = 256;
    int total = np * K;
    for (int i = t; i < total; i += 256) {
        int lp = i / K, k = i - lp * K;
        tile[lp][k] = nbr[(size_t)p0 * K + i];
    }
    __syncthreads();
    if (t < np) {
#pragma unroll
        for (int k = 0; k < K; ++k)
            nbrT[(size_t)k * M + p0 + t] = tile[t][k];
    }
}

// ---------------- weight -> B-fragment conversion (hi/lo bf16 split) ----------------
struct WbArgs {
    const float* src[8];
    uint4* dst[8];
    int CINF[8];
    int COFF[8];
    int K2[8];    // 2*K
};

__global__ __launch_bounds__(64) void convert_wb(WbArgs a) {
    int j = blockIdx.y;
    int s2 = blockIdx.x;
    if (s2 >= a.K2[j]) return;
    int lane = threadIdx.x;
    int k = s2 >> 1, tile = s2 & 1;
    int c = a.COFF[j] + (lane >> 4) * 8;
    int o = tile * 16 + (lane & 15);
    const float* w = a.src[j] + ((size_t)k * a.CINF[j] + c) * 32 + o;
    u32 hw[4], lw[4];
#pragma unroll
    for (int q = 0; q < 4; ++q) {
        float w0 = w[(2 * q) * 32], w1 = w[(2 * q + 1) * 32];
        u32 h0 = f2bf(w0), h1 = f2bf(w1);
        float r0 = w0 - __uint_as_float(h0 << 16);
        float r1 = w1 - __uint_as_float(h1 << 16);
        hw[q] = h0 | (h1 << 16);
        lw[q] = f2bf(r0) | (f2bf(r1) << 16);
    }
    uint4 hv; hv.x = hw[0]; hv.y = hw[1]; hv.z = hw[2]; hv.w = hw[3];
    uint4 lv; lv.x = lw[0]; lv.y = lw[1]; lv.z = lw[2]; lv.w = lw[3];
    a.dst[j][(size_t)(s2 * 2 + 0) * 64 + lane] = hv;
    a.dst[j][(size_t)(s2 * 2 + 1) * 64 + lane] = lv;
}

// ---------------- conv_part: k-range partial conv, fp16 partial output, no stats ----------------
// 16 waves x 16 points; weights+idx in LDS (~72 KB -> 2 blocks/CU = 32 waves); depth-3 prefetch.
template<int KB>
__global__ __launch_bounds__(1024, 8) void conv_part(
    const u16* __restrict__ src, const int* __restrict__ nbrTk,
    const uint4* __restrict__ wb, u16* __restrict__ outh, int M)
{
    __shared__ uint4 wl[KB * 256];
    __shared__ int il[KB * 256];
    int tid = threadIdx.x;
    int lane = tid & 63, wid = tid >> 6;
    int p0 = blockIdx.x * 256 + wid * 16;
    int row = lane & 15, hi4 = lane >> 4;
    int lpt = wid * 16 + row;
    const uint4 z4 = {0u, 0u, 0u, 0u};

    for (int i = tid; i < KB * 256; i += 1024) wl[i] = wb[i];
    for (int i = tid; i < KB * 256; i += 1024) {
        int k = i >> 8, pl = i & 255;
        int pp = blockIdx.x * 256 + pl;
        il[i] = (pp < M) ? nbrTk[(size_t)k * M + pp] : -1;
    }

    f32x4 acc0 = {0.f, 0.f, 0.f, 0.f};
    f32x4 acc1 = {0.f, 0.f, 0.f, 0.f};

    __syncthreads();

    auto gld = [&](int k) -> uint4 {
        int idx = il[(k << 8) + lpt];
        int j = idx >= 0 ? idx : 0;
        uint4 v = reinterpret_cast<const uint4*>(src + (size_t)j * 32)[hi4];
        u32 m = (idx >= 0) ? 0xFFFFFFFFu : 0u;
        uint4 r; r.x = v.x & m; r.y = v.y & m; r.z = v.z & m; r.w = v.w & m;
        return r;
    };

    uint4 g0 = gld(0);
    uint4 g1 = (KB > 1) ? gld(1) : z4;
    uint4 g2 = (KB > 2) ? gld(2) : z4;

#pragma unroll 1
    for (int k = 0; k < KB; ++k) {
        uint4 gn = (k + 3 < KB) ? gld(k + 3) : z4;
        const uint4* bl = &wl[k * 256];
        bf16x8 a = __builtin_bit_cast(bf16x8, g0);
        acc0 = mfma16(a, bl[lane], acc0);
        acc0 = mfma16(a, bl[64 + lane], acc0);
        acc1 = mfma16(a, bl[128 + lane], acc1);
        acc1 = mfma16(a, bl[192 + lane], acc1);
        g0 = g1; g1 = g2; g2 = gn;
    }

#pragma unroll
    for (int r = 0; r < 4; ++r) {
        int pp = p0 + hi4 * 4 + r;
        if (pp < M) {
            outh[(size_t)pp * 32 + (lane & 15)] = f2h(acc0[r]);
            outh[(size_t)pp * 32 + 16 + (lane & 15)] = f2h(acc1[r]);
        }
    }
}

// ---------------- merge NB fp16 partials -> bf16 out + striped stats ----------------
template<int NB>
__global__ __launch_bounds__(256) void merge_conv(
    const u16* __restrict__ t0, const u16* __restrict__ t1,
    const u16* __restrict__ t2, const u16* __restrict__ t3,
    u16* __restrict__ out, float* __restrict__ stats, int M)
{
    __shared__ float ssum[32], ssq[32];
    int tid = threadIdx.x;
    if (tid < 32) { ssum[tid] = 0.f; ssq[tid] = 0.f; }
    __syncthreads();
    int i = blockIdx.x * 256 + tid;
    int total = M * 4;
    int c0 = (i & 3) * 8;
    float v[8];
#pragma unroll
    for (int j = 0; j < 8; ++j) v[j] = 0.f;
    if (i < total) {
        uint4 a0 = reinterpret_cast<const uint4*>(t0)[i];
        uint4 a1 = reinterpret_cast<const uint4*>(t1)[i];
        u32 w0[4] = { a0.x, a0.y, a0.z, a0.w };
        u32 w1[4] = { a1.x, a1.y, a1.z, a1.w };
#pragma unroll
        for (int q = 0; q < 4; ++q) {
            v[2 * q]     = h2f((u16)(w0[q] & 0xFFFF)) + h2f((u16)(w1[q] & 0xFFFF));
            v[2 * q + 1] = h2f((u16)(w0[q] >> 16)) + h2f((u16)(w1[q] >> 16));
        }
        if (NB == 4) {
            uint4 a2 = reinterpret_cast<const uint4*>(t2)[i];
            uint4 a3 = reinterpret_cast<const uint4*>(t3)[i];
            u32 w2[4] = { a2.x, a2.y, a2.z, a2.w };
            u32 w3[4] = { a3.x, a3.y, a3.z, a3.w };
#pragma unroll
            for (int q = 0; q < 4; ++q) {
                v[2 * q]     += h2f((u16)(w2[q] & 0xFFFF)) + h2f((u16)(w3[q] & 0xFFFF));
                v[2 * q + 1] += h2f((u16)(w2[q] >> 16)) + h2f((u16)(w3[q] >> 16));
            }
        }
        u32 r[4];
#pragma unroll
        for (int q = 0; q < 4; ++q) r[q] = pack2(v[2 * q], v[2 * q + 1]);
        uint4 o; o.x = r[0]; o.y = r[1]; o.z = r[2]; o.w = r[3];
        reinterpret_cast<uint4*>(out)[i] = o;
    }
#pragma unroll
    for (int j = 0; j < 8; ++j) {
        atomicAdd(&ssum[c0 + j], v[j]);
        atomicAdd(&ssq[c0 + j], v[j] * v[j]);
    }
    __syncthreads();
    if (tid < 32) {
        float* sst = stats + ((blockIdx.x & (NSTRIPE - 1)) << 6);
        atomicAdd(&sst[tid], ssum[tid]);
        atomicAdd(&sst[32 + tid], ssq[tid]);
    }
}

// ---------------- conv_blk8: full K=8 conv, bf16 out + striped stats ----------------
__global__ __launch_bounds__(1024, 8) void conv_blk8(
    const u16* __restrict__ src, const int* __restrict__ nbrT,
    const uint4* __restrict__ wb, u16* __restrict__ out,
    float* __restrict__ stats, int M)
{
    constexpr int K = 8;
    __shared__ uint4 wl[K * 256];
    __shared__ int il[K * 256];
    __shared__ float red[15][64];
    int tid = threadIdx.x;
    int lane = tid & 63, wid = tid >> 6;
    int p0 = blockIdx.x * 256 + wid * 16;
    int row = lane & 15, hi4 = lane >> 4;
    int lpt = wid * 16 + row;
    const uint4 z4 = {0u, 0u, 0u, 0u};

    for (int i = tid; i < K * 256; i += 1024) wl[i] = wb[i];
    for (int i = tid; i < K * 256; i += 1024) {
        int k = i >> 8, pl = i & 255;
        int pp = blockIdx.x * 256 + pl;
        il[i] = (pp < M) ? nbrT[(size_t)k * M + pp] : -1;
    }

    f32x4 acc0 = {0.f, 0.f, 0.f, 0.f};
    f32x4 acc1 = {0.f, 0.f, 0.f, 0.f};

    __syncthreads();

    auto gld = [&](int k) -> uint4 {
        int idx = il[(k << 8) + lpt];
        int j = idx >= 0 ? idx : 0;
        uint4 v = reinterpret_cast<const uint4*>(src + (size_t)j * 32)[hi4];
        u32 m = (idx >= 0) ? 0xFFFFFFFFu : 0u;
        uint4 r; r.x = v.x & m; r.y = v.y & m; r.z = v.z & m; r.w = v.w & m;
        return r;
    };

    uint4 g0 = gld(0);
    uint4 g1 = gld(1);
    uint4 g2 = gld(2);

#pragma unroll 1
    for (int k = 0; k < K; ++k) {
        uint4 gn = (k + 3 < K) ? gld(k + 3) : z4;
        const uint4* bl = &wl[k * 256];
        bf16x8 a = __builtin_bit_cast(bf16x8, g0);
        acc0 = mfma16(a, bl[lane], acc0);
        acc0 = mfma16(a, bl[64 + lane], acc0);
        acc1 = mfma16(a, bl[128 + lane], acc1);
        acc1 = mfma16(a, bl[192 + lane], acc1);
        g0 = g1; g1 = g2; g2 = gn;
    }

#pragma unroll
    for (int r = 0; r < 4; ++r) {
        int pp = p0 + hi4 * 4 + r;
        if (pp < M) {
            out[(size_t)pp * 32 + (lane & 15)] = (u16)f2bf(acc0[r]);
            out[(size_t)pp * 32 + 16 + (lane & 15)] = (u16)f2bf(acc1[r]);
        }
    }

    float s0 = 0.f, q0 = 0.f, s1 = 0.f, q1 = 0.f;
#pragma unroll
    for (int r = 0; r < 4; ++r) {
        s0 += acc0[r]; q0 += acc0[r] * acc0[r];
        s1 += acc1[r]; q1 += acc1[r] * acc1[r];
    }
#pragma unroll
    for (int m = 16; m <= 32; m <<= 1) {
        s0 += __shfl_xor(s0, m, 64); q0 += __shfl_xor(q0, m, 64);
        s1 += __shfl_xor(s1, m, 64); q1 += __shfl_xor(q1, m, 64);
    }
    float val = (lane < 16) ? s0 : (lane < 32) ? s1 : (lane < 48) ? q0 : q1;
    if (wid > 0) red[wid - 1][lane] = val;
    __syncthreads();
    if (wid == 0) {
        float t = val;
#pragma unroll
        for (int w = 0; w < 15; ++w) t += red[w][lane];
        atomicAdd(&stats[((blockIdx.x & (NSTRIPE - 1)) << 6) + lane], t);
    }
}

// ---------------- conv_mfma: 4-wave version for small N1 grids ----------------
template<int K>
__global__ __launch_bounds__(256, 6) void conv_mfma(
    const u16* __restrict__ src, const int* __restrict__ nbrT,
    const uint4* __restrict__ wb, u16* __restrict__ out,
    float* __restrict__ stats, int M)
{
    constexpr int KS = K;
    constexpr int NCH = (KS + 1) / 2;
    __shared__ uint4 wlds[2][512];
    __shared__ float red[4][64];

    int tid = threadIdx.x;
    int lane = tid & 63, wid = tid >> 6;
    int p0 = blockIdx.x * 64 + wid * 16;
    int row = lane & 15, hi4 = lane >> 4;
    int p = p0 + row;
    bool rowok = p < M;
    const uint4 z4 = {0u, 0u, 0u, 0u};

    f32x4 acc0 = {0.f, 0.f, 0.f, 0.f};
    f32x4 acc1 = {0.f, 0.f, 0.f, 0.f};

    {
        uint4 a0 = wb[tid], a1 = wb[256 + tid];
        wlds[0][tid] = a0; wlds[0][256 + tid] = a1;
    }
    uint4 av0 = z4, av1 = z4;
    {
        int iA = -1, iB = -1;
        if (rowok) {
            iA = nbrT[p];
            if (KS > 1) iB = nbrT[(size_t)M + p];
        }
        if (iA >= 0) av0 = reinterpret_cast<const uint4*>(src + (size_t)iA * 32)[hi4];
        if (KS > 1 && iB >= 0) av1 = reinterpret_cast<const uint4*>(src + (size_t)iB * 32)[hi4];
    }

    uint4 wr0 = z4, wr1 = z4;
#pragma unroll 1
    for (int c = 0; c < NCH; ++c) {
        bool last = (c + 1 >= NCH);
        if (!last) {
            wr0 = wb[(size_t)(c + 1) * 512 + tid];
            wr1 = wb[(size_t)(c + 1) * 512 + 256 + tid];
        }
        int nA = -1, nB = -1;
        if (!last && rowok) {
            int s0 = 2 * c + 2;
            nA = nbrT[(size_t)s0 * M + p];
            if (s0 + 1 < KS) nB = nbrT[(size_t)(s0 + 1) * M + p];
        }
        asm volatile("s_waitcnt lgkmcnt(0)" ::: "memory");
        __builtin_amdgcn_s_barrier();
        asm volatile("" ::: "memory");
        uint4 nav0 = z4, nav1 = z4;
        if (nA >= 0) nav0 = reinterpret_cast<const uint4*>(src + (size_t)nA * 32)[hi4];
        if (nB >= 0) nav1 = reinterpret_cast<const uint4*>(src + (size_t)nB * 32)[hi4];

        const uint4* bl = wlds[c & 1];
        {
            bf16x8 a = __builtin_bit_cast(bf16x8, av0);
            acc0 = mfma16(a, bl[lane], acc0);
            acc0 = mfma16(a, bl[64 + lane], acc0);
            acc1 = mfma16(a, bl[128 + lane], acc1);
            acc1 = mfma16(a, bl[192 + lane], acc1);
        }
        if (2 * c + 1 < KS) {
            bf16x8 a = __builtin_bit_cast(bf16x8, av1);
            acc0 = mfma16(a, bl[256 + lane], acc0);
            acc0 = mfma16(a, bl[320 + lane], acc0);
            acc1 = mfma16(a, bl[384 + lane], acc1);
            acc1 = mfma16(a, bl[448 + lane], acc1);
        }
        if (!last) {
            wlds[(c + 1) & 1][tid] = wr0;
            wlds[(c + 1) & 1][256 + tid] = wr1;
        }
        av0 = nav0; av1 = nav1;
    }

#pragma unroll
    for (int r = 0; r < 4; ++r) {
        int pp = p0 + hi4 * 4 + r;
        if (pp < M) {
            out[(size_t)pp * 32 + (lane & 15)] = (u16)f2bf(acc0[r]);
            out[(size_t)pp * 32 + 16 + (lane & 15)] = (u16)f2bf(acc1[r]);
        }
    }

    float s0 = 0.f, q0 = 0.f, s1 = 0.f, q1 = 0.f;
#pragma unroll
    for (int r = 0; r < 4; ++r) {
        s0 += acc0[r]; q0 += acc0[r] * acc0[r];
        s1 += acc1[r]; q1 += acc1[r] * acc1[r];
    }
#pragma unroll
    for (int m = 16; m <= 32; m <<= 1) {
        s0 += __shfl_xor(s0, m, 64); q0 += __shfl_xor(q0, m, 64);
        s1 += __shfl_xor(s1, m, 64); q1 += __shfl_xor(q1, m, 64);
    }
    float val = (lane < 16) ? s0 : (lane < 32) ? s1 : (lane < 48) ? q0 : q1;
    red[wid][lane] = val;
    __syncthreads();
    if (wid == 0) {
        float t = red[0][lane] + red[1][lane] + red[2][lane] + red[3][lane];
        atomicAdd(&stats[((blockIdx.x & (NSTRIPE - 1)) << 6) + lane], t);
    }
}

// ---------------- shared scalar epilogue (conv_x3, conv_ds2) — striped stats ----------------
__device__ __forceinline__ void reduce_store_stats(
    float (&acc)[32], int lane, int wid, bool act, int p,
    u16* __restrict__ out, float* __restrict__ sst)
{
    __shared__ float lds[3][64][17];
#pragma unroll
    for (int r = 0; r < 2; ++r) {
        if (wid > 0) {
#pragma unroll
            for (int j = 0; j < 16; ++j) lds[wid - 1][lane][j] = acc[r * 16 + j];
        }
        __syncthreads();
        if (wid == 0) {
#pragma unroll
            for (int w = 0; w < 3; ++w)
#pragma unroll
                for (int j = 0; j < 16; ++j) acc[r * 16 + j] += lds[w][lane][j];
        }
        __syncthreads();
    }
    if (wid == 0) {
        if (act) {
            u32 wd[16];
#pragma unroll
            for (int q = 0; q < 16; ++q) wd[q] = pack2(acc[2 * q], acc[2 * q + 1]);
            uint4* dst = reinterpret_cast<uint4*>(out + (size_t)p * 32);
            uint4 v;
            v.x = wd[0];  v.y = wd[1];  v.z = wd[2];  v.w = wd[3];  dst[0] = v;
            v.x = wd[4];  v.y = wd[5];  v.z = wd[6];  v.w = wd[7];  dst[1] = v;
            v.x = wd[8];  v.y = wd[9];  v.z = wd[10]; v.w = wd[11]; dst[2] = v;
            v.x = wd[12]; v.y = wd[13]; v.z = wd[14]; v.w = wd[15]; dst[3] = v;
        } else {
#pragma unroll
            for (int o = 0; o < 32; ++o) acc[o] = 0.f;
        }
        float sel1 = 0.f, sel2 = 0.f;
#pragma unroll
        for (int o = 0; o < 32; ++o) {
            float s1 = acc[o], s2 = acc[o] * acc[o];
#pragma unroll
            for (int m = 1; m <= 32; m <<= 1) { s1 += __shfl_xor(s1, m, 64); s2 += __shfl_xor(s2, m, 64); }
            if (lane == o) sel1 = s1;
            if (lane == o + 32) sel2 = s2;
        }
        atomicAdd(&sst[lane], lane < 32 ? sel1 : sel2);
    }
}

__global__ __launch_bounds__(256, 8) void conv_x3(
    const float* __restrict__ src, const int* __restrict__ nbrT,
    const float* __restrict__ W, u16* __restrict__ out,
    float* __restrict__ stats, int M)
{
    constexpr int K = 27;
    int lane = threadIdx.x & 63;
    int wid = __builtin_amdgcn_readfirstlane(threadIdx.x >> 6);
    int p = blockIdx.x * 64 + lane;
    bool act = p < M;
    constexpr int JMAX = 7;

    float acc[32];
#pragma unroll
    for (int o = 0; o < 32; ++o) acc[o] = 0.f;

    int idxs[JMAX];
#pragma unroll
    for (int j = 0; j < JMAX; ++j) {
        int k = wid + 4 * j;
        idxs[j] = (act && k < K) ? nbrT[(size_t)k * M + p] : -1;
    }
#pragma unroll
    for (int j = 0; j < JMAX; ++j) {
        int k = wid + 4 * j;
        if (k >= K) break;
        int idx = idxs[j];
        if (idx >= 0) {
            const float* __restrict__ xr = src + (size_t)idx * 3;
            const float* __restrict__ wk = W + (size_t)k * 3 * 32;
            float x0 = xr[0], x1 = xr[1], x2 = xr[2];
#pragma unroll
            for (int o = 0; o < 32; ++o) {
                float s = fmaf(x0, wk[o], 0.f);
                s = fmaf(x1, wk[32 + o], s);
                acc[o] += fmaf(x2, wk[64 + o], s);
            }
        }
    }
    reduce_store_stats(acc, lane, wid, act, p, out,
                       stats + ((blockIdx.x & (NSTRIPE - 1)) << 6));
}

// ---------------- ds 1x1 conv from two 32-ch sources (u_bn, x0) ----------------
__global__ __launch_bounds__(256, 4) void conv_ds2(
    const u16* __restrict__ u, const u16* __restrict__ x0,
    const float* __restrict__ W, u16* __restrict__ out,
    float* __restrict__ stats, int M)
{
    int lane = threadIdx.x & 63;
    int wid = __builtin_amdgcn_readfirstlane(threadIdx.x >> 6);
    int p = blockIdx.x * 64 + lane;
    bool act = p < M;

    float acc[32];
#pragma unroll
    for (int o = 0; o < 32; ++o) acc[o] = 0.f;

    if (act) {
        const u16* srcp = (wid < 2) ? u : x0;
        const uint4* xr = reinterpret_cast<const uint4*>(srcp + (size_t)p * 32 + (wid & 1) * 16);
        const float* wk = W + (size_t)wid * 16 * 32;
#pragma unroll
        for (int h = 0; h < 2; ++h) {
            uint4 v = xr[h];
            float xv[8] = { bflo(v.x), bfhi(v.x), bflo(v.y), bfhi(v.y),
                            bflo(v.z), bfhi(v.z), bflo(v.w), bfhi(v.w) };
#pragma unroll
            for (int c = 0; c < 8; ++c)
#pragma unroll
                for (int o = 0; o < 32; ++o)
                    acc[o] = fmaf(xv[c], wk[(h * 8 + c) * 32 + o], acc[o]);
        }
    }
    reduce_store_stats(acc, lane, wid, act, p, out,
                       stats + ((blockIdx.x & (NSTRIPE - 1)) << 6));
}

// ---------------- bn apply: sums 16 stripes once per block, then y = a*x + b ----------------
template<bool RELU>
__global__ __launch_bounds__(256) void bn_apply(
    u16* __restrict__ buf, const float* __restrict__ stats,
    const float* __restrict__ gb, float invM, int total)
{
    __shared__ float ab[64];
    if (threadIdx.x < 32) {
        int c = threadIdx.x;
        float s = 0.f, q = 0.f;
#pragma unroll
        for (int st = 0; st < NSTRIPE; ++st) {
            s += stats[st * 64 + c];
            q += stats[st * 64 + 32 + c];
        }
        float mu = s * invM;
        float var = fmaxf(q * invM - mu * mu, 0.f);
        float a = gb[c] * rsqrtf(var + 1e-5f);
        ab[c] = a;
        ab[32 + c] = gb[32 + c] - mu * a;
    }
    __syncthreads();
    int i = blockIdx.x * 256 + threadIdx.x;
    if (i >= total) return;
    int c0 = (i & 3) * 8;
    uint4 v = reinterpret_cast<uint4*>(buf)[i];
    u32 w[4] = { v.x, v.y, v.z, v.w };
    u32 r[4];
#pragma unroll
    for (int q = 0; q < 4; ++q) {
        int c = c0 + 2 * q;
        float y0 = fmaf(ab[c], bflo(w[q]), ab[32 + c]);
        float y1 = fmaf(ab[c + 1], bfhi(w[q]), ab[32 + c + 1]);
        if (RELU) { y0 = fmaxf(y0, 0.f); y1 = fmaxf(y1, 0.f); }
        r[q] = pack2(y0, y1);
    }
    uint4 o; o.x = r[0]; o.y = r[1]; o.z = r[2]; o.w = r[3];
    reinterpret_cast<uint4*>(buf)[i] = o;
}

// ---------------- attention ----------------
__device__ __forceinline__ void load_row32(const u16* __restrict__ base, int p, float (&nv)[32])
{
    const uint4* xr = reinterpret_cast<const uint4*>(base + (size_t)p * 32);
#pragma unroll
    for (int q = 0; q < 4; ++q) {
        uint4 v = xr[q];
        nv[q * 8 + 0] = bflo(v.x); nv[q * 8 + 1] = bfhi(v.x);
        nv[q * 8 + 2] = bflo(v.y); nv[q * 8 + 3] = bfhi(v.y);
        nv[q * 8 + 4] = bflo(v.z); nv[q * 8 + 5] = bfhi(v.z);
        nv[q * 8 + 6] = bflo(v.w); nv[q * 8 + 7] = bfhi(v.w);
    }
}

__global__ __launch_bounds__(256) void att_logits(
    const u16* __restrict__ net, const float* __restrict__ wi,
    const float* __restrict__ bi, float* __restrict__ lbuf,
    u32* __restrict__ mx, int M)
{
    int p = blockIdx.x * 256 + threadIdx.x;
    float l = -3.0e38f;
    if (p < M) {
        float nv[32];
        load_row32(net, p, nv);
        float s = bi[0];
#pragma unroll
        for (int c = 0; c < 32; ++c) s = fmaf(nv[c], wi[c], s);
        lbuf[p] = s;
        l = s;
    }
#pragma unroll
    for (int m = 1; m <= 32; m <<= 1) l = fmaxf(l, __shfl_xor(l, m, 64));
    if ((threadIdx.x & 63) == 0) {
        u32 b = __float_as_uint(l);
        u32 e = (b & 0x80000000u) ? ~b : (b | 0x80000000u);
        atomicMax(mx, e);
    }
}

__global__ __launch_bounds__(256) void att_accum(
    const u16* __restrict__ net, const float* __restrict__ lbuf,
    float* __restrict__ att, int M)
{
    int p = blockIdx.x * 256 + threadIdx.x;
    int lane = threadIdx.x & 63, wid = threadIdx.x >> 6;
    u32 um = __float_as_uint(att[0]);
    float mx = (um & 0x80000000u) ? __uint_as_float(um ^ 0x80000000u) : __uint_as_float(~um);
    float w = 0.f;
    float nv[32];
#pragma unroll
    for (int c = 0; c < 32; ++c) nv[c] = 0.f;
    if (p < M) {
        w = expf(lbuf[p] - mx);
        load_row32(net, p, nv);
    }
    float sel = 0.f;
#pragma unroll
    for (int c = 0; c < 32; ++c) {
        float s = w * nv[c];
#pragma unroll
        for (int m = 1; m <= 32; m <<= 1) s += __shfl_xor(s, m, 64);
        if (lane == c) sel = s;
    }
    {
        float s = w;
#pragma unroll
        for (int m = 1; m <= 32; m <<= 1) s += __shfl_xor(s, m, 64);
        if (lane == 32) sel = s;
    }
    __shared__ float red[4][33];
    if (lane < 33) red[wid][lane] = sel;
    __syncthreads();
    if (wid == 0 && lane < 33) {
        float t = red[0][lane] + red[1][lane] + red[2][lane] + red[3][lane];
        atomicAdd(lane < 32 ? &att[2 + lane] : &att[1], t);
    }
}

__global__ void att_ctx_k(const float* __restrict__ wk, const float* __restrict__ bk,
                          float* __restrict__ att)
{
    int o = threadIdx.x;
    if (o >= 32) return;
    float invS = 1.0f / att[1];
    float s = bk[o];
#pragma unroll
    for (int c = 0; c < 32; ++c) s = fmaf(att[2 + c] * invS, wk[c * 32 + o], s);
    att[34 + o] = s;
}

__global__ __launch_bounds__(256) void att_out_res(
    const u16* __restrict__ net, const u16* __restrict__ d,
    const float* __restrict__ wv, const float* __restrict__ bv,
    const float* __restrict__ wo, const float* __restrict__ bo,
    const float* __restrict__ att, u16* __restrict__ r, int M)
{
    int p = blockIdx.x * 256 + threadIdx.x;
    if (p >= M) return;
    float nv[32];
    load_row32(net, p, nv);
    float vv[32];
#pragma unroll
    for (int o = 0; o < 32; ++o) {
        float s = bv[o];
#pragma unroll
        for (int c = 0; c < 32; ++c) s = fmaf(nv[c], wv[c * 32 + o], s);
        vv[o] = s * att[34 + o];
    }
    float dv[32];
    load_row32(d, p, dv);
    u32 wd[16];
#pragma unroll
    for (int q = 0; q < 16; ++q) {
        float y[2];
#pragma unroll
        for (int t = 0; t < 2; ++t) {
            int oo = 2 * q + t;
            float s = bo[oo];
#pragma unroll
            for (int o = 0; o < 32; ++o) s = fmaf(vv[o], wo[o * 32 + oo], s);
            y[t] = fmaxf(s + dv[oo], 0.f);
        }
        wd[q] = pack2(y[0], y[1]);
    }
    uint4* dst = reinterpret_cast<uint4*>(r + (size_t)p * 32);
    uint4 v;
    v.x = wd[0];  v.y = wd[1];  v.z = wd[2];  v.w = wd[3];  dst[0] = v;
    v.x = wd[4];  v.y = wd[5];  v.z = wd[6];  v.w = wd[7];  dst[1] = v;
    v.x = wd[8];  v.y = wd[9];  v.z = wd[10]; v.w = wd[11]; dst[2] = v;
    v.x = wd[12]; v.y = wd[13]; v.z = wd[14]; v.w = wd[15]; dst[3] = v;
}

// ---------------- final: y = relu(bn(net2) + bn(ds)); out = y@Wcls + bcls ----------------
__global__ __launch_bounds__(256) void final_cls(
    const u16* __restrict__ net2, const u16* __restrict__ dsr,
    const float* __restrict__ st7, const float* __restrict__ st8,
    const float* __restrict__ gb7, const float* __restrict__ gb8,
    const float* __restrict__ wcls, const float* __restrict__ bcls,
    float* __restrict__ outp, float invM, int M)
{
    __shared__ float ab7[64], ab8[64];
    if (threadIdx.x < 64) {
        int c = threadIdx.x & 31;
        const float* st = (threadIdx.x < 32) ? st7 : st8;
        const float* g  = (threadIdx.x < 32) ? gb7 : gb8;
        float* abp      = (threadIdx.x < 32) ? ab7 : ab8;
        float s = 0.f, q = 0.f;
#pragma unroll
        for (int k = 0; k < NSTRIPE; ++k) {
            s += st[k * 64 + c];
            q += st[k * 64 + 32 + c];
        }
        float mu = s * invM;
        float var = fmaxf(q * invM - mu * mu, 0.f);
        float a = g[c] * rsqrtf(var + 1e-5f);
        abp[c] = a;
        abp[32 + c] = g[32 + c] - mu * a;
    }
    __syncthreads();
    int p = blockIdx.x * 256 + threadIdx.x;
    if (p >= M) return;
    float nv[32], dv[32];
    load_row32(net2, p, nv);
    load_row32(dsr, p, dv);
    float y[32];
#pragma unroll
    for (int c = 0; c < 32; ++c) {
        float t = fmaf(ab7[c], nv[c], ab7[32 + c]) + fmaf(ab8[c], dv[c], ab8[32 + c]);
        y[c] = fmaxf(t, 0.f);
    }
#pragma unroll
    for (int j = 0; j < NCLSS; ++j) {
        float s = bcls[j];
#pragma unroll
        for (int c = 0; c < 32; ++c) s = fmaf(y[c], wcls[c * NCLSS + j], s);
        outp[(size_t)p * NCLSS + j] = s;
    }
}

// ---------------- host ----------------
extern "C" void kernel_launch(void* const* d_in, const int* in_sizes, int n_in,
                              void* d_out, int out_size, void* d_ws, size_t ws_size,
                              hipStream_t stream)
{
    char* wsb = (char*)d_ws;

    float* ST  = (float*)wsb;                        // 9216 floats + ATT
    float* ATT = ST + 9216;
    float* L   = (float*)(wsb + 65536);              // N1 logits fp32
    const size_t SZN = 7680000ull;                   // N*32*2 bytes
    const size_t SZ1 = 960000ull;                    // N1*32*2 bytes
    u16* A  = (u16*)(wsb + 131072);
    u16* B  = (u16*)(wsb + 131072 + SZN);
    u16* C  = (u16*)(wsb + 131072 + 2 * SZN);
    u16* D  = (u16*)(wsb + 131072 + 2 * SZN + SZ1);
    u16* E  = (u16*)(wsb + 131072 + 2 * SZN + 2 * SZ1);
    u16* G  = (u16*)(wsb + 131072 + 2 * SZN + 3 * SZ1);
    u16* T0 = (u16*)(wsb + 131072 + 3 * SZN + 3 * SZ1);          // fp16 partials
    u16* T1 = (u16*)(wsb + 131072 + 4 * SZN + 3 * SZ1);
    u16* T2 = (u16*)(wsb + 131072 + 5 * SZN + 3 * SZ1);
    u16* T3 = (u16*)(wsb + 131072 + 6 * SZN + 3 * SZ1);

    size_t wboff = 131072 + 7 * SZN + 3 * SZ1;
    auto wbsz = [](int K) { return (size_t)((K + 1) & ~1) * 4096; };
    uint4* wb_stem1 = (uint4*)(wsb + wboff);         size_t o1 = wboff + wbsz(27);
    uint4* wb_down  = (uint4*)(wsb + o1);            size_t o2 = o1 + wbsz(8);
    uint4* wb_res1  = (uint4*)(wsb + o2);            size_t o3 = o2 + wbsz(27);
    uint4* wb_res2  = (uint4*)(wsb + o3);            size_t o4 = o3 + wbsz(27);
    uint4* wb_up    = (uint4*)(wsb + o4);            size_t o5 = o4 + wbsz(8);
    uint4* wb_f1A   = (uint4*)(wsb + o5);            size_t o6 = o5 + wbsz(27);
    uint4* wb_f1B   = (uint4*)(wsb + o6);            size_t o7 = o6 + wbsz(27);
    uint4* wb_fuse2 = (uint4*)(wsb + o7);            size_t o8 = o7 + wbsz(27);

    int* nbrT0 = (int*)(wsb + o8);                   size_t o9  = o8 + 27ull * NPTS * 4;
    int* nbrTd = (int*)(wsb + o9);                   size_t o10 = o9 + 8ull * N1PTS * 4;
    int* nbrT1 = (int*)(wsb + o10);                  size_t o11 = o10 + 27ull * N1PTS * 4;
    int* nbrTu = (int*)(wsb + o11);

    const float* X        = (const float*)d_in[0];
    const float* Wstem0   = (const float*)d_in[1];
    const float* gb_stem0 = (const float*)d_in[2];
    const float* Wstem1   = (const float*)d_in[3];
    const float* gb_stem1 = (const float*)d_in[4];
    const float* Wdown    = (const float*)d_in[5];
    const float* gb_down  = (const float*)d_in[6];
    const float* Wres1    = (const float*)d_in[7];
    const float* gb_res1  = (const float*)d_in[8];
    const float* Wres2    = (const float*)d_in[9];
    const float* gb_res2  = (const float*)d_in[10];
    const float* wi = (const float*)d_in[11];
    const float* bi = (const float*)d_in[12];
    const float* wk = (const float*)d_in[13];
    const float* bk = (const float*)d_in[14];
    const float* wv = (const float*)d_in[15];
    const float* bv = (const float*)d_in[16];
    const float* wo = (const float*)d_in[17];
    const float* bo = (const float*)d_in[18];
    const float* Wup      = (const float*)d_in[19];
    const float* gb_up    = (const float*)d_in[20];
    const float* Wfuse1   = (const float*)d_in[21];
    const float* gb_fuse1 = (const float*)d_in[22];
    const float* Wfuse2   = (const float*)d_in[23];
    const float* gb_fuse2 = (const float*)d_in[24];
    const float* Wds      = (const float*)d_in[25];
    const float* gb_ds    = (const float*)d_in[26];
    const float* Wcls     = (const float*)d_in[27];
    const float* bcls     = (const float*)d_in[28];

    const int* nbr0     = (const int*)d_in[29];
    const int* nbr_down = (const int*)d_in[30];
    const int* nbr1     = (const int*)d_in[31];
    const int* nbr_up   = (const int*)d_in[32];

    const float invN  = 1.0f / (float)NPTS;
    const float invN1 = 1.0f / (float)N1PTS;

    hipMemsetAsync((void*)ST, 0, (9216 + 66) * sizeof(float), stream);

    hipLaunchKernelGGL((transpose_nbr<27>), dim3(cdiv(NPTS, 256)), dim3(256), 0, stream,
                       nbr0, nbrT0, NPTS);
    hipLaunchKernelGGL((transpose_nbr<8>), dim3(cdiv(N1PTS, 256)), dim3(256), 0, stream,
                       nbr_down, nbrTd, N1PTS);
    hipLaunchKernelGGL((transpose_nbr<27>), dim3(cdiv(N1PTS, 256)), dim3(256), 0, stream,
                       nbr1, nbrT1, N1PTS);
    hipLaunchKernelGGL((transpose_nbr<8>), dim3(cdiv(NPTS, 256)), dim3(256), 0, stream,
                       nbr_up, nbrTu, NPTS);

    {
        WbArgs a;
        a.src[0] = Wstem1; a.dst[0] = wb_stem1; a.CINF[0] = 32; a.COFF[0] = 0;  a.K2[0] = 54;
        a.src[1] = Wdown;  a.dst[1] = wb_down;  a.CINF[1] = 32; a.COFF[1] = 0;  a.K2[1] = 16;
        a.src[2] = Wres1;  a.dst[2] = wb_res1;  a.CINF[2] = 32; a.COFF[2] = 0;  a.K2[2] = 54;
        a.src[3] = Wres2;  a.dst[3] = wb_res2;  a.CINF[3] = 32; a.COFF[3] = 0;  a.K2[3] = 54;
        a.src[4] = Wup;    a.dst[4] = wb_up;    a.CINF[4] = 32; a.COFF[4] = 0;  a.K2[4] = 16;
        a.src[5] = Wfuse1; a.dst[5] = wb_f1A;   a.CINF[5] = 64; a.COFF[5] = 0;  a.K2[5] = 54;
        a.src[6] = Wfuse1; a.dst[6] = wb_f1B;   a.CINF[6] = 64; a.COFF[6] = 32; a.K2[6] = 54;
        a.src[7] = Wfuse2; a.dst[7] = wb_fuse2; a.CINF[7] = 32; a.COFF[7] = 0;  a.K2[7] = 54;
        hipLaunchKernelGGL(convert_wb, dim3(54, 8), dim3(64), 0, stream, a);
    }

    const int gS   = cdiv(NPTS, 64);     // conv_x3, conv_ds2
    const int gB   = cdiv(NPTS, 256);    // conv_part / conv_blk8 (469)
    const int gM1  = cdiv(N1PTS, 64);    // conv_mfma N1
    const int gBN  = cdiv(NPTS * 4, 256);
    const int gBN1 = cdiv(N1PTS * 4, 256);
    const int gN1p = cdiv(N1PTS, 256);
    const int gN   = cdiv(NPTS, 256);
    const int KH0 = 14, KH1 = 13;        // 27 = 14 + 13 k-split

    // stem
    hipLaunchKernelGGL(conv_x3, dim3(gS), dim3(256), 0, stream,
                       X, nbrT0, Wstem0, A, ST + 0 * 1024, NPTS);
    hipLaunchKernelGGL((bn_apply<true>), dim3(gBN), dim3(256), 0, stream,
                       A, ST + 0 * 1024, gb_stem0, invN, NPTS * 4);
    // stem1 (k-split halves -> fp16 partials -> merge)
    hipLaunchKernelGGL((conv_part<14>), dim3(gB), dim3(1024), 0, stream,
                       A, nbrT0, wb_stem1, T0, NPTS);
    hipLaunchKernelGGL((conv_part<13>), dim3(gB), dim3(1024), 0, stream,
                       A, nbrT0 + (size_t)KH0 * NPTS, wb_stem1 + KH0 * 256, T1, NPTS);
    hipLaunchKernelGGL((merge_conv<2>), dim3(gBN), dim3(256), 0, stream,
                       T0, T1, (const u16*)nullptr, (const u16*)nullptr, B, ST + 1 * 1024, NPTS);
    hipLaunchKernelGGL((bn_apply<true>), dim3(gBN), dim3(256), 0, stream,
                       B, ST + 1 * 1024, gb_stem1, invN, NPTS * 4);   // B = x0

    // downsample
    hipLaunchKernelGGL((conv_mfma<8>), dim3(gM1), dim3(256), 0, stream,
                       B, nbrTd, wb_down, C, ST + 2 * 1024, N1PTS);
    hipLaunchKernelGGL((bn_apply<true>), dim3(gBN1), dim3(256), 0, stream,
                       C, ST + 2 * 1024, gb_down, invN1, N1PTS * 4);  // C = d

    // residual block convs
    hipLaunchKernelGGL((conv_mfma<27>), dim3(gM1), dim3(256), 0, stream,
                       C, nbrT1, wb_res1, D, ST + 3 * 1024, N1PTS);
    hipLaunchKernelGGL((bn_apply<true>), dim3(gBN1), dim3(256), 0, stream,
                       D, ST + 3 * 1024, gb_res1, invN1, N1PTS * 4);
    hipLaunchKernelGGL((conv_mfma<27>), dim3(gM1), dim3(256), 0, stream,
                       D, nbrT1, wb_res2, E, ST + 4 * 1024, N1PTS);
    hipLaunchKernelGGL((bn_apply<false>), dim3(gBN1), dim3(256), 0, stream,
                       E, ST + 4 * 1024, gb_res2, invN1, N1PTS * 4);  // E = net

    // attention + residual add (writes r into D)
    hipLaunchKernelGGL(att_logits, dim3(gN1p), dim3(256), 0, stream,
                       E, wi, bi, L, (u32*)ATT, N1PTS);
    hipLaunchKernelGGL(att_accum, dim3(gN1p), dim3(256), 0, stream, E, L, ATT, N1PTS);
    hipLaunchKernelGGL(att_ctx_k, dim3(1), dim3(64), 0, stream, wk, bk, ATT);
    hipLaunchKernelGGL(att_out_res, dim3(gN1p), dim3(256), 0, stream,
                       E, C, wv, bv, wo, bo, ATT, D, N1PTS);          // D = r

    // upsample (K=8, src L2-resident)
    hipLaunchKernelGGL(conv_blk8, dim3(gB), dim3(1024), 0, stream,
                       D, nbrTu, wb_up, A, ST + 5 * 1024, NPTS);
    hipLaunchKernelGGL((bn_apply<true>), dim3(gBN), dim3(256), 0, stream,
                       A, ST + 5 * 1024, gb_up, invN, NPTS * 4);      // A = u_bn

    // fuse1: 4 k/source-split partials (cat never materialized)
    hipLaunchKernelGGL((conv_part<14>), dim3(gB), dim3(1024), 0, stream,
                       A, nbrT0, wb_f1A, T0, NPTS);
    hipLaunchKernelGGL((conv_part<13>), dim3(gB), dim3(1024), 0, stream,
                       A, nbrT0 + (size_t)KH0 * NPTS, wb_f1A + KH0 * 256, T1, NPTS);
    hipLaunchKernelGGL((conv_part<14>), dim3(gB), dim3(1024), 0, stream,
                       B, nbrT0, wb_f1B, T2, NPTS);
    hipLaunchKernelGGL((conv_part<13>), dim3(gB), dim3(1024), 0, stream,
                       B, nbrT0 + (size_t)KH0 * NPTS, wb_f1B + KH0 * 256, T3, NPTS);
    hipLaunchKernelGGL(conv_ds2, dim3(gS), dim3(256), 0, stream,
                       A, B, Wds, G, ST + 8 * 1024, NPTS);            // G = ds raw
    hipLaunchKernelGGL((merge_conv<4>), dim3(gBN), dim3(256), 0, stream,
                       T0, T1, T2, T3, A, ST + 6 * 1024, NPTS);       // A = fuse1 raw
    hipLaunchKernelGGL((bn_apply<true>), dim3(gBN), dim3(256), 0, stream,
                       A, ST + 6 * 1024, gb_fuse1, invN, NPTS * 4);

    // fuse2 (k-split)
    hipLaunchKernelGGL((conv_part<14>), dim3(gB), dim3(1024), 0, stream,
                       A, nbrT0, wb_fuse2, T0, NPTS);
    hipLaunchKernelGGL((conv_part<13>), dim3(gB), dim3(1024), 0, stream,
                       A, nbrT0 + (size_t)KH0 * NPTS, wb_fuse2 + KH0 * 256, T1, NPTS);
    hipLaunchKernelGGL((merge_conv<2>), dim3(gBN), dim3(256), 0, stream,
                       T0, T1, (const u16*)nullptr, (const u16*)nullptr, B, ST + 7 * 1024, NPTS);  // B = net2 raw

    // final fuse + classifier
    hipLaunchKernelGGL(final_cls, dim3(gN), dim3(256), 0, stream,
                       B, G, ST + 7 * 1024, ST + 8 * 1024, gb_fuse2, gb_ds,
                       Wcls, bcls, (float*)d_out, invN, NPTS);
}

// Round 13
// 493.115 us; speedup vs baseline: 1.1540x; 1.0023x over previous
//
#include <hip/hip_runtime.h>

typedef unsigned int u32;
typedef unsigned short u16;

#define NPTS 120000
#define N1PTS 15000
#define NCLSS 17
#define NSTRIPE 16

static inline int cdiv(int a, int b) { return (a + b - 1) / b; }

typedef __attribute__((ext_vector_type(8))) short bf16x8;
typedef __attribute__((ext_vector_type(4))) float f32x4;

// bf16 helpers (storage-only bf16; math fp32)
__device__ __forceinline__ float bflo(u32 u) { return __uint_as_float(u << 16); }
__device__ __forceinline__ float bfhi(u32 u) { return __uint_as_float(u & 0xFFFF0000u); }
__device__ __forceinline__ u32 f2bf(float f) {   // RNE
    u32 u = __float_as_uint(f);
    return (u + 0x7FFFu + ((u >> 16) & 1u)) >> 16;
}
__device__ __forceinline__ u32 pack2(float a, float b) { return f2bf(a) | (f2bf(b) << 16); }
// fp16 (RNE) for partial-sum buffers
__device__ __forceinline__ u16 f2h(float f) { _Float16 h = (_Float16)f; return __builtin_bit_cast(u16, h); }
__device__ __forceinline__ float h2f(u16 b) { return (float)__builtin_bit_cast(_Float16, b); }

__device__ __forceinline__ f32x4 mfma16(bf16x8 a, uint4 b, f32x4 c) {
    return __builtin_amdgcn_mfma_f32_16x16x32_bf16(a, __builtin_bit_cast(bf16x8, b), c, 0, 0, 0);
}

// ---------------- nbr transpose: nbrT[k*M + p] = nbr[p*K + k] ----------------
template<int K>
__global__ __launch_bounds__(256) void transpose_nbr(
    const int* __restrict__ nbr, int* __restrict__ nbrT, int M)
{
    __shared__ int tile[256][K + 1];
    int p0 = blockIdx.x * 256;
    int t = threadIdx.x;
    int np = M - p0; if (np > 256) np = 256;
    int total = np * K;
    for (int i = t; i < total; i += 256) {
        int lp = i / K, k = i - lp * K;
        tile[lp][k] = nbr[(size_t)p0 * K + i];
    }
    __syncthreads();
    if (t < np) {
#pragma unroll
        for (int k = 0; k < K; ++k)
            nbrT[(size_t)k * M + p0 + t] = tile[t][k];
    }
}

// ---------------- weight -> B-fragment conversion (hi/lo bf16 split) ----------------
struct WbArgs {
    const float* src[8];
    uint4* dst[8];
    int CINF[8];
    int COFF[8];
    int K2[8];    // 2*K
};

__global__ __launch_bounds__(64) void convert_wb(WbArgs a) {
    int j = blockIdx.y;
    int s2 = blockIdx.x;
    if (s2 >= a.K2[j]) return;
    int lane = threadIdx.x;
    int k = s2 >> 1, tile = s2 & 1;
    int c = a.COFF[j] + (lane >> 4) * 8;
    int o = tile * 16 + (lane & 15);
    const float* w = a.src[j] + ((size_t)k * a.CINF[j] + c) * 32 + o;
    u32 hw[4], lw[4];
#pragma unroll
    for (int q = 0; q < 4; ++q) {
        float w0 = w[(2 * q) * 32], w1 = w[(2 * q + 1) * 32];
        u32 h0 = f2bf(w0), h1 = f2bf(w1);
        float r0 = w0 - __uint_as_float(h0 << 16);
        float r1 = w1 - __uint_as_float(h1 << 16);
        hw[q] = h0 | (h1 << 16);
        lw[q] = f2bf(r0) | (f2bf(r1) << 16);
    }
    uint4 hv; hv.x = hw[0]; hv.y = hw[1]; hv.z = hw[2]; hv.w = hw[3];
    uint4 lv; lv.x = lw[0]; lv.y = lw[1]; lv.z = lw[2]; lv.w = lw[3];
    a.dst[j][(size_t)(s2 * 2 + 0) * 64 + lane] = hv;
    a.dst[j][(size_t)(s2 * 2 + 1) * 64 + lane] = lv;
}

// ---------------- conv_part: k-range partial conv, fp16 partial output, no stats ----------------
// 16 waves x 16 points; weights+idx in LDS (~72 KB -> 2 blocks/CU = 32 waves); depth-3 prefetch.
template<int KB>
__global__ __launch_bounds__(1024, 8) void conv_part(
    const u16* __restrict__ src, const int* __restrict__ nbrTk,
    const uint4* __restrict__ wb, u16* __restrict__ outh, int M)
{
    __shared__ uint4 wl[KB * 256];
    __shared__ int il[KB * 256];
    int tid = threadIdx.x;
    int lane = tid & 63, wid = tid >> 6;
    int p0 = blockIdx.x * 256 + wid * 16;
    int row = lane & 15, hi4 = lane >> 4;
    int lpt = wid * 16 + row;
    const uint4 z4 = {0u, 0u, 0u, 0u};

    for (int i = tid; i < KB * 256; i += 1024) wl[i] = wb[i];
    for (int i = tid; i < KB * 256; i += 1024) {
        int k = i >> 8, pl = i & 255;
        int pp = blockIdx.x * 256 + pl;
        il[i] = (pp < M) ? nbrTk[(size_t)k * M + pp] : -1;
    }

    f32x4 acc0 = {0.f, 0.f, 0.f, 0.f};
    f32x4 acc1 = {0.f, 0.f, 0.f, 0.f};

    __syncthreads();

    auto gld = [&](int k) -> uint4 {
        int idx = il[(k << 8) + lpt];
        int j = idx >= 0 ? idx : 0;
        uint4 v = reinterpret_cast<const uint4*>(src + (size_t)j * 32)[hi4];
        u32 m = (idx >= 0) ? 0xFFFFFFFFu : 0u;
        uint4 r; r.x = v.x & m; r.y = v.y & m; r.z = v.z & m; r.w = v.w & m;
        return r;
    };

    uint4 g0 = gld(0);
    uint4 g1 = (KB > 1) ? gld(1) : z4;
    uint4 g2 = (KB > 2) ? gld(2) : z4;

#pragma unroll 1
    for (int k = 0; k < KB; ++k) {
        uint4 gn = (k + 3 < KB) ? gld(k + 3) : z4;
        const uint4* bl = &wl[k * 256];
        bf16x8 a = __builtin_bit_cast(bf16x8, g0);
        acc0 = mfma16(a, bl[lane], acc0);
        acc0 = mfma16(a, bl[64 + lane], acc0);
        acc1 = mfma16(a, bl[128 + lane], acc1);
        acc1 = mfma16(a, bl[192 + lane], acc1);
        g0 = g1; g1 = g2; g2 = gn;
    }

#pragma unroll
    for (int r = 0; r < 4; ++r) {
        int pp = p0 + hi4 * 4 + r;
        if (pp < M) {
            outh[(size_t)pp * 32 + (lane & 15)] = f2h(acc0[r]);
            outh[(size_t)pp * 32 + 16 + (lane & 15)] = f2h(acc1[r]);
        }
    }
}

// ---------------- merge NB fp16 partials -> bf16 out + striped stats ----------------
template<int NB>
__global__ __launch_bounds__(256) void merge_conv(
    const u16* __restrict__ t0, const u16* __restrict__ t1,
    const u16* __restrict__ t2, const u16* __restrict__ t3,
    u16* __restrict__ out, float* __restrict__ stats, int M)
{
    __shared__ float ssum[32], ssq[32];
    int tid = threadIdx.x;
    if (tid < 32) { ssum[tid] = 0.f; ssq[tid] = 0.f; }
    __syncthreads();
    int i = blockIdx.x * 256 + tid;
    int total = M * 4;
    int c0 = (i & 3) * 8;
    float v[8];
#pragma unroll
    for (int j = 0; j < 8; ++j) v[j] = 0.f;
    if (i < total) {
        uint4 a0 = reinterpret_cast<const uint4*>(t0)[i];
        uint4 a1 = reinterpret_cast<const uint4*>(t1)[i];
        u32 w0[4] = { a0.x, a0.y, a0.z, a0.w };
        u32 w1[4] = { a1.x, a1.y, a1.z, a1.w };
#pragma unroll
        for (int q = 0; q < 4; ++q) {
            v[2 * q]     = h2f((u16)(w0[q] & 0xFFFF)) + h2f((u16)(w1[q] & 0xFFFF));
            v[2 * q + 1] = h2f((u16)(w0[q] >> 16)) + h2f((u16)(w1[q] >> 16));
        }
        if (NB == 4) {
            uint4 a2 = reinterpret_cast<const uint4*>(t2)[i];
            uint4 a3 = reinterpret_cast<const uint4*>(t3)[i];
            u32 w2[4] = { a2.x, a2.y, a2.z, a2.w };
            u32 w3[4] = { a3.x, a3.y, a3.z, a3.w };
#pragma unroll
            for (int q = 0; q < 4; ++q) {
                v[2 * q]     += h2f((u16)(w2[q] & 0xFFFF)) + h2f((u16)(w3[q] & 0xFFFF));
                v[2 * q + 1] += h2f((u16)(w2[q] >> 16)) + h2f((u16)(w3[q] >> 16));
            }
        }
        u32 r[4];
#pragma unroll
        for (int q = 0; q < 4; ++q) r[q] = pack2(v[2 * q], v[2 * q + 1]);
        uint4 o; o.x = r[0]; o.y = r[1]; o.z = r[2]; o.w = r[3];
        reinterpret_cast<uint4*>(out)[i] = o;
    }
#pragma unroll
    for (int j = 0; j < 8; ++j) {
        atomicAdd(&ssum[c0 + j], v[j]);
        atomicAdd(&ssq[c0 + j], v[j] * v[j]);
    }
    __syncthreads();
    if (tid < 32) {
        float* sst = stats + ((blockIdx.x & (NSTRIPE - 1)) << 6);
        atomicAdd(&sst[tid], ssum[tid]);
        atomicAdd(&sst[32 + tid], ssq[tid]);
    }
}

// ---------------- conv_blk8: full K=8 conv, bf16 out + striped stats ----------------
__global__ __launch_bounds__(1024, 8) void conv_blk8(
    const u16* __restrict__ src, const int* __restrict__ nbrT,
    const uint4* __restrict__ wb, u16* __restrict__ out,
    float* __restrict__ stats, int M)
{
    constexpr int K = 8;
    __shared__ uint4 wl[K * 256];
    __shared__ int il[K * 256];
    __shared__ float red[15][64];
    int tid = threadIdx.x;
    int lane = tid & 63, wid = tid >> 6;
    int p0 = blockIdx.x * 256 + wid * 16;
    int row = lane & 15, hi4 = lane >> 4;
    int lpt = wid * 16 + row;
    const uint4 z4 = {0u, 0u, 0u, 0u};

    for (int i = tid; i < K * 256; i += 1024) wl[i] = wb[i];
    for (int i = tid; i < K * 256; i += 1024) {
        int k = i >> 8, pl = i & 255;
        int pp = blockIdx.x * 256 + pl;
        il[i] = (pp < M) ? nbrT[(size_t)k * M + pp] : -1;
    }

    f32x4 acc0 = {0.f, 0.f, 0.f, 0.f};
    f32x4 acc1 = {0.f, 0.f, 0.f, 0.f};

    __syncthreads();

    auto gld = [&](int k) -> uint4 {
        int idx = il[(k << 8) + lpt];
        int j = idx >= 0 ? idx : 0;
        uint4 v = reinterpret_cast<const uint4*>(src + (size_t)j * 32)[hi4];
        u32 m = (idx >= 0) ? 0xFFFFFFFFu : 0u;
        uint4 r; r.x = v.x & m; r.y = v.y & m; r.z = v.z & m; r.w = v.w & m;
        return r;
    };

    uint4 g0 = gld(0);
    uint4 g1 = gld(1);
    uint4 g2 = gld(2);

#pragma unroll 1
    for (int k = 0; k < K; ++k) {
        uint4 gn = (k + 3 < K) ? gld(k + 3) : z4;
        const uint4* bl = &wl[k * 256];
        bf16x8 a = __builtin_bit_cast(bf16x8, g0);
        acc0 = mfma16(a, bl[lane], acc0);
        acc0 = mfma16(a, bl[64 + lane], acc0);
        acc1 = mfma16(a, bl[128 + lane], acc1);
        acc1 = mfma16(a, bl[192 + lane], acc1);
        g0 = g1; g1 = g2; g2 = gn;
    }

#pragma unroll
    for (int r = 0; r < 4; ++r) {
        int pp = p0 + hi4 * 4 + r;
        if (pp < M) {
            out[(size_t)pp * 32 + (lane & 15)] = (u16)f2bf(acc0[r]);
            out[(size_t)pp * 32 + 16 + (lane & 15)] = (u16)f2bf(acc1[r]);
        }
    }

    float s0 = 0.f, q0 = 0.f, s1 = 0.f, q1 = 0.f;
#pragma unroll
    for (int r = 0; r < 4; ++r) {
        s0 += acc0[r]; q0 += acc0[r] * acc0[r];
        s1 += acc1[r]; q1 += acc1[r] * acc1[r];
    }
#pragma unroll
    for (int m = 16; m <= 32; m <<= 1) {
        s0 += __shfl_xor(s0, m, 64); q0 += __shfl_xor(q0, m, 64);
        s1 += __shfl_xor(s1, m, 64); q1 += __shfl_xor(q1, m, 64);
    }
    float val = (lane < 16) ? s0 : (lane < 32) ? s1 : (lane < 48) ? q0 : q1;
    if (wid > 0) red[wid - 1][lane] = val;
    __syncthreads();
    if (wid == 0) {
        float t = val;
#pragma unroll
        for (int w = 0; w < 15; ++w) t += red[w][lane];
        atomicAdd(&stats[((blockIdx.x & (NSTRIPE - 1)) << 6) + lane], t);
    }
}

// ---------------- conv_mfma: 4-wave version for small N1 grids ----------------
template<int K>
__global__ __launch_bounds__(256, 6) void conv_mfma(
    const u16* __restrict__ src, const int* __restrict__ nbrT,
    const uint4* __restrict__ wb, u16* __restrict__ out,
    float* __restrict__ stats, int M)
{
    constexpr int KS = K;
    constexpr int NCH = (KS + 1) / 2;
    __shared__ uint4 wlds[2][512];
    __shared__ float red[4][64];

    int tid = threadIdx.x;
    int lane = tid & 63, wid = tid >> 6;
    int p0 = blockIdx.x * 64 + wid * 16;
    int row = lane & 15, hi4 = lane >> 4;
    int p = p0 + row;
    bool rowok = p < M;
    const uint4 z4 = {0u, 0u, 0u, 0u};

    f32x4 acc0 = {0.f, 0.f, 0.f, 0.f};
    f32x4 acc1 = {0.f, 0.f, 0.f, 0.f};

    {
        uint4 a0 = wb[tid], a1 = wb[256 + tid];
        wlds[0][tid] = a0; wlds[0][256 + tid] = a1;
    }
    uint4 av0 = z4, av1 = z4;
    {
        int iA = -1, iB = -1;
        if (rowok) {
            iA = nbrT[p];
            if (KS > 1) iB = nbrT[(size_t)M + p];
        }
        if (iA >= 0) av0 = reinterpret_cast<const uint4*>(src + (size_t)iA * 32)[hi4];
        if (KS > 1 && iB >= 0) av1 = reinterpret_cast<const uint4*>(src + (size_t)iB * 32)[hi4];
    }

    uint4 wr0 = z4, wr1 = z4;
#pragma unroll 1
    for (int c = 0; c < NCH; ++c) {
        bool last = (c + 1 >= NCH);
        if (!last) {
            wr0 = wb[(size_t)(c + 1) * 512 + tid];
            wr1 = wb[(size_t)(c + 1) * 512 + 256 + tid];
        }
        int nA = -1, nB = -1;
        if (!last && rowok) {
            int s0 = 2 * c + 2;
            nA = nbrT[(size_t)s0 * M + p];
            if (s0 + 1 < KS) nB = nbrT[(size_t)(s0 + 1) * M + p];
        }
        asm volatile("s_waitcnt lgkmcnt(0)" ::: "memory");
        __builtin_amdgcn_s_barrier();
        asm volatile("" ::: "memory");
        uint4 nav0 = z4, nav1 = z4;
        if (nA >= 0) nav0 = reinterpret_cast<const uint4*>(src + (size_t)nA * 32)[hi4];
        if (nB >= 0) nav1 = reinterpret_cast<const uint4*>(src + (size_t)nB * 32)[hi4];

        const uint4* bl = wlds[c & 1];
        {
            bf16x8 a = __builtin_bit_cast(bf16x8, av0);
            acc0 = mfma16(a, bl[lane], acc0);
            acc0 = mfma16(a, bl[64 + lane], acc0);
            acc1 = mfma16(a, bl[128 + lane], acc1);
            acc1 = mfma16(a, bl[192 + lane], acc1);
        }
        if (2 * c + 1 < KS) {
            bf16x8 a = __builtin_bit_cast(bf16x8, av1);
            acc0 = mfma16(a, bl[256 + lane], acc0);
            acc0 = mfma16(a, bl[320 + lane], acc0);
            acc1 = mfma16(a, bl[384 + lane], acc1);
            acc1 = mfma16(a, bl[448 + lane], acc1);
        }
        if (!last) {
            wlds[(c + 1) & 1][tid] = wr0;
            wlds[(c + 1) & 1][256 + tid] = wr1;
        }
        av0 = nav0; av1 = nav1;
    }

#pragma unroll
    for (int r = 0; r < 4; ++r) {
        int pp = p0 + hi4 * 4 + r;
        if (pp < M) {
            out[(size_t)pp * 32 + (lane & 15)] = (u16)f2bf(acc0[r]);
            out[(size_t)pp * 32 + 16 + (lane & 15)] = (u16)f2bf(acc1[r]);
        }
    }

    float s0 = 0.f, q0 = 0.f, s1 = 0.f, q1 = 0.f;
#pragma unroll
    for (int r = 0; r < 4; ++r) {
        s0 += acc0[r]; q0 += acc0[r] * acc0[r];
        s1 += acc1[r]; q1 += acc1[r] * acc1[r];
    }
#pragma unroll
    for (int m = 16; m <= 32; m <<= 1) {
        s0 += __shfl_xor(s0, m, 64); q0 += __shfl_xor(q0, m, 64);
        s1 += __shfl_xor(s1, m, 64); q1 += __shfl_xor(q1, m, 64);
    }
    float val = (lane < 16) ? s0 : (lane < 32) ? s1 : (lane < 48) ? q0 : q1;
    red[wid][lane] = val;
    __syncthreads();
    if (wid == 0) {
        float t = red[0][lane] + red[1][lane] + red[2][lane] + red[3][lane];
        atomicAdd(&stats[((blockIdx.x & (NSTRIPE - 1)) << 6) + lane], t);
    }
}

// ---------------- shared scalar epilogue (conv_x3, conv_ds2) — striped stats ----------------
__device__ __forceinline__ void reduce_store_stats(
    float (&acc)[32], int lane, int wid, bool act, int p,
    u16* __restrict__ out, float* __restrict__ sst)
{
    __shared__ float lds[3][64][17];
#pragma unroll
    for (int r = 0; r < 2; ++r) {
        if (wid > 0) {
#pragma unroll
            for (int j = 0; j < 16; ++j) lds[wid - 1][lane][j] = acc[r * 16 + j];
        }
        __syncthreads();
        if (wid == 0) {
#pragma unroll
            for (int w = 0; w < 3; ++w)
#pragma unroll
                for (int j = 0; j < 16; ++j) acc[r * 16 + j] += lds[w][lane][j];
        }
        __syncthreads();
    }
    if (wid == 0) {
        if (act) {
            u32 wd[16];
#pragma unroll
            for (int q = 0; q < 16; ++q) wd[q] = pack2(acc[2 * q], acc[2 * q + 1]);
            uint4* dst = reinterpret_cast<uint4*>(out + (size_t)p * 32);
            uint4 v;
            v.x = wd[0];  v.y = wd[1];  v.z = wd[2];  v.w = wd[3];  dst[0] = v;
            v.x = wd[4];  v.y = wd[5];  v.z = wd[6];  v.w = wd[7];  dst[1] = v;
            v.x = wd[8];  v.y = wd[9];  v.z = wd[10]; v.w = wd[11]; dst[2] = v;
            v.x = wd[12]; v.y = wd[13]; v.z = wd[14]; v.w = wd[15]; dst[3] = v;
        } else {
#pragma unroll
            for (int o = 0; o < 32; ++o) acc[o] = 0.f;
        }
        float sel1 = 0.f, sel2 = 0.f;
#pragma unroll
        for (int o = 0; o < 32; ++o) {
            float s1 = acc[o], s2 = acc[o] * acc[o];
#pragma unroll
            for (int m = 1; m <= 32; m <<= 1) { s1 += __shfl_xor(s1, m, 64); s2 += __shfl_xor(s2, m, 64); }
            if (lane == o) sel1 = s1;
            if (lane == o + 32) sel2 = s2;
        }
        atomicAdd(&sst[lane], lane < 32 ? sel1 : sel2);
    }
}

__global__ __launch_bounds__(256, 8) void conv_x3(
    const float* __restrict__ src, const int* __restrict__ nbrT,
    const float* __restrict__ W, u16* __restrict__ out,
    float* __restrict__ stats, int M)
{
    constexpr int K = 27;
    int lane = threadIdx.x & 63;
    int wid = __builtin_amdgcn_readfirstlane(threadIdx.x >> 6);
    int p = blockIdx.x * 64 + lane;
    bool act = p < M;
    constexpr int JMAX = 7;

    float acc[32];
#pragma unroll
    for (int o = 0; o < 32; ++o) acc[o] = 0.f;

    int idxs[JMAX];
#pragma unroll
    for (int j = 0; j < JMAX; ++j) {
        int k = wid + 4 * j;
        idxs[j] = (act && k < K) ? nbrT[(size_t)k * M + p] : -1;
    }
#pragma unroll
    for (int j = 0; j < JMAX; ++j) {
        int k = wid + 4 * j;
        if (k >= K) break;
        int idx = idxs[j];
        if (idx >= 0) {
            const float* __restrict__ xr = src + (size_t)idx * 3;
            const float* __restrict__ wk = W + (size_t)k * 3 * 32;
            float x0 = xr[0], x1 = xr[1], x2 = xr[2];
#pragma unroll
            for (int o = 0; o < 32; ++o) {
                float s = fmaf(x0, wk[o], 0.f);
                s = fmaf(x1, wk[32 + o], s);
                acc[o] += fmaf(x2, wk[64 + o], s);
            }
        }
    }
    reduce_store_stats(acc, lane, wid, act, p, out,
                       stats + ((blockIdx.x & (NSTRIPE - 1)) << 6));
}

// ---------------- ds 1x1 conv from two 32-ch sources (u_bn, x0) ----------------
__global__ __launch_bounds__(256, 4) void conv_ds2(
    const u16* __restrict__ u, const u16* __restrict__ x0,
    const float* __restrict__ W, u16* __restrict__ out,
    float* __restrict__ stats, int M)
{
    int lane = threadIdx.x & 63;
    int wid = __builtin_amdgcn_readfirstlane(threadIdx.x >> 6);
    int p = blockIdx.x * 64 + lane;
    bool act = p < M;

    float acc[32];
#pragma unroll
    for (int o = 0; o < 32; ++o) acc[o] = 0.f;

    if (act) {
        const u16* srcp = (wid < 2) ? u : x0;
        const uint4* xr = reinterpret_cast<const uint4*>(srcp + (size_t)p * 32 + (wid & 1) * 16);
        const float* wk = W + (size_t)wid * 16 * 32;
#pragma unroll
        for (int h = 0; h < 2; ++h) {
            uint4 v = xr[h];
            float xv[8] = { bflo(v.x), bfhi(v.x), bflo(v.y), bfhi(v.y),
                            bflo(v.z), bfhi(v.z), bflo(v.w), bfhi(v.w) };
#pragma unroll
            for (int c = 0; c < 8; ++c)
#pragma unroll
                for (int o = 0; o < 32; ++o)
                    acc[o] = fmaf(xv[c], wk[(h * 8 + c) * 32 + o], acc[o]);
        }
    }
    reduce_store_stats(acc, lane, wid, act, p, out,
                       stats + ((blockIdx.x & (NSTRIPE - 1)) << 6));
}

// ---------------- bn apply: sums 16 stripes once per block, then y = a*x + b ----------------
template<bool RELU>
__global__ __launch_bounds__(256) void bn_apply(
    u16* __restrict__ buf, const float* __restrict__ stats,
    const float* __restrict__ gb, float invM, int total)
{
    __shared__ float ab[64];
    if (threadIdx.x < 32) {
        int c = threadIdx.x;
        float s = 0.f, q = 0.f;
#pragma unroll
        for (int st = 0; st < NSTRIPE; ++st) {
            s += stats[st * 64 + c];
            q += stats[st * 64 + 32 + c];
        }
        float mu = s * invM;
        float var = fmaxf(q * invM - mu * mu, 0.f);
        float a = gb[c] * rsqrtf(var + 1e-5f);
        ab[c] = a;
        ab[32 + c] = gb[32 + c] - mu * a;
    }
    __syncthreads();
    int i = blockIdx.x * 256 + threadIdx.x;
    if (i >= total) return;
    int c0 = (i & 3) * 8;
    uint4 v = reinterpret_cast<uint4*>(buf)[i];
    u32 w[4] = { v.x, v.y, v.z, v.w };
    u32 r[4];
#pragma unroll
    for (int q = 0; q < 4; ++q) {
        int c = c0 + 2 * q;
        float y0 = fmaf(ab[c], bflo(w[q]), ab[32 + c]);
        float y1 = fmaf(ab[c + 1], bfhi(w[q]), ab[32 + c + 1]);
        if (RELU) { y0 = fmaxf(y0, 0.f); y1 = fmaxf(y1, 0.f); }
        r[q] = pack2(y0, y1);
    }
    uint4 o; o.x = r[0]; o.y = r[1]; o.z = r[2]; o.w = r[3];
    reinterpret_cast<uint4*>(buf)[i] = o;
}

// ---------------- attention ----------------
__device__ __forceinline__ void load_row32(const u16* __restrict__ base, int p, float (&nv)[32])
{
    const uint4* xr = reinterpret_cast<const uint4*>(base + (size_t)p * 32);
#pragma unroll
    for (int q = 0; q < 4; ++q) {
        uint4 v = xr[q];
        nv[q * 8 + 0] = bflo(v.x); nv[q * 8 + 1] = bfhi(v.x);
        nv[q * 8 + 2] = bflo(v.y); nv[q * 8 + 3] = bfhi(v.y);
        nv[q * 8 + 4] = bflo(v.z); nv[q * 8 + 5] = bfhi(v.z);
        nv[q * 8 + 6] = bflo(v.w); nv[q * 8 + 7] = bfhi(v.w);
    }
}

__global__ __launch_bounds__(256) void att_logits(
    const u16* __restrict__ net, const float* __restrict__ wi,
    const float* __restrict__ bi, float* __restrict__ lbuf,
    u32* __restrict__ mx, int M)
{
    int p = blockIdx.x * 256 + threadIdx.x;
    float l = -3.0e38f;
    if (p < M) {
        float nv[32];
        load_row32(net, p, nv);
        float s = bi[0];
#pragma unroll
        for (int c = 0; c < 32; ++c) s = fmaf(nv[c], wi[c], s);
        lbuf[p] = s;
        l = s;
    }
#pragma unroll
    for (int m = 1; m <= 32; m <<= 1) l = fmaxf(l, __shfl_xor(l, m, 64));
    if ((threadIdx.x & 63) == 0) {
        u32 b = __float_as_uint(l);
        u32 e = (b & 0x80000000u) ? ~b : (b | 0x80000000u);
        atomicMax(mx, e);
    }
}

__global__ __launch_bounds__(256) void att_accum(
    const u16* __restrict__ net, const float* __restrict__ lbuf,
    float* __restrict__ att, int M)
{
    int p = blockIdx.x * 256 + threadIdx.x;
    int lane = threadIdx.x & 63, wid = threadIdx.x >> 6;
    u32 um = __float_as_uint(att[0]);
    float mx = (um & 0x80000000u) ? __uint_as_float(um ^ 0x80000000u) : __uint_as_float(~um);
    float w = 0.f;
    float nv[32];
#pragma unroll
    for (int c = 0; c < 32; ++c) nv[c] = 0.f;
    if (p < M) {
        w = expf(lbuf[p] - mx);
        load_row32(net, p, nv);
    }
    float sel = 0.f;
#pragma unroll
    for (int c = 0; c < 32; ++c) {
        float s = w * nv[c];
#pragma unroll
        for (int m = 1; m <= 32; m <<= 1) s += __shfl_xor(s, m, 64);
        if (lane == c) sel = s;
    }
    {
        float s = w;
#pragma unroll
        for (int m = 1; m <= 32; m <<= 1) s += __shfl_xor(s, m, 64);
        if (lane == 32) sel = s;
    }
    __shared__ float red[4][33];
    if (lane < 33) red[wid][lane] = sel;
    __syncthreads();
    if (wid == 0 && lane < 33) {
        float t = red[0][lane] + red[1][lane] + red[2][lane] + red[3][lane];
        atomicAdd(lane < 32 ? &att[2 + lane] : &att[1], t);
    }
}

__global__ void att_ctx_k(const float* __restrict__ wk, const float* __restrict__ bk,
                          float* __restrict__ att)
{
    int o = threadIdx.x;
    if (o >= 32) return;
    float invS = 1.0f / att[1];
    float s = bk[o];
#pragma unroll
    for (int c = 0; c < 32; ++c) s = fmaf(att[2 + c] * invS, wk[c * 32 + o], s);
    att[34 + o] = s;
}

__global__ __launch_bounds__(256) void att_out_res(
    const u16* __restrict__ net, const u16* __restrict__ d,
    const float* __restrict__ wv, const float* __restrict__ bv,
    const float* __restrict__ wo, const float* __restrict__ bo,
    const float* __restrict__ att, u16* __restrict__ r, int M)
{
    int p = blockIdx.x * 256 + threadIdx.x;
    if (p >= M) return;
    float nv[32];
    load_row32(net, p, nv);
    float vv[32];
#pragma unroll
    for (int o = 0; o < 32; ++o) {
        float s = bv[o];
#pragma unroll
        for (int c = 0; c < 32; ++c) s = fmaf(nv[c], wv[c * 32 + o], s);
        vv[o] = s * att[34 + o];
    }
    float dv[32];
    load_row32(d, p, dv);
    u32 wd[16];
#pragma unroll
    for (int q = 0; q < 16; ++q) {
        float y[2];
#pragma unroll
        for (int t = 0; t < 2; ++t) {
            int oo = 2 * q + t;
            float s = bo[oo];
#pragma unroll
            for (int o = 0; o < 32; ++o) s = fmaf(vv[o], wo[o * 32 + oo], s);
            y[t] = fmaxf(s + dv[oo], 0.f);
        }
        wd[q] = pack2(y[0], y[1]);
    }
    uint4* dst = reinterpret_cast<uint4*>(r + (size_t)p * 32);
    uint4 v;
    v.x = wd[0];  v.y = wd[1];  v.z = wd[2];  v.w = wd[3];  dst[0] = v;
    v.x = wd[4];  v.y = wd[5];  v.z = wd[6];  v.w = wd[7];  dst[1] = v;
    v.x = wd[8];  v.y = wd[9];  v.z = wd[10]; v.w = wd[11]; dst[2] = v;
    v.x = wd[12]; v.y = wd[13]; v.z = wd[14]; v.w = wd[15]; dst[3] = v;
}

// ---------------- final: y = relu(bn(net2) + bn(ds)); out = y@Wcls + bcls ----------------
__global__ __launch_bounds__(256) void final_cls(
    const u16* __restrict__ net2, const u16* __restrict__ dsr,
    const float* __restrict__ st7, const float* __restrict__ st8,
    const float* __restrict__ gb7, const float* __restrict__ gb8,
    const float* __restrict__ wcls, const float* __restrict__ bcls,
    float* __restrict__ outp, float invM, int M)
{
    __shared__ float ab7[64], ab8[64];
    if (threadIdx.x < 64) {
        int c = threadIdx.x & 31;
        const float* st = (threadIdx.x < 32) ? st7 : st8;
        const float* g  = (threadIdx.x < 32) ? gb7 : gb8;
        float* abp      = (threadIdx.x < 32) ? ab7 : ab8;
        float s = 0.f, q = 0.f;
#pragma unroll
        for (int k = 0; k < NSTRIPE; ++k) {
            s += st[k * 64 + c];
            q += st[k * 64 + 32 + c];
        }
        float mu = s * invM;
        float var = fmaxf(q * invM - mu * mu, 0.f);
        float a = g[c] * rsqrtf(var + 1e-5f);
        abp[c] = a;
        abp[32 + c] = g[32 + c] - mu * a;
    }
    __syncthreads();
    int p = blockIdx.x * 256 + threadIdx.x;
    if (p >= M) return;
    float nv[32], dv[32];
    load_row32(net2, p, nv);
    load_row32(dsr, p, dv);
    float y[32];
#pragma unroll
    for (int c = 0; c < 32; ++c) {
        float t = fmaf(ab7[c], nv[c], ab7[32 + c]) + fmaf(ab8[c], dv[c], ab8[32 + c]);
        y[c] = fmaxf(t, 0.f);
    }
#pragma unroll
    for (int j = 0; j < NCLSS; ++j) {
        float s = bcls[j];
#pragma unroll
        for (int c = 0; c < 32; ++c) s = fmaf(y[c], wcls[c * NCLSS + j], s);
        outp[(size_t)p * NCLSS + j] = s;
    }
}

// ---------------- host ----------------
extern "C" void kernel_launch(void* const* d_in, const int* in_sizes, int n_in,
                              void* d_out, int out_size, void* d_ws, size_t ws_size,
                              hipStream_t stream)
{
    char* wsb = (char*)d_ws;

    float* ST  = (float*)wsb;                        // 9216 floats + ATT
    float* ATT = ST + 9216;
    float* L   = (float*)(wsb + 65536);              // N1 logits fp32
    const size_t SZN = 7680000ull;                   // N*32*2 bytes
    const size_t SZ1 = 960000ull;                    // N1*32*2 bytes
    u16* A  = (u16*)(wsb + 131072);
    u16* B  = (u16*)(wsb + 131072 + SZN);
    u16* C  = (u16*)(wsb + 131072 + 2 * SZN);
    u16* D  = (u16*)(wsb + 131072 + 2 * SZN + SZ1);
    u16* E  = (u16*)(wsb + 131072 + 2 * SZN + 2 * SZ1);
    u16* G  = (u16*)(wsb + 131072 + 2 * SZN + 3 * SZ1);
    u16* T0 = (u16*)(wsb + 131072 + 3 * SZN + 3 * SZ1);          // fp16 partials
    u16* T1 = (u16*)(wsb + 131072 + 4 * SZN + 3 * SZ1);
    u16* T2 = (u16*)(wsb + 131072 + 5 * SZN + 3 * SZ1);
    u16* T3 = (u16*)(wsb + 131072 + 6 * SZN + 3 * SZ1);

    size_t wboff = 131072 + 7 * SZN + 3 * SZ1;
    auto wbsz = [](int K) { return (size_t)((K + 1) & ~1) * 4096; };
    uint4* wb_stem1 = (uint4*)(wsb + wboff);         size_t o1 = wboff + wbsz(27);
    uint4* wb_down  = (uint4*)(wsb + o1);            size_t o2 = o1 + wbsz(8);
    uint4* wb_res1  = (uint4*)(wsb + o2);            size_t o3 = o2 + wbsz(27);
    uint4* wb_res2  = (uint4*)(wsb + o3);            size_t o4 = o3 + wbsz(27);
    uint4* wb_up    = (uint4*)(wsb + o4);            size_t o5 = o4 + wbsz(8);
    uint4* wb_f1A   = (uint4*)(wsb + o5);            size_t o6 = o5 + wbsz(27);
    uint4* wb_f1B   = (uint4*)(wsb + o6);            size_t o7 = o6 + wbsz(27);
    uint4* wb_fuse2 = (uint4*)(wsb + o7);            size_t o8 = o7 + wbsz(27);

    int* nbrT0 = (int*)(wsb + o8);                   size_t o9  = o8 + 27ull * NPTS * 4;
    int* nbrTd = (int*)(wsb + o9);                   size_t o10 = o9 + 8ull * N1PTS * 4;
    int* nbrT1 = (int*)(wsb + o10);                  size_t o11 = o10 + 27ull * N1PTS * 4;
    int* nbrTu = (int*)(wsb + o11);

    const float* X        = (const float*)d_in[0];
    const float* Wstem0   = (const float*)d_in[1];
    const float* gb_stem0 = (const float*)d_in[2];
    const float* Wstem1   = (const float*)d_in[3];
    const float* gb_stem1 = (const float*)d_in[4];
    const float* Wdown    = (const float*)d_in[5];
    const float* gb_down  = (const float*)d_in[6];
    const float* Wres1    = (const float*)d_in[7];
    const float* gb_res1  = (const float*)d_in[8];
    const float* Wres2    = (const float*)d_in[9];
    const float* gb_res2  = (const float*)d_in[10];
    const float* wi = (const float*)d_in[11];
    const float* bi = (const float*)d_in[12];
    const float* wk = (const float*)d_in[13];
    const float* bk = (const float*)d_in[14];
    const float* wv = (const float*)d_in[15];
    const float* bv = (const float*)d_in[16];
    const float* wo = (const float*)d_in[17];
    const float* bo = (const float*)d_in[18];
    const float* Wup      = (const float*)d_in[19];
    const float* gb_up    = (const float*)d_in[20];
    const float* Wfuse1   = (const float*)d_in[21];
    const float* gb_fuse1 = (const float*)d_in[22];
    const float* Wfuse2   = (const float*)d_in[23];
    const float* gb_fuse2 = (const float*)d_in[24];
    const float* Wds      = (const float*)d_in[25];
    const float* gb_ds    = (const float*)d_in[26];
    const float* Wcls     = (const float*)d_in[27];
    const float* bcls     = (const float*)d_in[28];

    const int* nbr0     = (const int*)d_in[29];
    const int* nbr_down = (const int*)d_in[30];
    const int* nbr1     = (const int*)d_in[31];
    const int* nbr_up   = (const int*)d_in[32];

    const float invN  = 1.0f / (float)NPTS;
    const float invN1 = 1.0f / (float)N1PTS;

    hipMemsetAsync((void*)ST, 0, (9216 + 66) * sizeof(float), stream);

    hipLaunchKernelGGL((transpose_nbr<27>), dim3(cdiv(NPTS, 256)), dim3(256), 0, stream,
                       nbr0, nbrT0, NPTS);
    hipLaunchKernelGGL((transpose_nbr<8>), dim3(cdiv(N1PTS, 256)), dim3(256), 0, stream,
                       nbr_down, nbrTd, N1PTS);
    hipLaunchKernelGGL((transpose_nbr<27>), dim3(cdiv(N1PTS, 256)), dim3(256), 0, stream,
                       nbr1, nbrT1, N1PTS);
    hipLaunchKernelGGL((transpose_nbr<8>), dim3(cdiv(NPTS, 256)), dim3(256), 0, stream,
                       nbr_up, nbrTu, NPTS);

    {
        WbArgs a;
        a.src[0] = Wstem1; a.dst[0] = wb_stem1; a.CINF[0] = 32; a.COFF[0] = 0;  a.K2[0] = 54;
        a.src[1] = Wdown;  a.dst[1] = wb_down;  a.CINF[1] = 32; a.COFF[1] = 0;  a.K2[1] = 16;
        a.src[2] = Wres1;  a.dst[2] = wb_res1;  a.CINF[2] = 32; a.COFF[2] = 0;  a.K2[2] = 54;
        a.src[3] = Wres2;  a.dst[3] = wb_res2;  a.CINF[3] = 32; a.COFF[3] = 0;  a.K2[3] = 54;
        a.src[4] = Wup;    a.dst[4] = wb_up;    a.CINF[4] = 32; a.COFF[4] = 0;  a.K2[4] = 16;
        a.src[5] = Wfuse1; a.dst[5] = wb_f1A;   a.CINF[5] = 64; a.COFF[5] = 0;  a.K2[5] = 54;
        a.src[6] = Wfuse1; a.dst[6] = wb_f1B;   a.CINF[6] = 64; a.COFF[6] = 32; a.K2[6] = 54;
        a.src[7] = Wfuse2; a.dst[7] = wb_fuse2; a.CINF[7] = 32; a.COFF[7] = 0;  a.K2[7] = 54;
        hipLaunchKernelGGL(convert_wb, dim3(54, 8), dim3(64), 0, stream, a);
    }

    const int gS   = cdiv(NPTS, 64);     // conv_x3, conv_ds2
    const int gB   = cdiv(NPTS, 256);    // conv_part / conv_blk8 (469)
    const int gM1  = cdiv(N1PTS, 64);    // conv_mfma N1
    const int gBN  = cdiv(NPTS * 4, 256);
    const int gBN1 = cdiv(N1PTS * 4, 256);
    const int gN1p = cdiv(N1PTS, 256);
    const int gN   = cdiv(NPTS, 256);
    const int KH0 = 14, KH1 = 13;        // 27 = 14 + 13 k-split

    // stem
    hipLaunchKernelGGL(conv_x3, dim3(gS), dim3(256), 0, stream,
                       X, nbrT0, Wstem0, A, ST + 0 * 1024, NPTS);
    hipLaunchKernelGGL((bn_apply<true>), dim3(gBN), dim3(256), 0, stream,
                       A, ST + 0 * 1024, gb_stem0, invN, NPTS * 4);
    // stem1 (k-split halves -> fp16 partials -> merge)
    hipLaunchKernelGGL((conv_part<14>), dim3(gB), dim3(1024), 0, stream,
                       A, nbrT0, wb_stem1, T0, NPTS);
    hipLaunchKernelGGL((conv_part<13>), dim3(gB), dim3(1024), 0, stream,
                       A, nbrT0 + (size_t)KH0 * NPTS, wb_stem1 + KH0 * 256, T1, NPTS);
    hipLaunchKernelGGL((merge_conv<2>), dim3(gBN), dim3(256), 0, stream,
                       T0, T1, (const u16*)nullptr, (const u16*)nullptr, B, ST + 1 * 1024, NPTS);
    hipLaunchKernelGGL((bn_apply<true>), dim3(gBN), dim3(256), 0, stream,
                       B, ST + 1 * 1024, gb_stem1, invN, NPTS * 4);   // B = x0

    // downsample
    hipLaunchKernelGGL((conv_mfma<8>), dim3(gM1), dim3(256), 0, stream,
                       B, nbrTd, wb_down, C, ST + 2 * 1024, N1PTS);
    hipLaunchKernelGGL((bn_apply<true>), dim3(gBN1), dim3(256), 0, stream,
                       C, ST + 2 * 1024, gb_down, invN1, N1PTS * 4);  // C = d

    // residual block convs
    hipLaunchKernelGGL((conv_mfma<27>), dim3(gM1), dim3(256), 0, stream,
                       C, nbrT1, wb_res1, D, ST + 3 * 1024, N1PTS);
    hipLaunchKernelGGL((bn_apply<true>), dim3(gBN1), dim3(256), 0, stream,
                       D, ST + 3 * 1024, gb_res1, invN1, N1PTS * 4);
    hipLaunchKernelGGL((conv_mfma<27>), dim3(gM1), dim3(256), 0, stream,
                       D, nbrT1, wb_res2, E, ST + 4 * 1024, N1PTS);
    hipLaunchKernelGGL((bn_apply<false>), dim3(gBN1), dim3(256), 0, stream,
                       E, ST + 4 * 1024, gb_res2, invN1, N1PTS * 4);  // E = net

    // attention + residual add (writes r into D)
    hipLaunchKernelGGL(att_logits, dim3(gN1p), dim3(256), 0, stream,
                       E, wi, bi, L, (u32*)ATT, N1PTS);
    hipLaunchKernelGGL(att_accum, dim3(gN1p), dim3(256), 0, stream, E, L, ATT, N1PTS);
    hipLaunchKernelGGL(att_ctx_k, dim3(1), dim3(64), 0, stream, wk, bk, ATT);
    hipLaunchKernelGGL(att_out_res, dim3(gN1p), dim3(256), 0, stream,
                       E, C, wv, bv, wo, bo, ATT, D, N1PTS);          // D = r

    // upsample (K=8, src L2-resident)
    hipLaunchKernelGGL(conv_blk8, dim3(gB), dim3(1024), 0, stream,
                       D, nbrTu, wb_up, A, ST + 5 * 1024, NPTS);
    hipLaunchKernelGGL((bn_apply<true>), dim3(gBN), dim3(256), 0, stream,
                       A, ST + 5 * 1024, gb_up, invN, NPTS * 4);      // A = u_bn

    // fuse1: 4 k/source-split partials (cat never materialized)
    hipLaunchKernelGGL((conv_part<14>), dim3(gB), dim3(1024), 0, stream,
                       A, nbrT0, wb_f1A, T0, NPTS);
    hipLaunchKernelGGL((conv_part<13>), dim3(gB), dim3(1024), 0, stream,
                       A, nbrT0 + (size_t)KH0 * NPTS, wb_f1A + KH0 * 256, T1, NPTS);
    hipLaunchKernelGGL((conv_part<14>), dim3(gB), dim3(1024), 0, stream,
                       B, nbrT0, wb_f1B, T2, NPTS);
    hipLaunchKernelGGL((conv_part<13>), dim3(gB), dim3(1024), 0, stream,
                       B, nbrT0 + (size_t)KH0 * NPTS, wb_f1B + KH0 * 256, T3, NPTS);
    hipLaunchKernelGGL(conv_ds2, dim3(gS), dim3(256), 0, stream,
                       A, B, Wds, G, ST + 8 * 1024, NPTS);            // G = ds raw
    hipLaunchKernelGGL((merge_conv<4>), dim3(gBN), dim3(256), 0, stream,
                       T0, T1, T2, T3, A, ST + 6 * 1024, NPTS);       // A = fuse1 raw
    hipLaunchKernelGGL((bn_apply<true>), dim3(gBN), dim3(256), 0, stream,
                       A, ST + 6 * 1024, gb_fuse1, invN, NPTS * 4);

    // fuse2 (k-split)
    hipLaunchKernelGGL((conv_part<14>), dim3(gB), dim3(1024), 0, stream,
                       A, nbrT0, wb_fuse2, T0, NPTS);
    hipLaunchKernelGGL((conv_part<13>), dim3(gB), dim3(1024), 0, stream,
                       A, nbrT0 + (size_t)KH0 * NPTS, wb_fuse2 + KH0 * 256, T1, NPTS);
    hipLaunchKernelGGL((merge_conv<2>), dim3(gBN), dim3(256), 0, stream,
                       T0, T1, (const u16*)nullptr, (const u16*)nullptr, B, ST + 7 * 1024, NPTS);  // B = net2 raw

    // final fuse + classifier
    hipLaunchKernelGGL(final_cls, dim3(gN), dim3(256), 0, stream,
                       B, G, ST + 7 * 1024, ST + 8 * 1024, gb_fuse2, gb_ds,
                       Wcls, bcls, (float*)d_out, invN, NPTS);
}

// Round 14
// 375.623 us; speedup vs baseline: 1.5149x; 1.3128x over previous
//
#include <hip/hip_runtime.h>

typedef unsigned int u32;
typedef unsigned short u16;

#define NPTS 120000
#define N1PTS 15000
#define NCLSS 17
#define NSTRIPE 16

static inline int cdiv(int a, int b) { return (a + b - 1) / b; }

typedef __attribute__((ext_vector_type(8))) short bf16x8;
typedef __attribute__((ext_vector_type(4))) float f32x4;

// bf16 helpers (storage-only bf16; math fp32)
__device__ __forceinline__ float bflo(u32 u) { return __uint_as_float(u << 16); }
__device__ __forceinline__ float bfhi(u32 u) { return __uint_as_float(u & 0xFFFF0000u); }
__device__ __forceinline__ u32 f2bf(float f) {   // RNE
    u32 u = __float_as_uint(f);
    return (u + 0x7FFFu + ((u >> 16) & 1u)) >> 16;
}
__device__ __forceinline__ u32 pack2(float a, float b) { return f2bf(a) | (f2bf(b) << 16); }

__device__ __forceinline__ f32x4 mfma16(bf16x8 a, uint4 b, f32x4 c) {
    return __builtin_amdgcn_mfma_f32_16x16x32_bf16(a, __builtin_bit_cast(bf16x8, b), c, 0, 0, 0);
}

// ---------------- nbr transpose: nbrT[k*M + p] = nbr[p*K + k] ----------------
template<int K>
__global__ __launch_bounds__(256) void transpose_nbr(
    const int* __restrict__ nbr, int* __restrict__ nbrT, int M)
{
    __shared__ int tile[256][K + 1];
    int p0 = blockIdx.x * 256;
    int t = threadIdx.x;
    int np = M - p0; if (np > 256) np = 256;
    int total = np * K;
    for (int i = t; i < total; i += 256) {
        int lp = i / K, k = i - lp * K;
        tile[lp][k] = nbr[(size_t)p0 * K + i];
    }
    __syncthreads();
    if (t < np) {
#pragma unroll
        for (int k = 0; k < K; ++k)
            nbrT[(size_t)k * M + p0 + t] = tile[t][k];
    }
}

// ---------------- weight -> B-fragment conversion (hi/lo bf16 split) ----------------
struct WbArgs {
    const float* src[8];
    uint4* dst[8];
    int CINF[8];
    int COFF[8];
    int K2[8];    // 2*K
};

__global__ __launch_bounds__(64) void convert_wb(WbArgs a) {
    int j = blockIdx.y;
    int s2 = blockIdx.x;
    if (s2 >= a.K2[j]) return;
    int lane = threadIdx.x;
    int k = s2 >> 1, tile = s2 & 1;
    int c = a.COFF[j] + (lane >> 4) * 8;
    int o = tile * 16 + (lane & 15);
    const float* w = a.src[j] + ((size_t)k * a.CINF[j] + c) * 32 + o;
    u32 hw[4], lw[4];
#pragma unroll
    for (int q = 0; q < 4; ++q) {
        float w0 = w[(2 * q) * 32], w1 = w[(2 * q + 1) * 32];
        u32 h0 = f2bf(w0), h1 = f2bf(w1);
        float r0 = w0 - __uint_as_float(h0 << 16);
        float r1 = w1 - __uint_as_float(h1 << 16);
        hw[q] = h0 | (h1 << 16);
        lw[q] = f2bf(r0) | (f2bf(r1) << 16);
    }
    uint4 hv; hv.x = hw[0]; hv.y = hw[1]; hv.z = hw[2]; hv.w = hw[3];
    uint4 lv; lv.x = lw[0]; lv.y = lw[1]; lv.z = lw[2]; lv.w = lw[3];
    a.dst[j][(size_t)(s2 * 2 + 0) * 64 + lane] = hv;
    a.dst[j][(size_t)(s2 * 2 + 1) * 64 + lane] = lv;
}

// ---------------- conv_part: k-range partial conv, fp32-chained accumulation ----------------
// 16 waves x 16 points; weights+idx in LDS; depth-3 prefetch; barrier-free k-loop.
// MODE 0: acc=0, write fp32 T.  MODE 1: acc=T, write fp32 T.
// MODE 2: acc=T, write bf16 out + striped stats (butterfly, no LDS atomics).
template<int KB, int MODE>
__global__ __launch_bounds__(1024, 8) void conv_part(
    const u16* __restrict__ src, const int* __restrict__ nbrTk,
    const uint4* __restrict__ wb, float* __restrict__ T,
    u16* __restrict__ out, float* __restrict__ stats, int M)
{
    __shared__ uint4 wl[KB * 256];
    __shared__ int il[KB * 256];
    __shared__ float red[15][64];
    int tid = threadIdx.x;
    int lane = tid & 63, wid = tid >> 6;
    int p0 = blockIdx.x * 256 + wid * 16;
    int row = lane & 15, hi4 = lane >> 4;
    int lpt = wid * 16 + row;
    int col = lane & 15;
    const uint4 z4 = {0u, 0u, 0u, 0u};

    for (int i = tid; i < KB * 256; i += 1024) wl[i] = wb[i];
    for (int i = tid; i < KB * 256; i += 1024) {
        int k = i >> 8, pl = i & 255;
        int pp = blockIdx.x * 256 + pl;
        il[i] = (pp < M) ? nbrTk[(size_t)k * M + pp] : -1;
    }

    f32x4 acc0, acc1;
    if (MODE >= 1) {
#pragma unroll
        for (int r = 0; r < 4; ++r) {
            int pp = p0 + hi4 * 4 + r;
            int ps = pp < M ? pp : 0;
            acc0[r] = T[(size_t)ps * 32 + col];
            acc1[r] = T[(size_t)ps * 32 + 16 + col];
        }
    } else {
        acc0 = {0.f, 0.f, 0.f, 0.f};
        acc1 = {0.f, 0.f, 0.f, 0.f};
    }

    __syncthreads();

    auto gld = [&](int k) -> uint4 {
        int idx = il[(k << 8) + lpt];
        int j = idx >= 0 ? idx : 0;
        uint4 v = reinterpret_cast<const uint4*>(src + (size_t)j * 32)[hi4];
        u32 m = (idx >= 0) ? 0xFFFFFFFFu : 0u;
        uint4 r; r.x = v.x & m; r.y = v.y & m; r.z = v.z & m; r.w = v.w & m;
        return r;
    };

    uint4 g0 = gld(0);
    uint4 g1 = (KB > 1) ? gld(1) : z4;
    uint4 g2 = (KB > 2) ? gld(2) : z4;

#pragma unroll 1
    for (int k = 0; k < KB; ++k) {
        uint4 gn = (k + 3 < KB) ? gld(k + 3) : z4;
        const uint4* bl = &wl[k * 256];
        bf16x8 a = __builtin_bit_cast(bf16x8, g0);
        acc0 = mfma16(a, bl[lane], acc0);
        acc0 = mfma16(a, bl[64 + lane], acc0);
        acc1 = mfma16(a, bl[128 + lane], acc1);
        acc1 = mfma16(a, bl[192 + lane], acc1);
        g0 = g1; g1 = g2; g2 = gn;
    }

    if (MODE <= 1) {
#pragma unroll
        for (int r = 0; r < 4; ++r) {
            int pp = p0 + hi4 * 4 + r;
            if (pp < M) {
                T[(size_t)pp * 32 + col] = acc0[r];
                T[(size_t)pp * 32 + 16 + col] = acc1[r];
            }
        }
        return;
    }

    // MODE 2: bf16 store + striped stats
#pragma unroll
    for (int r = 0; r < 4; ++r) {
        int pp = p0 + hi4 * 4 + r;
        if (pp < M) {
            out[(size_t)pp * 32 + col] = (u16)f2bf(acc0[r]);
            out[(size_t)pp * 32 + 16 + col] = (u16)f2bf(acc1[r]);
        }
    }
    float s0 = 0.f, q0 = 0.f, s1 = 0.f, q1 = 0.f;
#pragma unroll
    for (int r = 0; r < 4; ++r) {
        s0 += acc0[r]; q0 += acc0[r] * acc0[r];
        s1 += acc1[r]; q1 += acc1[r] * acc1[r];
    }
#pragma unroll
    for (int m = 16; m <= 32; m <<= 1) {
        s0 += __shfl_xor(s0, m, 64); q0 += __shfl_xor(q0, m, 64);
        s1 += __shfl_xor(s1, m, 64); q1 += __shfl_xor(q1, m, 64);
    }
    float val = (lane < 16) ? s0 : (lane < 32) ? s1 : (lane < 48) ? q0 : q1;
    if (wid > 0) red[wid - 1][lane] = val;
    __syncthreads();
    if (wid == 0) {
        float t = val;
#pragma unroll
        for (int w = 0; w < 15; ++w) t += red[w][lane];
        atomicAdd(&stats[((blockIdx.x & (NSTRIPE - 1)) << 6) + lane], t);
    }
}

// ---------------- conv_blk8: full K=8 conv, bf16 out + striped stats ----------------
__global__ __launch_bounds__(1024, 8) void conv_blk8(
    const u16* __restrict__ src, const int* __restrict__ nbrT,
    const uint4* __restrict__ wb, u16* __restrict__ out,
    float* __restrict__ stats, int M)
{
    constexpr int K = 8;
    __shared__ uint4 wl[K * 256];
    __shared__ int il[K * 256];
    __shared__ float red[15][64];
    int tid = threadIdx.x;
    int lane = tid & 63, wid = tid >> 6;
    int p0 = blockIdx.x * 256 + wid * 16;
    int row = lane & 15, hi4 = lane >> 4;
    int lpt = wid * 16 + row;
    const uint4 z4 = {0u, 0u, 0u, 0u};

    for (int i = tid; i < K * 256; i += 1024) wl[i] = wb[i];
    for (int i = tid; i < K * 256; i += 1024) {
        int k = i >> 8, pl = i & 255;
        int pp = blockIdx.x * 256 + pl;
        il[i] = (pp < M) ? nbrT[(size_t)k * M + pp] : -1;
    }

    f32x4 acc0 = {0.f, 0.f, 0.f, 0.f};
    f32x4 acc1 = {0.f, 0.f, 0.f, 0.f};

    __syncthreads();

    auto gld = [&](int k) -> uint4 {
        int idx = il[(k << 8) + lpt];
        int j = idx >= 0 ? idx : 0;
        uint4 v = reinterpret_cast<const uint4*>(src + (size_t)j * 32)[hi4];
        u32 m = (idx >= 0) ? 0xFFFFFFFFu : 0u;
        uint4 r; r.x = v.x & m; r.y = v.y & m; r.z = v.z & m; r.w = v.w & m;
        return r;
    };

    uint4 g0 = gld(0);
    uint4 g1 = gld(1);
    uint4 g2 = gld(2);

#pragma unroll 1
    for (int k = 0; k < K; ++k) {
        uint4 gn = (k + 3 < K) ? gld(k + 3) : z4;
        const uint4* bl = &wl[k * 256];
        bf16x8 a = __builtin_bit_cast(bf16x8, g0);
        acc0 = mfma16(a, bl[lane], acc0);
        acc0 = mfma16(a, bl[64 + lane], acc0);
        acc1 = mfma16(a, bl[128 + lane], acc1);
        acc1 = mfma16(a, bl[192 + lane], acc1);
        g0 = g1; g1 = g2; g2 = gn;
    }

#pragma unroll
    for (int r = 0; r < 4; ++r) {
        int pp = p0 + hi4 * 4 + r;
        if (pp < M) {
            out[(size_t)pp * 32 + (lane & 15)] = (u16)f2bf(acc0[r]);
            out[(size_t)pp * 32 + 16 + (lane & 15)] = (u16)f2bf(acc1[r]);
        }
    }

    float s0 = 0.f, q0 = 0.f, s1 = 0.f, q1 = 0.f;
#pragma unroll
    for (int r = 0; r < 4; ++r) {
        s0 += acc0[r]; q0 += acc0[r] * acc0[r];
        s1 += acc1[r]; q1 += acc1[r] * acc1[r];
    }
#pragma unroll
    for (int m = 16; m <= 32; m <<= 1) {
        s0 += __shfl_xor(s0, m, 64); q0 += __shfl_xor(q0, m, 64);
        s1 += __shfl_xor(s1, m, 64); q1 += __shfl_xor(q1, m, 64);
    }
    float val = (lane < 16) ? s0 : (lane < 32) ? s1 : (lane < 48) ? q0 : q1;
    if (wid > 0) red[wid - 1][lane] = val;
    __syncthreads();
    if (wid == 0) {
        float t = val;
#pragma unroll
        for (int w = 0; w < 15; ++w) t += red[w][lane];
        atomicAdd(&stats[((blockIdx.x & (NSTRIPE - 1)) << 6) + lane], t);
    }
}

// ---------------- conv_mfma: 4-wave version for small N1 grids ----------------
template<int K>
__global__ __launch_bounds__(256, 6) void conv_mfma(
    const u16* __restrict__ src, const int* __restrict__ nbrT,
    const uint4* __restrict__ wb, u16* __restrict__ out,
    float* __restrict__ stats, int M)
{
    constexpr int KS = K;
    constexpr int NCH = (KS + 1) / 2;
    __shared__ uint4 wlds[2][512];
    __shared__ float red[4][64];

    int tid = threadIdx.x;
    int lane = tid & 63, wid = tid >> 6;
    int p0 = blockIdx.x * 64 + wid * 16;
    int row = lane & 15, hi4 = lane >> 4;
    int p = p0 + row;
    bool rowok = p < M;
    const uint4 z4 = {0u, 0u, 0u, 0u};

    f32x4 acc0 = {0.f, 0.f, 0.f, 0.f};
    f32x4 acc1 = {0.f, 0.f, 0.f, 0.f};

    {
        uint4 a0 = wb[tid], a1 = wb[256 + tid];
        wlds[0][tid] = a0; wlds[0][256 + tid] = a1;
    }
    uint4 av0 = z4, av1 = z4;
    {
        int iA = -1, iB = -1;
        if (rowok) {
            iA = nbrT[p];
            if (KS > 1) iB = nbrT[(size_t)M + p];
        }
        if (iA >= 0) av0 = reinterpret_cast<const uint4*>(src + (size_t)iA * 32)[hi4];
        if (KS > 1 && iB >= 0) av1 = reinterpret_cast<const uint4*>(src + (size_t)iB * 32)[hi4];
    }

    uint4 wr0 = z4, wr1 = z4;
#pragma unroll 1
    for (int c = 0; c < NCH; ++c) {
        bool last = (c + 1 >= NCH);
        if (!last) {
            wr0 = wb[(size_t)(c + 1) * 512 + tid];
            wr1 = wb[(size_t)(c + 1) * 512 + 256 + tid];
        }
        int nA = -1, nB = -1;
        if (!last && rowok) {
            int s0 = 2 * c + 2;
            nA = nbrT[(size_t)s0 * M + p];
            if (s0 + 1 < KS) nB = nbrT[(size_t)(s0 + 1) * M + p];
        }
        asm volatile("s_waitcnt lgkmcnt(0)" ::: "memory");
        __builtin_amdgcn_s_barrier();
        asm volatile("" ::: "memory");
        uint4 nav0 = z4, nav1 = z4;
        if (nA >= 0) nav0 = reinterpret_cast<const uint4*>(src + (size_t)nA * 32)[hi4];
        if (nB >= 0) nav1 = reinterpret_cast<const uint4*>(src + (size_t)nB * 32)[hi4];

        const uint4* bl = wlds[c & 1];
        {
            bf16x8 a = __builtin_bit_cast(bf16x8, av0);
            acc0 = mfma16(a, bl[lane], acc0);
            acc0 = mfma16(a, bl[64 + lane], acc0);
            acc1 = mfma16(a, bl[128 + lane], acc1);
            acc1 = mfma16(a, bl[192 + lane], acc1);
        }
        if (2 * c + 1 < KS) {
            bf16x8 a = __builtin_bit_cast(bf16x8, av1);
            acc0 = mfma16(a, bl[256 + lane], acc0);
            acc0 = mfma16(a, bl[320 + lane], acc0);
            acc1 = mfma16(a, bl[384 + lane], acc1);
            acc1 = mfma16(a, bl[448 + lane], acc1);
        }
        if (!last) {
            wlds[(c + 1) & 1][tid] = wr0;
            wlds[(c + 1) & 1][256 + tid] = wr1;
        }
        av0 = nav0; av1 = nav1;
    }

#pragma unroll
    for (int r = 0; r < 4; ++r) {
        int pp = p0 + hi4 * 4 + r;
        if (pp < M) {
            out[(size_t)pp * 32 + (lane & 15)] = (u16)f2bf(acc0[r]);
            out[(size_t)pp * 32 + 16 + (lane & 15)] = (u16)f2bf(acc1[r]);
        }
    }

    float s0 = 0.f, q0 = 0.f, s1 = 0.f, q1 = 0.f;
#pragma unroll
    for (int r = 0; r < 4; ++r) {
        s0 += acc0[r]; q0 += acc0[r] * acc0[r];
        s1 += acc1[r]; q1 += acc1[r] * acc1[r];
    }
#pragma unroll
    for (int m = 16; m <= 32; m <<= 1) {
        s0 += __shfl_xor(s0, m, 64); q0 += __shfl_xor(q0, m, 64);
        s1 += __shfl_xor(s1, m, 64); q1 += __shfl_xor(q1, m, 64);
    }
    float val = (lane < 16) ? s0 : (lane < 32) ? s1 : (lane < 48) ? q0 : q1;
    red[wid][lane] = val;
    __syncthreads();
    if (wid == 0) {
        float t = red[0][lane] + red[1][lane] + red[2][lane] + red[3][lane];
        atomicAdd(&stats[((blockIdx.x & (NSTRIPE - 1)) << 6) + lane], t);
    }
}

// ---------------- shared scalar epilogue (conv_x3, conv_ds2) — striped stats ----------------
__device__ __forceinline__ void reduce_store_stats(
    float (&acc)[32], int lane, int wid, bool act, int p,
    u16* __restrict__ out, float* __restrict__ sst)
{
    __shared__ float lds[3][64][17];
#pragma unroll
    for (int r = 0; r < 2; ++r) {
        if (wid > 0) {
#pragma unroll
            for (int j = 0; j < 16; ++j) lds[wid - 1][lane][j] = acc[r * 16 + j];
        }
        __syncthreads();
        if (wid == 0) {
#pragma unroll
            for (int w = 0; w < 3; ++w)
#pragma unroll
                for (int j = 0; j < 16; ++j) acc[r * 16 + j] += lds[w][lane][j];
        }
        __syncthreads();
    }
    if (wid == 0) {
        if (act) {
            u32 wd[16];
#pragma unroll
            for (int q = 0; q < 16; ++q) wd[q] = pack2(acc[2 * q], acc[2 * q + 1]);
            uint4* dst = reinterpret_cast<uint4*>(out + (size_t)p * 32);
            uint4 v;
            v.x = wd[0];  v.y = wd[1];  v.z = wd[2];  v.w = wd[3];  dst[0] = v;
            v.x = wd[4];  v.y = wd[5];  v.z = wd[6];  v.w = wd[7];  dst[1] = v;
            v.x = wd[8];  v.y = wd[9];  v.z = wd[10]; v.w = wd[11]; dst[2] = v;
            v.x = wd[12]; v.y = wd[13]; v.z = wd[14]; v.w = wd[15]; dst[3] = v;
        } else {
#pragma unroll
            for (int o = 0; o < 32; ++o) acc[o] = 0.f;
        }
        float sel1 = 0.f, sel2 = 0.f;
#pragma unroll
        for (int o = 0; o < 32; ++o) {
            float s1 = acc[o], s2 = acc[o] * acc[o];
#pragma unroll
            for (int m = 1; m <= 32; m <<= 1) { s1 += __shfl_xor(s1, m, 64); s2 += __shfl_xor(s2, m, 64); }
            if (lane == o) sel1 = s1;
            if (lane == o + 32) sel2 = s2;
        }
        atomicAdd(&sst[lane], lane < 32 ? sel1 : sel2);
    }
}

__global__ __launch_bounds__(256, 8) void conv_x3(
    const float* __restrict__ src, const int* __restrict__ nbrT,
    const float* __restrict__ W, u16* __restrict__ out,
    float* __restrict__ stats, int M)
{
    constexpr int K = 27;
    int lane = threadIdx.x & 63;
    int wid = __builtin_amdgcn_readfirstlane(threadIdx.x >> 6);
    int p = blockIdx.x * 64 + lane;
    bool act = p < M;
    constexpr int JMAX = 7;

    float acc[32];
#pragma unroll
    for (int o = 0; o < 32; ++o) acc[o] = 0.f;

    int idxs[JMAX];
#pragma unroll
    for (int j = 0; j < JMAX; ++j) {
        int k = wid + 4 * j;
        idxs[j] = (act && k < K) ? nbrT[(size_t)k * M + p] : -1;
    }
#pragma unroll
    for (int j = 0; j < JMAX; ++j) {
        int k = wid + 4 * j;
        if (k >= K) break;
        int idx = idxs[j];
        if (idx >= 0) {
            const float* __restrict__ xr = src + (size_t)idx * 3;
            const float* __restrict__ wk = W + (size_t)k * 3 * 32;
            float x0 = xr[0], x1 = xr[1], x2 = xr[2];
#pragma unroll
            for (int o = 0; o < 32; ++o) {
                float s = fmaf(x0, wk[o], 0.f);
                s = fmaf(x1, wk[32 + o], s);
                acc[o] += fmaf(x2, wk[64 + o], s);
            }
        }
    }
    reduce_store_stats(acc, lane, wid, act, p, out,
                       stats + ((blockIdx.x & (NSTRIPE - 1)) << 6));
}

// ---------------- ds 1x1 conv from two 32-ch sources (u_bn, x0) ----------------
__global__ __launch_bounds__(256, 4) void conv_ds2(
    const u16* __restrict__ u, const u16* __restrict__ x0,
    const float* __restrict__ W, u16* __restrict__ out,
    float* __restrict__ stats, int M)
{
    int lane = threadIdx.x & 63;
    int wid = __builtin_amdgcn_readfirstlane(threadIdx.x >> 6);
    int p = blockIdx.x * 64 + lane;
    bool act = p < M;

    float acc[32];
#pragma unroll
    for (int o = 0; o < 32; ++o) acc[o] = 0.f;

    if (act) {
        const u16* srcp = (wid < 2) ? u : x0;
        const uint4* xr = reinterpret_cast<const uint4*>(srcp + (size_t)p * 32 + (wid & 1) * 16);
        const float* wk = W + (size_t)wid * 16 * 32;
#pragma unroll
        for (int h = 0; h < 2; ++h) {
            uint4 v = xr[h];
            float xv[8] = { bflo(v.x), bfhi(v.x), bflo(v.y), bfhi(v.y),
                            bflo(v.z), bfhi(v.z), bflo(v.w), bfhi(v.w) };
#pragma unroll
            for (int c = 0; c < 8; ++c)
#pragma unroll
                for (int o = 0; o < 32; ++o)
                    acc[o] = fmaf(xv[c], wk[(h * 8 + c) * 32 + o], acc[o]);
        }
    }
    reduce_store_stats(acc, lane, wid, act, p, out,
                       stats + ((blockIdx.x & (NSTRIPE - 1)) << 6));
}

// ---------------- bn apply: sums 16 stripes once per block, then y = a*x + b ----------------
template<bool RELU>
__global__ __launch_bounds__(256) void bn_apply(
    u16* __restrict__ buf, const float* __restrict__ stats,
    const float* __restrict__ gb, float invM, int total)
{
    __shared__ float ab[64];
    if (threadIdx.x < 32) {
        int c = threadIdx.x;
        float s = 0.f, q = 0.f;
#pragma unroll
        for (int st = 0; st < NSTRIPE; ++st) {
            s += stats[st * 64 + c];
            q += stats[st * 64 + 32 + c];
        }
        float mu = s * invM;
        float var = fmaxf(q * invM - mu * mu, 0.f);
        float a = gb[c] * rsqrtf(var + 1e-5f);
        ab[c] = a;
        ab[32 + c] = gb[32 + c] - mu * a;
    }
    __syncthreads();
    int i = blockIdx.x * 256 + threadIdx.x;
    if (i >= total) return;
    int c0 = (i & 3) * 8;
    uint4 v = reinterpret_cast<uint4*>(buf)[i];
    u32 w[4] = { v.x, v.y, v.z, v.w };
    u32 r[4];
#pragma unroll
    for (int q = 0; q < 4; ++q) {
        int c = c0 + 2 * q;
        float y0 = fmaf(ab[c], bflo(w[q]), ab[32 + c]);
        float y1 = fmaf(ab[c + 1], bfhi(w[q]), ab[32 + c + 1]);
        if (RELU) { y0 = fmaxf(y0, 0.f); y1 = fmaxf(y1, 0.f); }
        r[q] = pack2(y0, y1);
    }
    uint4 o; o.x = r[0]; o.y = r[1]; o.z = r[2]; o.w = r[3];
    reinterpret_cast<uint4*>(buf)[i] = o;
}

// ---------------- attention ----------------
__device__ __forceinline__ void load_row32(const u16* __restrict__ base, int p, float (&nv)[32])
{
    const uint4* xr = reinterpret_cast<const uint4*>(base + (size_t)p * 32);
#pragma unroll
    for (int q = 0; q < 4; ++q) {
        uint4 v = xr[q];
        nv[q * 8 + 0] = bflo(v.x); nv[q * 8 + 1] = bfhi(v.x);
        nv[q * 8 + 2] = bflo(v.y); nv[q * 8 + 3] = bfhi(v.y);
        nv[q * 8 + 4] = bflo(v.z); nv[q * 8 + 5] = bfhi(v.z);
        nv[q * 8 + 6] = bflo(v.w); nv[q * 8 + 7] = bfhi(v.w);
    }
}

__global__ __launch_bounds__(256) void att_logits(
    const u16* __restrict__ net, const float* __restrict__ wi,
    const float* __restrict__ bi, float* __restrict__ lbuf,
    u32* __restrict__ mx, int M)
{
    int p = blockIdx.x * 256 + threadIdx.x;
    float l = -3.0e38f;
    if (p < M) {
        float nv[32];
        load_row32(net, p, nv);
        float s = bi[0];
#pragma unroll
        for (int c = 0; c < 32; ++c) s = fmaf(nv[c], wi[c], s);
        lbuf[p] = s;
        l = s;
    }
#pragma unroll
    for (int m = 1; m <= 32; m <<= 1) l = fmaxf(l, __shfl_xor(l, m, 64));
    if ((threadIdx.x & 63) == 0) {
        u32 b = __float_as_uint(l);
        u32 e = (b & 0x80000000u) ? ~b : (b | 0x80000000u);
        atomicMax(mx, e);
    }
}

__global__ __launch_bounds__(256) void att_accum(
    const u16* __restrict__ net, const float* __restrict__ lbuf,
    float* __restrict__ att, int M)
{
    int p = blockIdx.x * 256 + threadIdx.x;
    int lane = threadIdx.x & 63, wid = threadIdx.x >> 6;
    u32 um = __float_as_uint(att[0]);
    float mx = (um & 0x80000000u) ? __uint_as_float(um ^ 0x80000000u) : __uint_as_float(~um);
    float w = 0.f;
    float nv[32];
#pragma unroll
    for (int c = 0; c < 32; ++c) nv[c] = 0.f;
    if (p < M) {
        w = expf(lbuf[p] - mx);
        load_row32(net, p, nv);
    }
    float sel = 0.f;
#pragma unroll
    for (int c = 0; c < 32; ++c) {
        float s = w * nv[c];
#pragma unroll
        for (int m = 1; m <= 32; m <<= 1) s += __shfl_xor(s, m, 64);
        if (lane == c) sel = s;
    }
    {
        float s = w;
#pragma unroll
        for (int m = 1; m <= 32; m <<= 1) s += __shfl_xor(s, m, 64);
        if (lane == 32) sel = s;
    }
    __shared__ float red[4][33];
    if (lane < 33) red[wid][lane] = sel;
    __syncthreads();
    if (wid == 0 && lane < 33) {
        float t = red[0][lane] + red[1][lane] + red[2][lane] + red[3][lane];
        atomicAdd(lane < 32 ? &att[2 + lane] : &att[1], t);
    }
}

__global__ void att_ctx_k(const float* __restrict__ wk, const float* __restrict__ bk,
                          float* __restrict__ att)
{
    int o = threadIdx.x;
    if (o >= 32) return;
    float invS = 1.0f / att[1];
    float s = bk[o];
#pragma unroll
    for (int c = 0; c < 32; ++c) s = fmaf(att[2 + c] * invS, wk[c * 32 + o], s);
    att[34 + o] = s;
}

__global__ __launch_bounds__(256) void att_out_res(
    const u16* __restrict__ net, const u16* __restrict__ d,
    const float* __restrict__ wv, const float* __restrict__ bv,
    const float* __restrict__ wo, const float* __restrict__ bo,
    const float* __restrict__ att, u16* __restrict__ r, int M)
{
    int p = blockIdx.x * 256 + threadIdx.x;
    if (p >= M) return;
    float nv[32];
    load_row32(net, p, nv);
    float vv[32];
#pragma unroll
    for (int o = 0; o < 32; ++o) {
        float s = bv[o];
#pragma unroll
        for (int c = 0; c < 32; ++c) s = fmaf(nv[c], wv[c * 32 + o], s);
        vv[o] = s * att[34 + o];
    }
    float dv[32];
    load_row32(d, p, dv);
    u32 wd[16];
#pragma unroll
    for (int q = 0; q < 16; ++q) {
        float y[2];
#pragma unroll
        for (int t = 0; t < 2; ++t) {
            int oo = 2 * q + t;
            float s = bo[oo];
#pragma unroll
            for (int o = 0; o < 32; ++o) s = fmaf(vv[o], wo[o * 32 + oo], s);
            y[t] = fmaxf(s + dv[oo], 0.f);
        }
        wd[q] = pack2(y[0], y[1]);
    }
    uint4* dst = reinterpret_cast<uint4*>(r + (size_t)p * 32);
    uint4 v;
    v.x = wd[0];  v.y = wd[1];  v.z = wd[2];  v.w = wd[3];  dst[0] = v;
    v.x = wd[4];  v.y = wd[5];  v.z = wd[6];  v.w = wd[7];  dst[1] = v;
    v.x = wd[8];  v.y = wd[9];  v.z = wd[10]; v.w = wd[11]; dst[2] = v;
    v.x = wd[12]; v.y = wd[13]; v.z = wd[14]; v.w = wd[15]; dst[3] = v;
}

// ---------------- final: y = relu(bn(net2) + bn(ds)); out = y@Wcls + bcls ----------------
__global__ __launch_bounds__(256) void final_cls(
    const u16* __restrict__ net2, const u16* __restrict__ dsr,
    const float* __restrict__ st7, const float* __restrict__ st8,
    const float* __restrict__ gb7, const float* __restrict__ gb8,
    const float* __restrict__ wcls, const float* __restrict__ bcls,
    float* __restrict__ outp, float invM, int M)
{
    __shared__ float ab7[64], ab8[64];
    if (threadIdx.x < 64) {
        int c = threadIdx.x & 31;
        const float* st = (threadIdx.x < 32) ? st7 : st8;
        const float* g  = (threadIdx.x < 32) ? gb7 : gb8;
        float* abp      = (threadIdx.x < 32) ? ab7 : ab8;
        float s = 0.f, q = 0.f;
#pragma unroll
        for (int k = 0; k < NSTRIPE; ++k) {
            s += st[k * 64 + c];
            q += st[k * 64 + 32 + c];
        }
        float mu = s * invM;
        float var = fmaxf(q * invM - mu * mu, 0.f);
        float a = g[c] * rsqrtf(var + 1e-5f);
        abp[c] = a;
        abp[32 + c] = g[32 + c] - mu * a;
    }
    __syncthreads();
    int p = blockIdx.x * 256 + threadIdx.x;
    if (p >= M) return;
    float nv[32], dv[32];
    load_row32(net2, p, nv);
    load_row32(dsr, p, dv);
    float y[32];
#pragma unroll
    for (int c = 0; c < 32; ++c) {
        float t = fmaf(ab7[c], nv[c], ab7[32 + c]) + fmaf(ab8[c], dv[c], ab8[32 + c]);
        y[c] = fmaxf(t, 0.f);
    }
#pragma unroll
    for (int j = 0; j < NCLSS; ++j) {
        float s = bcls[j];
#pragma unroll
        for (int c = 0; c < 32; ++c) s = fmaf(y[c], wcls[c * NCLSS + j], s);
        outp[(size_t)p * NCLSS + j] = s;
    }
}

// ---------------- host ----------------
extern "C" void kernel_launch(void* const* d_in, const int* in_sizes, int n_in,
                              void* d_out, int out_size, void* d_ws, size_t ws_size,
                              hipStream_t stream)
{
    char* wsb = (char*)d_ws;

    float* ST  = (float*)wsb;                        // 9216 floats + ATT
    float* ATT = ST + 9216;
    float* L   = (float*)(wsb + 65536);              // N1 logits fp32
    const size_t SZN = 7680000ull;                   // N*32*2 bytes
    const size_t SZ1 = 960000ull;                    // N1*32*2 bytes
    u16* A  = (u16*)(wsb + 131072);
    u16* B  = (u16*)(wsb + 131072 + SZN);
    u16* C  = (u16*)(wsb + 131072 + 2 * SZN);
    u16* D  = (u16*)(wsb + 131072 + 2 * SZN + SZ1);
    u16* E  = (u16*)(wsb + 131072 + 2 * SZN + 2 * SZ1);
    u16* G  = (u16*)(wsb + 131072 + 2 * SZN + 3 * SZ1);
    float* T = (float*)(wsb + 131072 + 3 * SZN + 3 * SZ1);       // N*32 fp32 accumulator

    size_t wboff = 131072 + 3 * SZN + 3 * SZ1 + 15360000ull;
    auto wbsz = [](int K) { return (size_t)((K + 1) & ~1) * 4096; };
    uint4* wb_stem1 = (uint4*)(wsb + wboff);         size_t o1 = wboff + wbsz(27);
    uint4* wb_down  = (uint4*)(wsb + o1);            size_t o2 = o1 + wbsz(8);
    uint4* wb_res1  = (uint4*)(wsb + o2);            size_t o3 = o2 + wbsz(27);
    uint4* wb_res2  = (uint4*)(wsb + o3);            size_t o4 = o3 + wbsz(27);
    uint4* wb_up    = (uint4*)(wsb + o4);            size_t o5 = o4 + wbsz(8);
    uint4* wb_f1A   = (uint4*)(wsb + o5);            size_t o6 = o5 + wbsz(27);
    uint4* wb_f1B   = (uint4*)(wsb + o6);            size_t o7 = o6 + wbsz(27);
    uint4* wb_fuse2 = (uint4*)(wsb + o7);            size_t o8 = o7 + wbsz(27);

    int* nbrT0 = (int*)(wsb + o8);                   size_t o9  = o8 + 27ull * NPTS * 4;
    int* nbrTd = (int*)(wsb + o9);                   size_t o10 = o9 + 8ull * N1PTS * 4;
    int* nbrT1 = (int*)(wsb + o10);                  size_t o11 = o10 + 27ull * N1PTS * 4;
    int* nbrTu = (int*)(wsb + o11);

    const float* X        = (const float*)d_in[0];
    const float* Wstem0   = (const float*)d_in[1];
    const float* gb_stem0 = (const float*)d_in[2];
    const float* Wstem1   = (const float*)d_in[3];
    const float* gb_stem1 = (const float*)d_in[4];
    const float* Wdown    = (const float*)d_in[5];
    const float* gb_down  = (const float*)d_in[6];
    const float* Wres1    = (const float*)d_in[7];
    const float* gb_res1  = (const float*)d_in[8];
    const float* Wres2    = (const float*)d_in[9];
    const float* gb_res2  = (const float*)d_in[10];
    const float* wi = (const float*)d_in[11];
    const float* bi = (const float*)d_in[12];
    const float* wk = (const float*)d_in[13];
    const float* bk = (const float*)d_in[14];
    const float* wv = (const float*)d_in[15];
    const float* bv = (const float*)d_in[16];
    const float* wo = (const float*)d_in[17];
    const float* bo = (const float*)d_in[18];
    const float* Wup      = (const float*)d_in[19];
    const float* gb_up    = (const float*)d_in[20];
    const float* Wfuse1   = (const float*)d_in[21];
    const float* gb_fuse1 = (const float*)d_in[22];
    const float* Wfuse2   = (const float*)d_in[23];
    const float* gb_fuse2 = (const float*)d_in[24];
    const float* Wds      = (const float*)d_in[25];
    const float* gb_ds    = (const float*)d_in[26];
    const float* Wcls     = (const float*)d_in[27];
    const float* bcls     = (const float*)d_in[28];

    const int* nbr0     = (const int*)d_in[29];
    const int* nbr_down = (const int*)d_in[30];
    const int* nbr1     = (const int*)d_in[31];
    const int* nbr_up   = (const int*)d_in[32];

    const float invN  = 1.0f / (float)NPTS;
    const float invN1 = 1.0f / (float)N1PTS;

    hipMemsetAsync((void*)ST, 0, (9216 + 66) * sizeof(float), stream);

    hipLaunchKernelGGL((transpose_nbr<27>), dim3(cdiv(NPTS, 256)), dim3(256), 0, stream,
                       nbr0, nbrT0, NPTS);
    hipLaunchKernelGGL((transpose_nbr<8>), dim3(cdiv(N1PTS, 256)), dim3(256), 0, stream,
                       nbr_down, nbrTd, N1PTS);
    hipLaunchKernelGGL((transpose_nbr<27>), dim3(cdiv(N1PTS, 256)), dim3(256), 0, stream,
                       nbr1, nbrT1, N1PTS);
    hipLaunchKernelGGL((transpose_nbr<8>), dim3(cdiv(NPTS, 256)), dim3(256), 0, stream,
                       nbr_up, nbrTu, NPTS);

    {
        WbArgs a;
        a.src[0] = Wstem1; a.dst[0] = wb_stem1; a.CINF[0] = 32; a.COFF[0] = 0;  a.K2[0] = 54;
        a.src[1] = Wdown;  a.dst[1] = wb_down;  a.CINF[1] = 32; a.COFF[1] = 0;  a.K2[1] = 16;
        a.src[2] = Wres1;  a.dst[2] = wb_res1;  a.CINF[2] = 32; a.COFF[2] = 0;  a.K2[2] = 54;
        a.src[3] = Wres2;  a.dst[3] = wb_res2;  a.CINF[3] = 32; a.COFF[3] = 0;  a.K2[3] = 54;
        a.src[4] = Wup;    a.dst[4] = wb_up;    a.CINF[4] = 32; a.COFF[4] = 0;  a.K2[4] = 16;
        a.src[5] = Wfuse1; a.dst[5] = wb_f1A;   a.CINF[5] = 64; a.COFF[5] = 0;  a.K2[5] = 54;
        a.src[6] = Wfuse1; a.dst[6] = wb_f1B;   a.CINF[6] = 64; a.COFF[6] = 32; a.K2[6] = 54;
        a.src[7] = Wfuse2; a.dst[7] = wb_fuse2; a.CINF[7] = 32; a.COFF[7] = 0;  a.K2[7] = 54;
        hipLaunchKernelGGL(convert_wb, dim3(54, 8), dim3(64), 0, stream, a);
    }

    const int gS   = cdiv(NPTS, 64);     // conv_x3, conv_ds2
    const int gB   = cdiv(NPTS, 256);    // conv_part / conv_blk8
    const int gM1  = cdiv(N1PTS, 64);    // conv_mfma N1
    const int gBN  = cdiv(NPTS * 4, 256);
    const int gBN1 = cdiv(N1PTS * 4, 256);
    const int gN1p = cdiv(N1PTS, 256);
    const int gN   = cdiv(NPTS, 256);
    const int KH0 = 14;                  // 27 = 14 + 13 k-split

    // stem
    hipLaunchKernelGGL(conv_x3, dim3(gS), dim3(256), 0, stream,
                       X, nbrT0, Wstem0, A, ST + 0 * 1024, NPTS);
    hipLaunchKernelGGL((bn_apply<true>), dim3(gBN), dim3(256), 0, stream,
                       A, ST + 0 * 1024, gb_stem0, invN, NPTS * 4);
    // stem1: chain 14 + 13
    hipLaunchKernelGGL((conv_part<14, 0>), dim3(gB), dim3(1024), 0, stream,
                       A, nbrT0, wb_stem1, T, (u16*)nullptr, (float*)nullptr, NPTS);
    hipLaunchKernelGGL((conv_part<13, 2>), dim3(gB), dim3(1024), 0, stream,
                       A, nbrT0 + (size_t)KH0 * NPTS, wb_stem1 + KH0 * 256, T, B, ST + 1 * 1024, NPTS);
    hipLaunchKernelGGL((bn_apply<true>), dim3(gBN), dim3(256), 0, stream,
                       B, ST + 1 * 1024, gb_stem1, invN, NPTS * 4);   // B = x0

    // downsample
    hipLaunchKernelGGL((conv_mfma<8>), dim3(gM1), dim3(256), 0, stream,
                       B, nbrTd, wb_down, C, ST + 2 * 1024, N1PTS);
    hipLaunchKernelGGL((bn_apply<true>), dim3(gBN1), dim3(256), 0, stream,
                       C, ST + 2 * 1024, gb_down, invN1, N1PTS * 4);  // C = d

    // residual block convs
    hipLaunchKernelGGL((conv_mfma<27>), dim3(gM1), dim3(256), 0, stream,
                       C, nbrT1, wb_res1, D, ST + 3 * 1024, N1PTS);
    hipLaunchKernelGGL((bn_apply<true>), dim3(gBN1), dim3(256), 0, stream,
                       D, ST + 3 * 1024, gb_res1, invN1, N1PTS * 4);
    hipLaunchKernelGGL((conv_mfma<27>), dim3(gM1), dim3(256), 0, stream,
                       D, nbrT1, wb_res2, E, ST + 4 * 1024, N1PTS);
    hipLaunchKernelGGL((bn_apply<false>), dim3(gBN1), dim3(256), 0, stream,
                       E, ST + 4 * 1024, gb_res2, invN1, N1PTS * 4);  // E = net

    // attention + residual add (writes r into D)
    hipLaunchKernelGGL(att_logits, dim3(gN1p), dim3(256), 0, stream,
                       E, wi, bi, L, (u32*)ATT, N1PTS);
    hipLaunchKernelGGL(att_accum, dim3(gN1p), dim3(256), 0, stream, E, L, ATT, N1PTS);
    hipLaunchKernelGGL(att_ctx_k, dim3(1), dim3(64), 0, stream, wk, bk, ATT);
    hipLaunchKernelGGL(att_out_res, dim3(gN1p), dim3(256), 0, stream,
                       E, C, wv, bv, wo, bo, ATT, D, N1PTS);          // D = r

    // upsample (K=8, src L2-resident)
    hipLaunchKernelGGL(conv_blk8, dim3(gB), dim3(1024), 0, stream,
                       D, nbrTu, wb_up, A, ST + 5 * 1024, NPTS);
    hipLaunchKernelGGL((bn_apply<true>), dim3(gBN), dim3(256), 0, stream,
                       A, ST + 5 * 1024, gb_up, invN, NPTS * 4);      // A = u_bn

    // fuse1: 4 chained partials (cat never materialized); ds independent
    hipLaunchKernelGGL((conv_part<14, 0>), dim3(gB), dim3(1024), 0, stream,
                       A, nbrT0, wb_f1A, T, (u16*)nullptr, (float*)nullptr, NPTS);
    hipLaunchKernelGGL((conv_part<13, 1>), dim3(gB), dim3(1024), 0, stream,
                       A, nbrT0 + (size_t)KH0 * NPTS, wb_f1A + KH0 * 256, T,
                       (u16*)nullptr, (float*)nullptr, NPTS);
    hipLaunchKernelGGL((conv_part<14, 1>), dim3(gB), dim3(1024), 0, stream,
                       B, nbrT0, wb_f1B, T, (u16*)nullptr, (float*)nullptr, NPTS);
    hipLaunchKernelGGL(conv_ds2, dim3(gS), dim3(256), 0, stream,
                       A, B, Wds, G, ST + 8 * 1024, NPTS);            // G = ds raw
    hipLaunchKernelGGL((conv_part<13, 2>), dim3(gB), dim3(1024), 0, stream,
                       B, nbrT0 + (size_t)KH0 * NPTS, wb_f1B + KH0 * 256, T, A, ST + 6 * 1024, NPTS);
    hipLaunchKernelGGL((bn_apply<true>), dim3(gBN), dim3(256), 0, stream,
                       A, ST + 6 * 1024, gb_fuse1, invN, NPTS * 4);   // A = fuse1 bn

    // fuse2: chain 14 + 13
    hipLaunchKernelGGL((conv_part<14, 0>), dim3(gB), dim3(1024), 0, stream,
                       A, nbrT0, wb_fuse2, T, (u16*)nullptr, (float*)nullptr, NPTS);
    hipLaunchKernelGGL((conv_part<13, 2>), dim3(gB), dim3(1024), 0, stream,
                       A, nbrT0 + (size_t)KH0 * NPTS, wb_fuse2 + KH0 * 256, T, B, ST + 7 * 1024, NPTS);  // B = net2 raw

    // final fuse + classifier
    hipLaunchKernelGGL(final_cls, dim3(gN), dim3(256), 0, stream,
                       B, G, ST + 7 * 1024, ST + 8 * 1024, gb_fuse2, gb_ds,
                       Wcls, bcls, (float*)d_out, invN, NPTS);
}